// Round 3
// baseline (5947.406 us; speedup 1.0000x reference)
//
#include <hip/hip_runtime.h>
#include <cstdint>
#include <cstddef>

// SpiralAutoencoder forward, MI355X gfx950.
// Inputs are float32 (per reference dtypes), indices int32, OUTPUT float32.
// Internal activations stored bf16 (u16) in d_ws, fp32 accumulation.
// Pools = gather via device-built capped per-row edge lists.
// ws ~32.2 MB: A(10.3MB bf16) | B(20.6MB bf16) | cur | lists | smalls(f32)

typedef unsigned short u16;
#define CDIV(a,b) (((a)+(b)-1)/(b))
#define POOL_CAP 64

__device__ __forceinline__ float bf(u16 u){ return __uint_as_float(((unsigned)u)<<16); }
__device__ __forceinline__ u16 fb(float x){
  unsigned u = __float_as_uint(x);
  unsigned r = u + 0x7fffu + ((u>>16)&1u);   // RNE
  return (u16)(r>>16);
}

// ---- f32 -> bf16 cast ----
__global__ void cast_k(const float* __restrict__ in, u16* __restrict__ out, int n){
  int i = blockIdx.x*blockDim.x + threadIdx.x;
  if (i < n) out[i] = fb(in[i]);
}

// ---- audio embedding: (32,1536) @ (64,1536)^T + b -> (32,64) f32 ----
__global__ void audio_emb_k(const float* __restrict__ ah, const float* __restrict__ W,
                            const float* __restrict__ b, float* __restrict__ out){
  int t = blockIdx.x, f = threadIdx.x;      // 32 blocks x 64 threads
  const float4* x4 = (const float4*)(ah + t*1536);
  const float4* w4 = (const float4*)(W + f*1536);
  float acc = b[f];
  for (int k=0;k<384;k++){
    float4 xv = x4[k], wv = w4[k];
    acc += xv.x*wv.x + xv.y*wv.y + xv.z*wv.z + xv.w*wv.w;
  }
  out[t*64+f] = acc;
}

// ---- spiral conv: out[b,v,o] = bias[o] + sum_{s<9,c<IC} x[b,idx[v,s],c]*W[o,s*IC+c]
//      x bf16, W f32, out bf16, fp32 accum, optional ELU ----
template<int IC>
__global__ void conv_k(const u16* __restrict__ x, const int* __restrict__ idx,
                       const float* __restrict__ W, const float* __restrict__ bias,
                       u16* __restrict__ out, int B, int V, int OC, int do_elu){
  int total = B*V*OC;
  int i = blockIdx.x*blockDim.x + threadIdx.x;
  if (i >= total) return;
  int o = i % OC; int bv = i / OC; int v = bv % V; int b = bv / V;
  const u16* xb = x + (size_t)b*V*IC;
  const float* wrow = W + (size_t)o*9*IC;
  const int* vix = idx + v*9;
  float acc = bias[o];
  for (int s=0;s<9;s++){
    const u16* xr = xb + (size_t)vix[s]*IC;
    const float* wr = wrow + s*IC;
    if constexpr (IC % 4 == 0){
      const ushort4* x4 = (const ushort4*)xr;
      const float4* w4 = (const float4*)wr;
      for (int k=0;k<IC/4;k++){
        ushort4 xv = x4[k]; float4 wv = w4[k];
        acc += bf(xv.x)*wv.x + bf(xv.y)*wv.y + bf(xv.z)*wv.z + bf(xv.w)*wv.w;
      }
    } else {
      for (int k=0;k<IC;k++) acc += bf(xr[k])*wr[k];
    }
  }
  if (do_elu && acc < 0.f) acc = expm1f(acc);
  out[i] = fb(acc);
}

// ---- build capped per-row edge lists for a pool matrix ----
__global__ void fill_lists_k(const int* __restrict__ rows, int nnz,
                             int* __restrict__ cur, int* __restrict__ lst){
  int e = blockIdx.x*blockDim.x + threadIdx.x;
  if (e >= nnz) return;
  int r = rows[e];
  int p = atomicAdd(&cur[r], 1);
  if (p < POOL_CAP) lst[r*POOL_CAP + p] = e;
}

// ---- pool gather: out[b,r,c] = sum_{e in row r} vals[e]*x[b,cols[e],c] ----
__global__ void pool_g_k(const u16* __restrict__ x, const int* __restrict__ cols,
                         const float* __restrict__ vals, const int* __restrict__ cur,
                         const int* __restrict__ lst, u16* __restrict__ out,
                         int B, int Vin, int Vout, int C){
  int total = B*Vout*C;
  int i = blockIdx.x*blockDim.x + threadIdx.x;
  if (i >= total) return;
  int c = i % C; int t = i / C; int r = t % Vout; int b = t / Vout;
  int deg = cur[r]; if (deg > POOL_CAP) deg = POOL_CAP;
  const int* le = lst + r*POOL_CAP;
  float acc = 0.f;
  for (int k=0;k<deg;k++){
    int e = le[k];
    acc += vals[e] * bf(x[((size_t)b*Vin + (size_t)cols[e])*C + c]);
  }
  out[i] = fb(acc);
}

// ---- encoder linear: z[f] = b[f] + sum_{k<5120} x[k]*W[f,k]  (x bf16, z f32) ----
__global__ void enc_lin_k(const u16* __restrict__ x, const float* __restrict__ W,
                          const float* __restrict__ b, float* __restrict__ z){
  int f = threadIdx.x;   // 64 threads
  const ushort4* x4 = (const ushort4*)x;
  const float4* w4 = (const float4*)(W + f*5120);
  float acc = b[f];
  for (int k=0;k<1280;k++){
    ushort4 xv = x4[k]; float4 wv = w4[k];
    acc += bf(xv.x)*wv.x + bf(xv.y)*wv.y + bf(xv.z)*wv.z + bf(xv.w)*wv.w;
  }
  z[f] = acc;
}

// ---- concat audio_emb(32,64) + z(64) -> h0(32,128) f32 ----
__global__ void concat_k(const float* __restrict__ aemb, const float* __restrict__ z,
                         float* __restrict__ h0){
  int i = blockIdx.x*blockDim.x + threadIdx.x;
  if (i >= 32*128) return;
  int t = i >> 7, j = i & 127;
  h0[i] = (j < 64) ? aemb[t*64 + j] : z[j-64];
}

// ---- 3-layer bidirectional LSTM, seq=32, H=32, single block. Weights f32. ----
__global__ void __launch_bounds__(256) lstm3_k(
    const float* __restrict__ h0,
    const float* __restrict__ l0_Wih, const float* __restrict__ l0_Whh,
    const float* __restrict__ l0_bih, const float* __restrict__ l0_bhh,
    const float* __restrict__ l12_Wih, const float* __restrict__ l12_Whh,
    const float* __restrict__ l12_bih, const float* __restrict__ l12_bhh,
    float* __restrict__ latent){
  __shared__ __align__(16) float xbuf[32*128];
  __shared__ __align__(16) float obuf[32*64];
  __shared__ __align__(16) float hs[2][32];
  __shared__ __align__(16) float cs[2][32];
  __shared__ __align__(16) float gs[2][128];
  int t = threadIdx.x;
  int dir = t >> 7, j = t & 127;
  for (int i=t;i<32*128;i+=256) xbuf[i]=h0[i];

  for (int layer=0; layer<3; layer++){
    int in_dim = (layer==0) ? 128 : 64;
    const float *Wih,*Whh,*bih,*bhh;
    if (layer==0){
      Wih=l0_Wih + dir*128*128; Whh=l0_Whh + dir*128*32;
      bih=l0_bih + dir*128;     bhh=l0_bhh + dir*128;
    } else {
      int m = (layer-1)*2 + dir;
      Wih=l12_Wih + m*128*64; Whh=l12_Whh + m*128*32;
      bih=l12_bih + m*128;    bhh=l12_bhh + m*128;
    }
    if (j < 32){ hs[dir][j]=0.f; cs[dir][j]=0.f; }
    float bias = bih[j] + bhh[j];
    const float4* w4  = (const float4*)(Wih + j*in_dim);
    const float4* wh4 = (const float4*)(Whh + j*32);
    __syncthreads();

    for (int s=0;s<32;s++){
      int tx = dir ? (31-s) : s;
      const float4* x4 = (const float4*)(xbuf + tx*in_dim);
      float acc = bias;
      for (int k=0;k<in_dim/4;k++){
        float4 xv=x4[k]; float4 wv=w4[k];
        acc += xv.x*wv.x+xv.y*wv.y+xv.z*wv.z+xv.w*wv.w;
      }
      const float4* h4 = (const float4*)(hs[dir]);
      #pragma unroll
      for (int k=0;k<8;k++){
        float4 hv=h4[k]; float4 wv=wh4[k];
        acc += hv.x*wv.x+hv.y*wv.y+hv.z*wv.z+hv.w*wv.w;
      }
      gs[dir][j] = acc;
      __syncthreads();
      if (j < 32){
        float ig = 1.f/(1.f+expf(-gs[dir][j]));
        float fg = 1.f/(1.f+expf(-gs[dir][32+j]));
        float gg = tanhf(gs[dir][64+j]);
        float og = 1.f/(1.f+expf(-gs[dir][96+j]));
        float cn = fg*cs[dir][j] + ig*gg;
        float hn = og*tanhf(cn);
        cs[dir][j]=cn; hs[dir][j]=hn;
        obuf[tx*64 + dir*32 + j] = hn;
      }
      __syncthreads();
    }
    for (int i=t;i<32*64;i+=256) xbuf[i]=obuf[i];
    __syncthreads();
  }
  for (int i=t;i<32*64;i+=256) latent[i]=obuf[i];
}

// ---- decoder linear: y[t,r] = b[r] + sum_{k<64} latent[t,k]*W[r,k] -> bf16 ----
__global__ void dec_lin_k(const float* __restrict__ latent, const float* __restrict__ W,
                          const float* __restrict__ b, u16* __restrict__ y){
  int i = blockIdx.x*blockDim.x + threadIdx.x;
  if (i >= 32*5120) return;
  int r = i % 5120, t = i / 5120;
  const float4* x4 = (const float4*)(latent + t*64);
  const float4* w4 = (const float4*)(W + (size_t)r*64);
  float acc = b[r];
  #pragma unroll
  for (int k=0;k<16;k++){
    float4 xv=x4[k]; float4 wv=w4[k];
    acc += xv.x*wv.x+xv.y*wv.y+xv.z*wv.z+xv.w*wv.w;
  }
  y[i] = fb(acc);
}

// ---- final conv (OC=3, IC=32, no ELU) + actor residual -> f32 out ----
__global__ void final_k(const u16* __restrict__ x, const int* __restrict__ idx,
                        const float* __restrict__ W, const float* __restrict__ bias,
                        const float* __restrict__ actor, float* __restrict__ out){
  int i = blockIdx.x*blockDim.x + threadIdx.x;
  if (i >= 32*5023*3) return;
  int o = i % 3; int bv = i/3; int v = bv % 5023; int b = bv / 5023;
  const u16* xb = x + (size_t)b*5023*32;
  const float* wrow = W + o*288;
  const int* vix = idx + v*9;
  float acc = bias[o];
  for (int s=0;s<9;s++){
    const ushort4* x4 = (const ushort4*)(xb + (size_t)vix[s]*32);
    const float4* w4 = (const float4*)(wrow + s*32);
    for (int k=0;k<8;k++){
      ushort4 xv=x4[k]; float4 wv=w4[k];
      acc += bf(xv.x)*wv.x+bf(xv.y)*wv.y+bf(xv.z)*wv.z+bf(xv.w)*wv.w;
    }
  }
  acc += actor[v*3+o];
  out[i] = acc;
}

extern "C" void kernel_launch(void* const* d_in, const int* in_sizes, int n_in,
                              void* d_out, int out_size, void* d_ws, size_t ws_size,
                              hipStream_t stream){
  (void)in_sizes; (void)n_in; (void)out_size; (void)ws_size;

  const float* audio = (const float*)d_in[0];
  const float* actor = (const float*)d_in[2];
  const int* sp[4]   = {(const int*)d_in[3],(const int*)d_in[4],(const int*)d_in[5],(const int*)d_in[6]};
  const int* drows[4]; const int* dcols[4]; const float* dvals[4];
  for (int i=0;i<4;i++){ drows[i]=(const int*)d_in[7+3*i]; dcols[i]=(const int*)d_in[8+3*i]; dvals[i]=(const float*)d_in[9+3*i]; }
  const int* urows[4]; const int* ucols[4]; const float* uvals[4];
  for (int i=0;i<4;i++){ urows[i]=(const int*)d_in[19+3*i]; ucols[i]=(const int*)d_in[20+3*i]; uvals[i]=(const float*)d_in[21+3*i]; }
  const float* encW[4]={(const float*)d_in[31],(const float*)d_in[33],(const float*)d_in[35],(const float*)d_in[37]};
  const float* encB[4]={(const float*)d_in[32],(const float*)d_in[34],(const float*)d_in[36],(const float*)d_in[38]};
  const float* enc_lin_W=(const float*)d_in[39]; const float* enc_lin_b=(const float*)d_in[40];
  const float* dec_lin_W=(const float*)d_in[41]; const float* dec_lin_b=(const float*)d_in[42];
  const float* decW[5]={(const float*)d_in[43],(const float*)d_in[45],(const float*)d_in[47],(const float*)d_in[49],(const float*)d_in[51]};
  const float* decB[5]={(const float*)d_in[44],(const float*)d_in[46],(const float*)d_in[48],(const float*)d_in[50],(const float*)d_in[52]};
  const float* audW=(const float*)d_in[53]; const float* audB=(const float*)d_in[54];
  const float* l0_Wih=(const float*)d_in[55]; const float* l0_Whh=(const float*)d_in[56];
  const float* l0_bih=(const float*)d_in[57]; const float* l0_bhh=(const float*)d_in[58];
  const float* l12_Wih=(const float*)d_in[59]; const float* l12_Whh=(const float*)d_in[60];
  const float* l12_bih=(const float*)d_in[61]; const float* l12_bhh=(const float*)d_in[62];
  float* out = (float*)d_out;

  // ---- workspace layout (bytes) ----
  char* base = (char*)d_ws;
  u16* A  = (u16*)base;                          // 5,143,552 bf16 = 10,287,104 B
  u16* Bb = (u16*)(base + 10287104);             // 10,287,104 bf16 = 20,574,208 B
  u16* Ac = (u16*)(base + 10287104 + 20574208);  // actor bf16: 15069 -> 30,144 B (pad 30,208)
  int* cur = (int*)(base + 10287104 + 20574208 + 30208);
  int* lst = cur + 5024;
  float* sm = (float*)((char*)lst + 5023*POOL_CAP*4);
  float* aemb   = sm;                 // 2048
  float* z      = sm + 2048;          // 64
  float* h0     = sm + 2048+64;       // 4096
  float* latent = sm + 2048+64+4096;  // 2048

  auto build = [&](const int* rows, int nnz, int Vout){
    hipMemsetAsync(cur, 0, (size_t)Vout*4, stream);
    fill_lists_k<<<CDIV(nnz,256),256,0,stream>>>(rows, nnz, cur, lst);
  };

  // ---- audio path ----
  audio_emb_k<<<32,64,0,stream>>>(audio, audW, audB, aemb);

  // ---- encoder (B=1): conv->A, pool->B alternation ----
  cast_k<<<CDIV(15069,256),256,0,stream>>>(actor, Ac, 15069);
  conv_k<3><<<CDIV(5023*32,256),256,0,stream>>>(Ac, sp[0], encW[0], encB[0], A, 1, 5023, 32, 1);
  build(drows[0], 3768, 1256);
  pool_g_k<<<CDIV(1256*32,256),256,0,stream>>>(A, dcols[0], dvals[0], cur, lst, Bb, 1, 5023, 1256, 32);

  conv_k<32><<<CDIV(1256*64,256),256,0,stream>>>(Bb, sp[1], encW[1], encB[1], A, 1, 1256, 64, 1);
  build(drows[1], 942, 314);
  pool_g_k<<<CDIV(314*64,256),256,0,stream>>>(A, dcols[1], dvals[1], cur, lst, Bb, 1, 1256, 314, 64);

  conv_k<64><<<CDIV(314*128,256),256,0,stream>>>(Bb, sp[2], encW[2], encB[2], A, 1, 314, 128, 1);
  build(drows[2], 237, 79);
  pool_g_k<<<CDIV(79*128,256),256,0,stream>>>(A, dcols[2], dvals[2], cur, lst, Bb, 1, 314, 79, 128);

  conv_k<128><<<CDIV(79*256,256),256,0,stream>>>(Bb, sp[3], encW[3], encB[3], A, 1, 79, 256, 1);
  build(drows[3], 60, 20);
  pool_g_k<<<CDIV(20*256,256),256,0,stream>>>(A, dcols[3], dvals[3], cur, lst, Bb, 1, 79, 20, 256);

  enc_lin_k<<<1,64,0,stream>>>(Bb, enc_lin_W, enc_lin_b, z);
  concat_k<<<CDIV(32*128,256),256,0,stream>>>(aemb, z, h0);

  // ---- LSTM (serial, single block) ----
  lstm3_k<<<1,256,0,stream>>>(h0, l0_Wih, l0_Whh, l0_bih, l0_bhh,
                              l12_Wih, l12_Whh, l12_bih, l12_bhh, latent);

  // ---- decoder (B=32 frames) ----
  dec_lin_k<<<CDIV(32*5120,256),256,0,stream>>>(latent, dec_lin_W, dec_lin_b, A); // (32,20,256)

  // stage j=3: up-pool u3 (20->79, C=256) A->B, conv sp3 dec_W0 B->A
  build(urows[3], 237, 79);
  pool_g_k<<<CDIV(32*79*256,256),256,0,stream>>>(A, ucols[3], uvals[3], cur, lst, Bb, 32, 20, 79, 256);
  conv_k<256><<<CDIV(32*79*256,256),256,0,stream>>>(Bb, sp[3], decW[0], decB[0], A, 32, 79, 256, 1);

  // stage j=2: up-pool u2 (79->314, C=256) A->B, conv sp2 dec_W1 B->A
  build(urows[2], 942, 314);
  pool_g_k<<<CDIV(32*314*256,256),256,0,stream>>>(A, ucols[2], uvals[2], cur, lst, Bb, 32, 79, 314, 256);
  conv_k<256><<<CDIV(32*314*128,256),256,0,stream>>>(Bb, sp[2], decW[1], decB[1], A, 32, 314, 128, 1);

  // stage j=1: up-pool u1 (314->1256, C=128) A->B, conv sp1 dec_W2 B->A
  build(urows[1], 3768, 1256);
  pool_g_k<<<CDIV(32*1256*128,256),256,0,stream>>>(A, ucols[1], uvals[1], cur, lst, Bb, 32, 314, 1256, 128);
  conv_k<128><<<CDIV(32*1256*64,256),256,0,stream>>>(Bb, sp[1], decW[2], decB[2], A, 32, 1256, 64, 1);

  // stage j=0: up-pool u0 (1256->5023, C=64) A->B, conv sp0 dec_W3 B->A
  build(urows[0], 15069, 5023);
  pool_g_k<<<CDIV(32*5023*64,256),256,0,stream>>>(A, ucols[0], uvals[0], cur, lst, Bb, 32, 1256, 5023, 64);
  conv_k<64><<<CDIV(32*5023*32,256),256,0,stream>>>(Bb, sp[0], decW[3], decB[3], A, 32, 5023, 32, 1);

  // final conv (288->3) + actor residual -> f32 out
  final_k<<<CDIV(32*5023*3,256),256,0,stream>>>(A, sp[0], decW[4], decB[4], actor, out);
}

// Round 4
// 1139.183 us; speedup vs baseline: 5.2208x; 5.2208x over previous
//
#include <hip/hip_runtime.h>
#include <cstdint>
#include <cstddef>

// SpiralAutoencoder forward, MI355X gfx950.
// Inputs f32, indices i32, output f32. Internal activations bf16, fp32 accum.
// Large spiral convs = MFMA bf16 GEMM (16x16x32), weights cast f32->bf16 in staging.
// Pools = gather via device-built capped per-row edge lists (fused builder).

typedef unsigned short u16;
typedef __attribute__((ext_vector_type(8))) short short8;
typedef __attribute__((ext_vector_type(4))) float float4v;
#define CDIV(a,b) (((a)+(b)-1)/(b))
#define POOL_CAP 64

__device__ __forceinline__ float bf(u16 u){ return __uint_as_float(((unsigned)u)<<16); }
__device__ __forceinline__ u16 fb(float x){
  unsigned u = __float_as_uint(x);
  unsigned r = u + 0x7fffu + ((u>>16)&1u);   // RNE
  return (u16)(r>>16);
}

// ---- f32 -> bf16 cast ----
__global__ void cast_k(const float* __restrict__ in, u16* __restrict__ out, int n){
  int i = blockIdx.x*blockDim.x + threadIdx.x;
  if (i < n) out[i] = fb(in[i]);
}

// ---- audio embedding: (32,1536) @ (64,1536)^T + b -> (32,64) f32 ----
__global__ void audio_emb_k(const float* __restrict__ ah, const float* __restrict__ W,
                            const float* __restrict__ b, float* __restrict__ out){
  int t = blockIdx.x, f = threadIdx.x;      // 32 blocks x 64 threads
  const float4* x4 = (const float4*)(ah + t*1536);
  const float4* w4 = (const float4*)(W + f*1536);
  float acc = b[f];
  for (int k=0;k<384;k++){
    float4 xv = x4[k], wv = w4[k];
    acc += xv.x*wv.x + xv.y*wv.y + xv.z*wv.z + xv.w*wv.w;
  }
  out[t*64+f] = acc;
}

// ---- scalar spiral conv for IC=3 (encoder stage 0) ----
__global__ void conv3_k(const u16* __restrict__ x, const int* __restrict__ idx,
                        const float* __restrict__ W, const float* __restrict__ bias,
                        u16* __restrict__ out, int V, int OC){
  int i = blockIdx.x*blockDim.x + threadIdx.x;
  if (i >= V*OC) return;
  int o = i % OC; int v = i / OC;
  const float* wrow = W + (size_t)o*27;
  const int* vix = idx + v*9;
  float acc = bias[o];
  for (int s=0;s<9;s++){
    const u16* xr = x + (size_t)vix[s]*3;
    acc += bf(xr[0])*wrow[s*3] + bf(xr[1])*wrow[s*3+1] + bf(xr[2])*wrow[s*3+2];
  }
  if (acc < 0.f) acc = expm1f(acc);
  out[i] = fb(acc);
}

// ---- MFMA spiral conv: out[m,o], m=b*V+v, K=9*IC, gathered A, W cast bf16 ----
// BM=64, BN in {32,64}, BK=32. One 32-chunk == one spiral entry (IC%32==0).
template<int IC, int BN>
__global__ void __launch_bounds__(256) conv_mfma(
    const u16* __restrict__ x, const int* __restrict__ idx,
    const float* __restrict__ W, const float* __restrict__ bias,
    u16* __restrict__ out, int V, int OC, int M){
  constexpr int K = 9*IC;
  constexpr int NT = BN/16;
  constexpr int LOG2 = (IC==32?5: IC==64?6: IC==128?7:8);
  constexpr int AST = 40;                 // LDS row stride (u16): 32 data + 8 pad
  __shared__ u16 Asm[64*AST];
  __shared__ u16 Bsm[BN*AST];
  __shared__ int rowB[64], rowV[64];
  int t = threadIdx.x;
  int m0 = blockIdx.x*64;
  int o0 = blockIdx.y*BN;
  if (t < 64){
    int mg = m0 + t;
    if (mg < M){ int b = mg / V; rowB[t] = b; rowV[t] = mg - b*V; }
    else rowB[t] = -1;
  }
  int lane = t & 63, wave = t >> 6;
  int quad = lane >> 4, col = lane & 15;
  float4v acc[NT];
  #pragma unroll
  for (int nt=0;nt<NT;nt++) acc[nt] = (float4v)0.f;
  int arow = t >> 2, aq = t & 3;

  for (int kc = 0; kc < K/32; ++kc){
    int s  = (kc*32) >> LOG2;
    int c0 = (kc*32) & (IC-1);
    __syncthreads();
    { // A tile: 64 rows x 32 bf16, contiguous 64B per row from gathered x
      int b = rowB[arow];
      uint4 val = {0u,0u,0u,0u};
      if (b >= 0){
        int ix = idx[rowV[arow]*9 + s];
        const u16* src = x + ((size_t)b*V + ix)*IC + c0 + aq*8;
        val = *(const uint4*)src;
      }
      *(uint4*)&Asm[arow*AST + aq*8] = val;
    }
    if (t < BN*4){ // B tile: BN rows of W, f32 -> bf16
      int br = t >> 2, bq = t & 3;
      const float* wsrc = W + (size_t)(o0+br)*K + kc*32 + bq*8;
      float4 w0 = *(const float4*)wsrc;
      float4 w1 = *(const float4*)(wsrc+4);
      alignas(16) u16 tmp[8] = {fb(w0.x),fb(w0.y),fb(w0.z),fb(w0.w),
                                fb(w1.x),fb(w1.y),fb(w1.z),fb(w1.w)};
      *(uint4*)&Bsm[br*AST + bq*8] = *(const uint4*)tmp;
    }
    __syncthreads();
    short8 a = *(const short8*)&Asm[(wave*16 + col)*AST + quad*8];
    #pragma unroll
    for (int nt=0; nt<NT; ++nt){
      short8 bfr = *(const short8*)&Bsm[(nt*16 + col)*AST + quad*8];
      acc[nt] = __builtin_amdgcn_mfma_f32_16x16x32_bf16(a, bfr, acc[nt], 0, 0, 0);
    }
  }
  // epilogue: D col=lane&15, row=quad*4+reg (m89-verified); bias+ELU -> bf16
  #pragma unroll
  for (int nt=0; nt<NT; ++nt){
    int o = o0 + nt*16 + col;
    float bv = bias[o];
    #pragma unroll
    for (int r=0;r<4;r++){
      int mg = m0 + wave*16 + quad*4 + r;
      if (mg < M){
        float val = acc[nt][r] + bv;
        if (val < 0.f) val = expm1f(val);
        out[(size_t)mg*OC + o] = fb(val);
      }
    }
  }
}

// ---- fused list builder for all 8 pool matrices ----
struct Lists {
  const int* rows[8];
  int nnz[8];
  int curoff[8];
  int lstoff[8];
};
__global__ void fill_all_k(Lists L, int* __restrict__ curBase, int* __restrict__ lstBase, int total){
  int i = blockIdx.x*blockDim.x + threadIdx.x;
  if (i >= total) return;
  int off = i, k = 0;
  while (off >= L.nnz[k]){ off -= L.nnz[k]; k++; }
  int r = L.rows[k][off];
  int p = atomicAdd(curBase + L.curoff[k] + r, 1);
  if (p < POOL_CAP) lstBase[L.lstoff[k] + r*POOL_CAP + p] = off;
}

// ---- pool gather: out[b,r,c] = sum_{e in row r} vals[e]*x[b,cols[e],c] ----
__global__ void pool_g_k(const u16* __restrict__ x, const int* __restrict__ cols,
                         const float* __restrict__ vals, const int* __restrict__ cur,
                         const int* __restrict__ lst, u16* __restrict__ out,
                         int B, int Vin, int Vout, int C){
  int total = B*Vout*C;
  int i = blockIdx.x*blockDim.x + threadIdx.x;
  if (i >= total) return;
  int c = i % C; int t = i / C; int r = t % Vout; int b = t / Vout;
  int deg = cur[r]; if (deg > POOL_CAP) deg = POOL_CAP;
  const int* le = lst + r*POOL_CAP;
  float acc = 0.f;
  for (int k=0;k<deg;k++){
    int e = le[k];
    acc += vals[e] * bf(x[((size_t)b*Vin + (size_t)cols[e])*C + c]);
  }
  out[i] = fb(acc);
}

// ---- encoder linear: z[f] = b[f] + sum_{k<5120} x[k]*W[f,k] ----
__global__ void enc_lin_k(const u16* __restrict__ x, const float* __restrict__ W,
                          const float* __restrict__ b, float* __restrict__ z){
  int f = threadIdx.x;   // 64 threads
  const ushort4* x4 = (const ushort4*)x;
  const float4* w4 = (const float4*)(W + f*5120);
  float acc = b[f];
  for (int k=0;k<1280;k++){
    ushort4 xv = x4[k]; float4 wv = w4[k];
    acc += bf(xv.x)*wv.x + bf(xv.y)*wv.y + bf(xv.z)*wv.z + bf(xv.w)*wv.w;
  }
  z[f] = acc;
}

// ---- concat audio_emb(32,64) + z(64) -> h0(32,128) ----
__global__ void concat_k(const float* __restrict__ aemb, const float* __restrict__ z,
                         float* __restrict__ h0){
  int i = blockIdx.x*blockDim.x + threadIdx.x;
  if (i >= 32*128) return;
  int t = i >> 7, j = i & 127;
  h0[i] = (j < 64) ? aemb[t*64 + j] : z[j-64];
}

// ---- 3-layer bidirectional LSTM, seq=32, H=32, single block ----
__global__ void __launch_bounds__(256) lstm3_k(
    const float* __restrict__ h0,
    const float* __restrict__ l0_Wih, const float* __restrict__ l0_Whh,
    const float* __restrict__ l0_bih, const float* __restrict__ l0_bhh,
    const float* __restrict__ l12_Wih, const float* __restrict__ l12_Whh,
    const float* __restrict__ l12_bih, const float* __restrict__ l12_bhh,
    float* __restrict__ latent){
  __shared__ __align__(16) float xbuf[32*128];
  __shared__ __align__(16) float obuf[32*64];
  __shared__ __align__(16) float hs[2][32];
  __shared__ __align__(16) float cs[2][32];
  __shared__ __align__(16) float gs[2][128];
  int t = threadIdx.x;
  int dir = t >> 7, j = t & 127;
  for (int i=t;i<32*128;i+=256) xbuf[i]=h0[i];

  for (int layer=0; layer<3; layer++){
    int in_dim = (layer==0) ? 128 : 64;
    const float *Wih,*Whh,*bih,*bhh;
    if (layer==0){
      Wih=l0_Wih + dir*128*128; Whh=l0_Whh + dir*128*32;
      bih=l0_bih + dir*128;     bhh=l0_bhh + dir*128;
    } else {
      int m = (layer-1)*2 + dir;
      Wih=l12_Wih + m*128*64; Whh=l12_Whh + m*128*32;
      bih=l12_bih + m*128;    bhh=l12_bhh + m*128;
    }
    if (j < 32){ hs[dir][j]=0.f; cs[dir][j]=0.f; }
    float bias = bih[j] + bhh[j];
    const float4* w4  = (const float4*)(Wih + j*in_dim);
    const float4* wh4 = (const float4*)(Whh + j*32);
    __syncthreads();

    for (int s=0;s<32;s++){
      int tx = dir ? (31-s) : s;
      const float4* x4 = (const float4*)(xbuf + tx*in_dim);
      float acc = bias;
      for (int k=0;k<in_dim/4;k++){
        float4 xv=x4[k]; float4 wv=w4[k];
        acc += xv.x*wv.x+xv.y*wv.y+xv.z*wv.z+xv.w*wv.w;
      }
      const float4* h4 = (const float4*)(hs[dir]);
      #pragma unroll
      for (int k=0;k<8;k++){
        float4 hv=h4[k]; float4 wv=wh4[k];
        acc += hv.x*wv.x+hv.y*wv.y+hv.z*wv.z+hv.w*wv.w;
      }
      gs[dir][j] = acc;
      __syncthreads();
      if (j < 32){
        float ig = 1.f/(1.f+expf(-gs[dir][j]));
        float fg = 1.f/(1.f+expf(-gs[dir][32+j]));
        float gg = tanhf(gs[dir][64+j]);
        float og = 1.f/(1.f+expf(-gs[dir][96+j]));
        float cn = fg*cs[dir][j] + ig*gg;
        float hn = og*tanhf(cn);
        cs[dir][j]=cn; hs[dir][j]=hn;
        obuf[tx*64 + dir*32 + j] = hn;
      }
      __syncthreads();
    }
    for (int i=t;i<32*64;i+=256) xbuf[i]=obuf[i];
    __syncthreads();
  }
  for (int i=t;i<32*64;i+=256) latent[i]=obuf[i];
}

// ---- decoder linear: y[t,r] = b[r] + sum_{k<64} latent[t,k]*W[r,k] -> bf16 ----
__global__ void dec_lin_k(const float* __restrict__ latent, const float* __restrict__ W,
                          const float* __restrict__ b, u16* __restrict__ y){
  int i = blockIdx.x*blockDim.x + threadIdx.x;
  if (i >= 32*5120) return;
  int r = i % 5120, t = i / 5120;
  const float4* x4 = (const float4*)(latent + t*64);
  const float4* w4 = (const float4*)(W + (size_t)r*64);
  float acc = b[r];
  #pragma unroll
  for (int k=0;k<16;k++){
    float4 xv=x4[k]; float4 wv=w4[k];
    acc += xv.x*wv.x+xv.y*wv.y+xv.z*wv.z+xv.w*wv.w;
  }
  y[i] = fb(acc);
}

// ---- final conv (OC=3, IC=32, no ELU) + actor residual -> f32 out ----
// one thread per (b,v); W (3x288) staged in LDS (broadcast reads)
__global__ void final_k(const u16* __restrict__ x, const int* __restrict__ idx,
                        const float* __restrict__ W, const float* __restrict__ bias,
                        const float* __restrict__ actor, float* __restrict__ out){
  __shared__ float Wsm[3*288];
  __shared__ float bsm[3];
  int t = threadIdx.x;
  for (int i=t;i<864;i+=256) Wsm[i]=W[i];
  if (t<3) bsm[t]=bias[t];
  __syncthreads();
  int g = blockIdx.x*256 + t;
  if (g >= 32*5023) return;
  int v = g % 5023, b = g / 5023;
  const u16* xb = x + (size_t)b*5023*32;
  const int* vix = idx + v*9;
  float a0=bsm[0], a1=bsm[1], a2=bsm[2];
  for (int s=0;s<9;s++){
    const ushort4* xr = (const ushort4*)(xb + (size_t)vix[s]*32);
    #pragma unroll
    for (int k=0;k<8;k++){
      ushort4 xv = xr[k];
      float x0=bf(xv.x), x1=bf(xv.y), x2=bf(xv.z), x3=bf(xv.w);
      int kk = s*32 + k*4;
      a0 += x0*Wsm[kk] + x1*Wsm[kk+1] + x2*Wsm[kk+2] + x3*Wsm[kk+3];
      a1 += x0*Wsm[288+kk] + x1*Wsm[288+kk+1] + x2*Wsm[288+kk+2] + x3*Wsm[288+kk+3];
      a2 += x0*Wsm[576+kk] + x1*Wsm[576+kk+1] + x2*Wsm[576+kk+2] + x3*Wsm[576+kk+3];
    }
  }
  out[(size_t)g*3+0] = a0 + actor[v*3+0];
  out[(size_t)g*3+1] = a1 + actor[v*3+1];
  out[(size_t)g*3+2] = a2 + actor[v*3+2];
}

extern "C" void kernel_launch(void* const* d_in, const int* in_sizes, int n_in,
                              void* d_out, int out_size, void* d_ws, size_t ws_size,
                              hipStream_t stream){
  (void)in_sizes; (void)n_in; (void)out_size; (void)ws_size;

  const float* audio = (const float*)d_in[0];
  const float* actor = (const float*)d_in[2];
  const int* sp[4]   = {(const int*)d_in[3],(const int*)d_in[4],(const int*)d_in[5],(const int*)d_in[6]};
  const int* drows[4]; const int* dcols[4]; const float* dvals[4];
  for (int i=0;i<4;i++){ drows[i]=(const int*)d_in[7+3*i]; dcols[i]=(const int*)d_in[8+3*i]; dvals[i]=(const float*)d_in[9+3*i]; }
  const int* urows[4]; const int* ucols[4]; const float* uvals[4];
  for (int i=0;i<4;i++){ urows[i]=(const int*)d_in[19+3*i]; ucols[i]=(const int*)d_in[20+3*i]; uvals[i]=(const float*)d_in[21+3*i]; }
  const float* encW[4]={(const float*)d_in[31],(const float*)d_in[33],(const float*)d_in[35],(const float*)d_in[37]};
  const float* encB[4]={(const float*)d_in[32],(const float*)d_in[34],(const float*)d_in[36],(const float*)d_in[38]};
  const float* enc_lin_W=(const float*)d_in[39]; const float* enc_lin_b=(const float*)d_in[40];
  const float* dec_lin_W=(const float*)d_in[41]; const float* dec_lin_b=(const float*)d_in[42];
  const float* decW[5]={(const float*)d_in[43],(const float*)d_in[45],(const float*)d_in[47],(const float*)d_in[49],(const float*)d_in[51]};
  const float* decB[5]={(const float*)d_in[44],(const float*)d_in[46],(const float*)d_in[48],(const float*)d_in[50],(const float*)d_in[52]};
  const float* audW=(const float*)d_in[53]; const float* audB=(const float*)d_in[54];
  const float* l0_Wih=(const float*)d_in[55]; const float* l0_Whh=(const float*)d_in[56];
  const float* l0_bih=(const float*)d_in[57]; const float* l0_bhh=(const float*)d_in[58];
  const float* l12_Wih=(const float*)d_in[59]; const float* l12_Whh=(const float*)d_in[60];
  const float* l12_bih=(const float*)d_in[61]; const float* l12_bhh=(const float*)d_in[62];
  float* out = (float*)d_out;

  // ---- workspace layout (bytes) ----
  char* base = (char*)d_ws;
  u16* A  = (u16*)base;                          // 10,287,104 B
  u16* Bb = (u16*)(base + 10287104);             // 20,574,208 B
  u16* Ac = (u16*)(base + 30861312);             // actor bf16 (30,208 B pad)
  int* curBase = (int*)(base + 30891520);        // 8341 ints (33,408 B pad)
  int* lstBase = (int*)(base + 30924928);        // 533,824 ints
  float* sm = (float*)(base + 33060224);
  float* aemb   = sm;                 // 2048
  float* z      = sm + 2048;          // 64
  float* h0     = sm + 2048+64;       // 4096
  float* latent = sm + 2048+64+4096;  // 2048

  // pool bookkeeping: d0,d1,d2,d3,u0,u1,u2,u3
  const int pVout[8] = {1256,314,79,20,5023,1256,314,79};
  const int pNnz[8]  = {3768,942,237,60,15069,3768,942,237};
  Lists L; int curoff=0, lstoff=0, totnnz=0;
  const int* prow[8] = {drows[0],drows[1],drows[2],drows[3],urows[0],urows[1],urows[2],urows[3]};
  int curo[8], lsto[8];
  for (int k=0;k<8;k++){
    L.rows[k]=prow[k]; L.nnz[k]=pNnz[k];
    L.curoff[k]=curoff; L.lstoff[k]=lstoff;
    curo[k]=curoff; lsto[k]=lstoff;
    curoff += pVout[k]; lstoff += pVout[k]*POOL_CAP; totnnz += pNnz[k];
  }
  hipMemsetAsync(curBase, 0, (size_t)curoff*4, stream);
  fill_all_k<<<CDIV(totnnz,256),256,0,stream>>>(L, curBase, lstBase, totnnz);

  // ---- audio path ----
  audio_emb_k<<<32,64,0,stream>>>(audio, audW, audB, aemb);

  // ---- encoder (B=1) ----
  cast_k<<<CDIV(15069,256),256,0,stream>>>(actor, Ac, 15069);
  conv3_k<<<CDIV(5023*32,256),256,0,stream>>>(Ac, sp[0], encW[0], encB[0], A, 5023, 32);
  pool_g_k<<<CDIV(1256*32,256),256,0,stream>>>(A, dcols[0], dvals[0], curBase+curo[0], lstBase+lsto[0], Bb, 1, 5023, 1256, 32);
  conv_mfma<32,64><<<dim3(CDIV(1256,64),1),256,0,stream>>>(Bb, sp[1], encW[1], encB[1], A, 1256, 64, 1256);
  pool_g_k<<<CDIV(314*64,256),256,0,stream>>>(A, dcols[1], dvals[1], curBase+curo[1], lstBase+lsto[1], Bb, 1, 1256, 314, 64);
  conv_mfma<64,64><<<dim3(CDIV(314,64),2),256,0,stream>>>(Bb, sp[2], encW[2], encB[2], A, 314, 128, 314);
  pool_g_k<<<CDIV(79*128,256),256,0,stream>>>(A, dcols[2], dvals[2], curBase+curo[2], lstBase+lsto[2], Bb, 1, 314, 79, 128);
  conv_mfma<128,64><<<dim3(CDIV(79,64),4),256,0,stream>>>(Bb, sp[3], encW[3], encB[3], A, 79, 256, 79);
  pool_g_k<<<CDIV(20*256,256),256,0,stream>>>(A, dcols[3], dvals[3], curBase+curo[3], lstBase+lsto[3], Bb, 1, 79, 20, 256);

  enc_lin_k<<<1,64,0,stream>>>(Bb, enc_lin_W, enc_lin_b, z);
  concat_k<<<CDIV(32*128,256),256,0,stream>>>(aemb, z, h0);

  // ---- LSTM (serial, single block) ----
  lstm3_k<<<1,256,0,stream>>>(h0, l0_Wih, l0_Whh, l0_bih, l0_bhh,
                              l12_Wih, l12_Whh, l12_bih, l12_bhh, latent);

  // ---- decoder (B=32) ----
  dec_lin_k<<<CDIV(32*5120,256),256,0,stream>>>(latent, dec_lin_W, dec_lin_b, A); // (32,20,256)

  // j=3: up-pool u3 (20->79,C=256), conv IC=256 OC=256
  pool_g_k<<<CDIV(32*79*256,256),256,0,stream>>>(A, ucols[3], uvals[3], curBase+curo[7], lstBase+lsto[7], Bb, 32, 20, 79, 256);
  conv_mfma<256,64><<<dim3(CDIV(2528,64),4),256,0,stream>>>(Bb, sp[3], decW[0], decB[0], A, 79, 256, 2528);

  // j=2: up-pool u2 (79->314,C=256), conv IC=256 OC=128
  pool_g_k<<<CDIV(32*314*256,256),256,0,stream>>>(A, ucols[2], uvals[2], curBase+curo[6], lstBase+lsto[6], Bb, 32, 79, 314, 256);
  conv_mfma<256,64><<<dim3(CDIV(10048,64),2),256,0,stream>>>(Bb, sp[2], decW[1], decB[1], A, 314, 128, 10048);

  // j=1: up-pool u1 (314->1256,C=128), conv IC=128 OC=64
  pool_g_k<<<CDIV(32*1256*128,256),256,0,stream>>>(A, ucols[1], uvals[1], curBase+curo[5], lstBase+lsto[5], Bb, 32, 314, 1256, 128);
  conv_mfma<128,64><<<dim3(CDIV(40192,64),1),256,0,stream>>>(Bb, sp[1], decW[2], decB[2], A, 1256, 64, 40192);

  // j=0: up-pool u0 (1256->5023,C=64), conv IC=64 OC=32
  pool_g_k<<<CDIV(32*5023*64,256),256,0,stream>>>(A, ucols[0], uvals[0], curBase+curo[4], lstBase+lsto[4], Bb, 32, 1256, 5023, 64);
  conv_mfma<64,32><<<dim3(CDIV(160736,64),1),256,0,stream>>>(Bb, sp[0], decW[3], decB[3], A, 5023, 32, 160736);

  // final conv (288->3) + actor residual -> f32 out
  final_k<<<CDIV(32*5023,256),256,0,stream>>>(A, sp[0], decW[4], decB[4], actor, out);
}

// Round 5
// 869.319 us; speedup vs baseline: 6.8415x; 1.3104x over previous
//
#include <hip/hip_runtime.h>
#include <cstdint>
#include <cstddef>

// SpiralAutoencoder forward, MI355X gfx950.
// Inputs f32, indices i32, output f32. Internal activations bf16, fp32 accum.
// Spiral convs = MFMA bf16 GEMM (16x16x32); LSTM = register-resident weights.
// Pools = gather via device-built capped per-row edge lists (fused builder).

typedef unsigned short u16;
typedef __attribute__((ext_vector_type(8))) short short8;
typedef __attribute__((ext_vector_type(4))) float float4v;
#define CDIV(a,b) (((a)+(b)-1)/(b))
#define POOL_CAP 64

__device__ __forceinline__ float bf(u16 u){ return __uint_as_float(((unsigned)u)<<16); }
__device__ __forceinline__ u16 fb(float x){
  unsigned u = __float_as_uint(x);
  unsigned r = u + 0x7fffu + ((u>>16)&1u);   // RNE
  return (u16)(r>>16);
}

// ---- f32 -> bf16 cast ----
__global__ void cast_k(const float* __restrict__ in, u16* __restrict__ out, int n){
  int i = blockIdx.x*blockDim.x + threadIdx.x;
  if (i < n) out[i] = fb(in[i]);
}

// ---- audio embedding: (32,1536) @ (64,1536)^T + b -> (32,64) f32 ----
__global__ void audio_emb_k(const float* __restrict__ ah, const float* __restrict__ W,
                            const float* __restrict__ b, float* __restrict__ out){
  int t = blockIdx.x, f = threadIdx.x;      // 32 blocks x 64 threads
  const float4* x4 = (const float4*)(ah + t*1536);
  const float4* w4 = (const float4*)(W + f*1536);
  float acc = b[f];
  for (int k=0;k<384;k++){
    float4 xv = x4[k], wv = w4[k];
    acc += xv.x*wv.x + xv.y*wv.y + xv.z*wv.z + xv.w*wv.w;
  }
  out[t*64+f] = acc;
}

// ---- scalar spiral conv for IC=3 (encoder stage 0) ----
__global__ void conv3_k(const u16* __restrict__ x, const int* __restrict__ idx,
                        const float* __restrict__ W, const float* __restrict__ bias,
                        u16* __restrict__ out, int V, int OC){
  int i = blockIdx.x*blockDim.x + threadIdx.x;
  if (i >= V*OC) return;
  int o = i % OC; int v = i / OC;
  const float* wrow = W + (size_t)o*27;
  const int* vix = idx + v*9;
  float acc = bias[o];
  for (int s=0;s<9;s++){
    const u16* xr = x + (size_t)vix[s]*3;
    acc += bf(xr[0])*wrow[s*3] + bf(xr[1])*wrow[s*3+1] + bf(xr[2])*wrow[s*3+2];
  }
  if (acc < 0.f) acc = expm1f(acc);
  out[i] = fb(acc);
}

// ---- MFMA spiral conv: out[m,o], m=b*V+v, K=9*IC, gathered A, W cast bf16 ----
// BM in {64,128}, BN in {32,64}, BK=32. One 32-chunk == one spiral entry.
template<int IC, int BN, int BM>
__global__ void __launch_bounds__(256) conv_mfma(
    const u16* __restrict__ x, const int* __restrict__ idx,
    const float* __restrict__ W, const float* __restrict__ bias,
    u16* __restrict__ out, int V, int OC, int M){
  constexpr int K = 9*IC;
  constexpr int NT = BN/16;
  constexpr int MT = BM/64;               // m-frags per wave
  constexpr int LOG2 = (IC==32?5: IC==64?6: IC==128?7:8);
  constexpr int AST = 40;                 // LDS row stride (u16): 32 data + 8 pad
  __shared__ u16 Asm[BM*AST];
  __shared__ u16 Bsm[BN*AST];
  __shared__ int rowB[BM], rowV[BM];
  int t = threadIdx.x;
  int m0 = blockIdx.x*BM;
  int o0 = blockIdx.y*BN;
  if (t < BM){
    int mg = m0 + t;
    if (mg < M){ int b = mg / V; rowB[t] = b; rowV[t] = mg - b*V; }
    else rowB[t] = -1;
  }
  int lane = t & 63, wave = t >> 6;
  int quad = lane >> 4, col = lane & 15;
  float4v acc[MT][NT];
  #pragma unroll
  for (int mi=0;mi<MT;mi++)
    #pragma unroll
    for (int nt=0;nt<NT;nt++) acc[mi][nt] = (float4v)0.f;

  for (int kc = 0; kc < K/32; ++kc){
    int s  = (kc*32) >> LOG2;
    int c0 = (kc*32) & (IC-1);
    __syncthreads();
    #pragma unroll
    for (int rpt=0; rpt<MT; ++rpt){   // A tile: BM rows x 32 bf16
      int seg = t + 256*rpt;
      int arow = seg >> 2, aq = seg & 3;
      int b = rowB[arow];
      uint4 val = {0u,0u,0u,0u};
      if (b >= 0){
        int ix = idx[rowV[arow]*9 + s];
        val = *(const uint4*)(x + ((size_t)b*V + ix)*IC + c0 + aq*8);
      }
      *(uint4*)&Asm[arow*AST + aq*8] = val;
    }
    if (t < BN*4){ // B tile: BN rows of W, f32 -> bf16
      int br = t >> 2, bq = t & 3;
      const float* wsrc = W + (size_t)(o0+br)*K + kc*32 + bq*8;
      float4 w0 = *(const float4*)wsrc;
      float4 w1 = *(const float4*)(wsrc+4);
      alignas(16) u16 tmp[8] = {fb(w0.x),fb(w0.y),fb(w0.z),fb(w0.w),
                                fb(w1.x),fb(w1.y),fb(w1.z),fb(w1.w)};
      *(uint4*)&Bsm[br*AST + bq*8] = *(const uint4*)tmp;
    }
    __syncthreads();
    short8 a[MT];
    #pragma unroll
    for (int mi=0;mi<MT;mi++)
      a[mi] = *(const short8*)&Asm[(wave*MT*16 + mi*16 + col)*AST + quad*8];
    #pragma unroll
    for (int nt=0; nt<NT; ++nt){
      short8 bfr = *(const short8*)&Bsm[(nt*16 + col)*AST + quad*8];
      #pragma unroll
      for (int mi=0;mi<MT;mi++)
        acc[mi][nt] = __builtin_amdgcn_mfma_f32_16x16x32_bf16(a[mi], bfr, acc[mi][nt], 0, 0, 0);
    }
  }
  // epilogue: D col=lane&15, row=quad*4+reg; bias+ELU -> bf16
  #pragma unroll
  for (int mi=0;mi<MT;mi++){
    #pragma unroll
    for (int nt=0; nt<NT; ++nt){
      int o = o0 + nt*16 + col;
      float bv = bias[o];
      #pragma unroll
      for (int r=0;r<4;r++){
        int mg = m0 + wave*MT*16 + mi*16 + quad*4 + r;
        if (mg < M){
          float val = acc[mi][nt][r] + bv;
          if (val < 0.f) val = expm1f(val);
          out[(size_t)mg*OC + o] = fb(val);
        }
      }
    }
  }
}

// ---- fused list builder for all 8 pool matrices ----
struct Lists {
  const int* rows[8];
  int nnz[8];
  int curoff[8];
  int lstoff[8];
};
__global__ void fill_all_k(Lists L, int* __restrict__ curBase, int* __restrict__ lstBase, int total){
  int i = blockIdx.x*blockDim.x + threadIdx.x;
  if (i >= total) return;
  int off = i, k = 0;
  while (off >= L.nnz[k]){ off -= L.nnz[k]; k++; }
  int r = L.rows[k][off];
  int p = atomicAdd(curBase + L.curoff[k] + r, 1);
  if (p < POOL_CAP) lstBase[L.lstoff[k] + r*POOL_CAP + p] = off;
}

// ---- pool gather, 4 channels/thread: out[b,r,c]=sum vals[e]*x[b,cols[e],c] ----
__global__ void pool_g4_k(const u16* __restrict__ x, const int* __restrict__ cols,
                          const float* __restrict__ vals, const int* __restrict__ cur,
                          const int* __restrict__ lst, u16* __restrict__ out,
                          int B, int Vin, int Vout, int C){
  int C4 = C >> 2;
  int total = B*Vout*C4;
  int i = blockIdx.x*blockDim.x + threadIdx.x;
  if (i >= total) return;
  int c4 = i % C4; int tt = i / C4; int r = tt % Vout; int b = tt / Vout;
  int deg = cur[r]; if (deg > POOL_CAP) deg = POOL_CAP;
  const int* le = lst + r*POOL_CAP;
  float a0=0.f,a1=0.f,a2=0.f,a3=0.f;
  for (int k=0;k<deg;k++){
    int e = le[k];
    float v = vals[e];
    ushort4 xv = *(const ushort4*)(x + ((size_t)b*Vin + (size_t)cols[e])*C + c4*4);
    a0 += v*bf(xv.x); a1 += v*bf(xv.y); a2 += v*bf(xv.z); a3 += v*bf(xv.w);
  }
  ushort4 o; o.x=fb(a0); o.y=fb(a1); o.z=fb(a2); o.w=fb(a3);
  *(ushort4*)(out + ((size_t)b*Vout + (size_t)r)*C + c4*4) = o;
}

// ---- encoder linear: z[f] = b[f] + sum_{k<5120} x[k]*W[f,k] ----
__global__ void enc_lin_k(const u16* __restrict__ x, const float* __restrict__ W,
                          const float* __restrict__ b, float* __restrict__ z){
  int f = threadIdx.x;   // 64 threads
  const ushort4* x4 = (const ushort4*)x;
  const float4* w4 = (const float4*)(W + f*5120);
  float acc = b[f];
  for (int k=0;k<1280;k++){
    ushort4 xv = x4[k]; float4 wv = w4[k];
    acc += bf(xv.x)*wv.x + bf(xv.y)*wv.y + bf(xv.z)*wv.z + bf(xv.w)*wv.w;
  }
  z[f] = acc;
}

// ---- concat audio_emb(32,64) + z(64) -> h0(32,128) ----
__global__ void concat_k(const float* __restrict__ aemb, const float* __restrict__ z,
                         float* __restrict__ h0){
  int i = blockIdx.x*blockDim.x + threadIdx.x;
  if (i >= 32*128) return;
  int t = i >> 7, j = i & 127;
  h0[i] = (j < 64) ? aemb[t*64 + j] : z[j-64];
}

// ---- LSTM: one bidirectional layer with register-resident bf16-packed weights ----
__device__ __forceinline__ float sigm(float x){ return 1.f/(1.f+__expf(-x)); }
__device__ __forceinline__ float tanhfast(float x){ return 1.f - 2.f/(__expf(2.f*x)+1.f); }

template<int IN_DIM>
__device__ __forceinline__ void lstm_layer(
    int j, bool rev,
    const float* __restrict__ Wih, const float* __restrict__ Whh,
    const float* __restrict__ bih, const float* __restrict__ bhh,
    const float* __restrict__ xbuf, float* __restrict__ obuf_d,
    float* __restrict__ hsd, float* __restrict__ csd, float* __restrict__ gsd){
  unsigned wih[IN_DIM/2];
  #pragma unroll
  for (int k=0;k<IN_DIM/2;k++){
    float2 w = *(const float2*)&Wih[(size_t)j*IN_DIM + 2*k];
    wih[k] = ((unsigned)fb(w.x)) | (((unsigned)fb(w.y))<<16);
  }
  unsigned whh[16];
  #pragma unroll
  for (int k=0;k<16;k++){
    float2 w = *(const float2*)&Whh[(size_t)j*32 + 2*k];
    whh[k] = ((unsigned)fb(w.x)) | (((unsigned)fb(w.y))<<16);
  }
  float bias = bih[j] + bhh[j];
  if (j < 32){ hsd[j]=0.f; csd[j]=0.f; }
  __syncthreads();

  for (int s=0;s<32;s++){
    int tx = rev ? (31-s) : s;
    float acc = bias;
    const float2* x2 = (const float2*)&xbuf[tx*IN_DIM];
    #pragma unroll
    for (int k=0;k<IN_DIM/2;k++){
      unsigned u = wih[k]; float2 xv = x2[k];
      acc = fmaf(xv.x, __uint_as_float(u<<16), acc);
      acc = fmaf(xv.y, __uint_as_float(u & 0xffff0000u), acc);
    }
    const float2* h2 = (const float2*)hsd;
    #pragma unroll
    for (int k=0;k<16;k++){
      unsigned u = whh[k]; float2 hv = h2[k];
      acc = fmaf(hv.x, __uint_as_float(u<<16), acc);
      acc = fmaf(hv.y, __uint_as_float(u & 0xffff0000u), acc);
    }
    gsd[j] = acc;
    __syncthreads();
    if (j < 32){
      float ig = sigm(gsd[j]);
      float fg = sigm(gsd[32+j]);
      float gg = tanhfast(gsd[64+j]);
      float og = sigm(gsd[96+j]);
      float cn = fg*csd[j] + ig*gg;
      float hn = og*tanhfast(cn);
      csd[j]=cn; hsd[j]=hn;
      obuf_d[tx*64 + j] = hn;
    }
    __syncthreads();
  }
}

__global__ void __launch_bounds__(256) lstm3_k(
    const float* __restrict__ h0,
    const float* __restrict__ l0_Wih, const float* __restrict__ l0_Whh,
    const float* __restrict__ l0_bih, const float* __restrict__ l0_bhh,
    const float* __restrict__ l12_Wih, const float* __restrict__ l12_Whh,
    const float* __restrict__ l12_bih, const float* __restrict__ l12_bhh,
    float* __restrict__ latent){
  __shared__ __align__(16) float xbuf[32*128];
  __shared__ __align__(16) float obuf[32*64];
  __shared__ __align__(16) float hs[2][32];
  __shared__ __align__(16) float cs[2][32];
  __shared__ __align__(16) float gs[2][128];
  int t = threadIdx.x;
  int dir = t >> 7, j = t & 127;
  bool rev = (dir == 1);
  for (int i=t;i<32*128;i+=256) xbuf[i]=h0[i];
  __syncthreads();

  lstm_layer<128>(j, rev, l0_Wih + dir*128*128, l0_Whh + dir*128*32,
                  l0_bih + dir*128, l0_bhh + dir*128,
                  xbuf, obuf + dir*32, hs[dir], cs[dir], gs[dir]);
  __syncthreads();
  for (int i=t;i<32*64;i+=256) xbuf[i]=obuf[i];
  __syncthreads();

  for (int layer=1; layer<3; layer++){
    int m = (layer-1)*2 + dir;
    lstm_layer<64>(j, rev, l12_Wih + m*128*64, l12_Whh + m*128*32,
                   l12_bih + m*128, l12_bhh + m*128,
                   xbuf, obuf + dir*32, hs[dir], cs[dir], gs[dir]);
    __syncthreads();
    for (int i=t;i<32*64;i+=256) xbuf[i]=obuf[i];
    __syncthreads();
  }
  for (int i=t;i<32*64;i+=256) latent[i]=obuf[i];
}

// ---- decoder linear: y[t,r] = b[r] + sum_{k<64} latent[t,k]*W[r,k] -> bf16 ----
__global__ void dec_lin_k(const float* __restrict__ latent, const float* __restrict__ W,
                          const float* __restrict__ b, u16* __restrict__ y){
  int i = blockIdx.x*blockDim.x + threadIdx.x;
  if (i >= 32*5120) return;
  int r = i % 5120, t = i / 5120;
  const float4* x4 = (const float4*)(latent + t*64);
  const float4* w4 = (const float4*)(W + (size_t)r*64);
  float acc = b[r];
  #pragma unroll
  for (int k=0;k<16;k++){
    float4 xv=x4[k]; float4 wv=w4[k];
    acc += xv.x*wv.x+xv.y*wv.y+xv.z*wv.z+xv.w*wv.w;
  }
  y[i] = fb(acc);
}

// ---- final conv (OC=3, IC=32, no ELU) + actor residual -> f32 out ----
__global__ void final_k(const u16* __restrict__ x, const int* __restrict__ idx,
                        const float* __restrict__ W, const float* __restrict__ bias,
                        const float* __restrict__ actor, float* __restrict__ out){
  __shared__ float Wsm[3*288];
  __shared__ float bsm[3];
  int t = threadIdx.x;
  for (int i=t;i<864;i+=256) Wsm[i]=W[i];
  if (t<3) bsm[t]=bias[t];
  __syncthreads();
  int g = blockIdx.x*256 + t;
  if (g >= 32*5023) return;
  int v = g % 5023, b = g / 5023;
  const u16* xb = x + (size_t)b*5023*32;
  const int* vix = idx + v*9;
  float a0=bsm[0], a1=bsm[1], a2=bsm[2];
  for (int s=0;s<9;s++){
    const ushort4* xr = (const ushort4*)(xb + (size_t)vix[s]*32);
    #pragma unroll
    for (int k=0;k<8;k++){
      ushort4 xv = xr[k];
      float x0=bf(xv.x), x1=bf(xv.y), x2=bf(xv.z), x3=bf(xv.w);
      int kk = s*32 + k*4;
      a0 += x0*Wsm[kk] + x1*Wsm[kk+1] + x2*Wsm[kk+2] + x3*Wsm[kk+3];
      a1 += x0*Wsm[288+kk] + x1*Wsm[288+kk+1] + x2*Wsm[288+kk+2] + x3*Wsm[288+kk+3];
      a2 += x0*Wsm[576+kk] + x1*Wsm[576+kk+1] + x2*Wsm[576+kk+2] + x3*Wsm[576+kk+3];
    }
  }
  out[(size_t)g*3+0] = a0 + actor[v*3+0];
  out[(size_t)g*3+1] = a1 + actor[v*3+1];
  out[(size_t)g*3+2] = a2 + actor[v*3+2];
}

extern "C" void kernel_launch(void* const* d_in, const int* in_sizes, int n_in,
                              void* d_out, int out_size, void* d_ws, size_t ws_size,
                              hipStream_t stream){
  (void)in_sizes; (void)n_in; (void)out_size; (void)ws_size;

  const float* audio = (const float*)d_in[0];
  const float* actor = (const float*)d_in[2];
  const int* sp[4]   = {(const int*)d_in[3],(const int*)d_in[4],(const int*)d_in[5],(const int*)d_in[6]};
  const int* drows[4]; const int* dcols[4]; const float* dvals[4];
  for (int i=0;i<4;i++){ drows[i]=(const int*)d_in[7+3*i]; dcols[i]=(const int*)d_in[8+3*i]; dvals[i]=(const float*)d_in[9+3*i]; }
  const int* urows[4]; const int* ucols[4]; const float* uvals[4];
  for (int i=0;i<4;i++){ urows[i]=(const int*)d_in[19+3*i]; ucols[i]=(const int*)d_in[20+3*i]; uvals[i]=(const float*)d_in[21+3*i]; }
  const float* encW[4]={(const float*)d_in[31],(const float*)d_in[33],(const float*)d_in[35],(const float*)d_in[37]};
  const float* encB[4]={(const float*)d_in[32],(const float*)d_in[34],(const float*)d_in[36],(const float*)d_in[38]};
  const float* enc_lin_W=(const float*)d_in[39]; const float* enc_lin_b=(const float*)d_in[40];
  const float* dec_lin_W=(const float*)d_in[41]; const float* dec_lin_b=(const float*)d_in[42];
  const float* decW[5]={(const float*)d_in[43],(const float*)d_in[45],(const float*)d_in[47],(const float*)d_in[49],(const float*)d_in[51]};
  const float* decB[5]={(const float*)d_in[44],(const float*)d_in[46],(const float*)d_in[48],(const float*)d_in[50],(const float*)d_in[52]};
  const float* audW=(const float*)d_in[53]; const float* audB=(const float*)d_in[54];
  const float* l0_Wih=(const float*)d_in[55]; const float* l0_Whh=(const float*)d_in[56];
  const float* l0_bih=(const float*)d_in[57]; const float* l0_bhh=(const float*)d_in[58];
  const float* l12_Wih=(const float*)d_in[59]; const float* l12_Whh=(const float*)d_in[60];
  const float* l12_bih=(const float*)d_in[61]; const float* l12_bhh=(const float*)d_in[62];
  float* out = (float*)d_out;

  // ---- workspace layout (bytes) ----
  char* base = (char*)d_ws;
  u16* A  = (u16*)base;                          // 10,287,104 B
  u16* Bb = (u16*)(base + 10287104);             // 20,574,208 B
  u16* Ac = (u16*)(base + 30861312);             // actor bf16 (30,208 B pad)
  int* curBase = (int*)(base + 30891520);        // 8341 ints (33,408 B pad)
  int* lstBase = (int*)(base + 30924928);        // 533,824 ints
  float* sm = (float*)(base + 33060224);
  float* aemb   = sm;                 // 2048
  float* z      = sm + 2048;          // 64
  float* h0     = sm + 2048+64;       // 4096
  float* latent = sm + 2048+64+4096;  // 2048

  // pool bookkeeping: d0,d1,d2,d3,u0,u1,u2,u3
  const int pVout[8] = {1256,314,79,20,5023,1256,314,79};
  const int pNnz[8]  = {3768,942,237,60,15069,3768,942,237};
  Lists L; int curoff=0, lstoff=0, totnnz=0;
  const int* prow[8] = {drows[0],drows[1],drows[2],drows[3],urows[0],urows[1],urows[2],urows[3]};
  int curo[8], lsto[8];
  for (int k=0;k<8;k++){
    L.rows[k]=prow[k]; L.nnz[k]=pNnz[k];
    L.curoff[k]=curoff; L.lstoff[k]=lstoff;
    curo[k]=curoff; lsto[k]=lstoff;
    curoff += pVout[k]; lstoff += pVout[k]*POOL_CAP; totnnz += pNnz[k];
  }
  hipMemsetAsync(curBase, 0, (size_t)curoff*4, stream);
  fill_all_k<<<CDIV(totnnz,256),256,0,stream>>>(L, curBase, lstBase, totnnz);

  // ---- audio path ----
  audio_emb_k<<<32,64,0,stream>>>(audio, audW, audB, aemb);

  // ---- encoder (B=1) ----
  cast_k<<<CDIV(15069,256),256,0,stream>>>(actor, Ac, 15069);
  conv3_k<<<CDIV(5023*32,256),256,0,stream>>>(Ac, sp[0], encW[0], encB[0], A, 5023, 32);
  pool_g4_k<<<CDIV(1256*8,256),256,0,stream>>>(A, dcols[0], dvals[0], curBase+curo[0], lstBase+lsto[0], Bb, 1, 5023, 1256, 32);
  conv_mfma<32,64,64><<<dim3(CDIV(1256,64),1),256,0,stream>>>(Bb, sp[1], encW[1], encB[1], A, 1256, 64, 1256);
  pool_g4_k<<<CDIV(314*16,256),256,0,stream>>>(A, dcols[1], dvals[1], curBase+curo[1], lstBase+lsto[1], Bb, 1, 1256, 314, 64);
  conv_mfma<64,64,64><<<dim3(CDIV(314,64),2),256,0,stream>>>(Bb, sp[2], encW[2], encB[2], A, 314, 128, 314);
  pool_g4_k<<<CDIV(79*32,256),256,0,stream>>>(A, dcols[2], dvals[2], curBase+curo[2], lstBase+lsto[2], Bb, 1, 314, 79, 128);
  conv_mfma<128,64,64><<<dim3(CDIV(79,64),4),256,0,stream>>>(Bb, sp[3], encW[3], encB[3], A, 79, 256, 79);
  pool_g4_k<<<CDIV(20*64,256),256,0,stream>>>(A, dcols[3], dvals[3], curBase+curo[3], lstBase+lsto[3], Bb, 1, 79, 20, 256);

  enc_lin_k<<<1,64,0,stream>>>(Bb, enc_lin_W, enc_lin_b, z);
  concat_k<<<CDIV(32*128,256),256,0,stream>>>(aemb, z, h0);

  // ---- LSTM (serial, single block, reg-resident weights) ----
  lstm3_k<<<1,256,0,stream>>>(h0, l0_Wih, l0_Whh, l0_bih, l0_bhh,
                              l12_Wih, l12_Whh, l12_bih, l12_bhh, latent);

  // ---- decoder (B=32) ----
  dec_lin_k<<<CDIV(32*5120,256),256,0,stream>>>(latent, dec_lin_W, dec_lin_b, A); // (32,20,256)

  // j=3: up-pool u3 (20->79,C=256), conv IC=256 OC=256
  pool_g4_k<<<CDIV(32*79*64,256),256,0,stream>>>(A, ucols[3], uvals[3], curBase+curo[7], lstBase+lsto[7], Bb, 32, 20, 79, 256);
  conv_mfma<256,64,64><<<dim3(CDIV(2528,64),4),256,0,stream>>>(Bb, sp[3], decW[0], decB[0], A, 79, 256, 2528);

  // j=2: up-pool u2 (79->314,C=256), conv IC=256 OC=128
  pool_g4_k<<<CDIV(32*314*64,256),256,0,stream>>>(A, ucols[2], uvals[2], curBase+curo[6], lstBase+lsto[6], Bb, 32, 79, 314, 256);
  conv_mfma<256,64,128><<<dim3(CDIV(10048,128),2),256,0,stream>>>(Bb, sp[2], decW[1], decB[1], A, 314, 128, 10048);

  // j=1: up-pool u1 (314->1256,C=128), conv IC=128 OC=64
  pool_g4_k<<<CDIV(32*1256*32,256),256,0,stream>>>(A, ucols[1], uvals[1], curBase+curo[5], lstBase+lsto[5], Bb, 32, 314, 1256, 128);
  conv_mfma<128,64,128><<<dim3(CDIV(40192,128),1),256,0,stream>>>(Bb, sp[1], decW[2], decB[2], A, 1256, 64, 40192);

  // j=0: up-pool u0 (1256->5023,C=64), conv IC=64 OC=32
  pool_g4_k<<<CDIV(32*5023*16,256),256,0,stream>>>(A, ucols[0], uvals[0], curBase+curo[4], lstBase+lsto[4], Bb, 32, 1256, 5023, 64);
  conv_mfma<64,32,128><<<dim3(CDIV(160736,128),1),256,0,stream>>>(Bb, sp[0], decW[3], decB[3], A, 5023, 32, 160736);

  // final conv (288->3) + actor residual -> f32 out
  final_k<<<CDIV(32*5023,256),256,0,stream>>>(A, sp[0], decW[4], decB[4], actor, out);
}

// Round 6
// 771.010 us; speedup vs baseline: 7.7138x; 1.1275x over previous
//
#include <hip/hip_runtime.h>
#include <cstdint>
#include <cstddef>

// SpiralAutoencoder forward, MI355X gfx950.
// Inputs f32, indices i32, output f32. Internal activations bf16, fp32 accum.
// Spiral convs = MFMA bf16 GEMM (16x16x32); LSTM = register-resident weights.
// Pools = gather via device-built capped per-row edge lists (fused builder).
// Small linears = split-K wave-reduced (never single-wave serial dots).

typedef unsigned short u16;
typedef __attribute__((ext_vector_type(8))) short short8;
typedef __attribute__((ext_vector_type(4))) float float4v;
#define CDIV(a,b) (((a)+(b)-1)/(b))
#define POOL_CAP 64

__device__ __forceinline__ float bf(u16 u){ return __uint_as_float(((unsigned)u)<<16); }
__device__ __forceinline__ u16 fb(float x){
  unsigned u = __float_as_uint(x);
  unsigned r = u + 0x7fffu + ((u>>16)&1u);   // RNE
  return (u16)(r>>16);
}

// ---- audio embedding: (32,1536)@(64,1536)^T + b -> h0[t*128+f] (f<64) ----
// 32 blocks x 256 threads; 4 lanes per output feature, shuffle-reduce.
__global__ void audio_emb_k(const float* __restrict__ ah, const float* __restrict__ W,
                            const float* __restrict__ b, float* __restrict__ h0){
  int t = blockIdx.x;
  int f = threadIdx.x >> 2, sl = threadIdx.x & 3;
  const float4* x4 = (const float4*)(ah + t*1536);
  const float4* w4 = (const float4*)(W + f*1536);
  float acc = 0.f;
  for (int k=sl; k<384; k+=4){
    float4 xv = x4[k], wv = w4[k];
    acc += xv.x*wv.x + xv.y*wv.y + xv.z*wv.z + xv.w*wv.w;
  }
  acc += __shfl_down(acc, 2, 64);
  acc += __shfl_down(acc, 1, 64);
  if (sl == 0) h0[t*128 + f] = acc + b[f];
}

// ---- scalar spiral conv for IC=3 (encoder stage 0), reads f32 actor ----
__global__ void conv3_k(const float* __restrict__ x, const int* __restrict__ idx,
                        const float* __restrict__ W, const float* __restrict__ bias,
                        u16* __restrict__ out, int V, int OC){
  int i = blockIdx.x*blockDim.x + threadIdx.x;
  if (i >= V*OC) return;
  int o = i % OC; int v = i / OC;
  const float* wrow = W + (size_t)o*27;
  const int* vix = idx + v*9;
  float acc = bias[o];
  for (int s=0;s<9;s++){
    const float* xr = x + (size_t)vix[s]*3;
    acc += xr[0]*wrow[s*3] + xr[1]*wrow[s*3+1] + xr[2]*wrow[s*3+2];
  }
  if (acc < 0.f) acc = expm1f(acc);
  out[i] = fb(acc);
}

// ---- MFMA spiral conv: out[m,o], m=b*V+v, K=9*IC, gathered A, W cast bf16 ----
template<int IC, int BN, int BM>
__global__ void __launch_bounds__(256) conv_mfma(
    const u16* __restrict__ x, const int* __restrict__ idx,
    const float* __restrict__ W, const float* __restrict__ bias,
    u16* __restrict__ out, int V, int OC, int M){
  constexpr int K = 9*IC;
  constexpr int NT = BN/16;
  constexpr int MT = BM/64;
  constexpr int LOG2 = (IC==32?5: IC==64?6: IC==128?7:8);
  constexpr int AST = 40;                 // LDS row stride (u16): 32 data + 8 pad
  __shared__ u16 Asm[BM*AST];
  __shared__ u16 Bsm[BN*AST];
  __shared__ int rowB[BM], rowV[BM];
  int t = threadIdx.x;
  int m0 = blockIdx.x*BM;
  int o0 = blockIdx.y*BN;
  if (t < BM){
    int mg = m0 + t;
    if (mg < M){ int b = mg / V; rowB[t] = b; rowV[t] = mg - b*V; }
    else rowB[t] = -1;
  }
  int lane = t & 63, wave = t >> 6;
  int quad = lane >> 4, col = lane & 15;
  float4v acc[MT][NT];
  #pragma unroll
  for (int mi=0;mi<MT;mi++)
    #pragma unroll
    for (int nt=0;nt<NT;nt++) acc[mi][nt] = (float4v)0.f;

  for (int kc = 0; kc < K/32; ++kc){
    int s  = (kc*32) >> LOG2;
    int c0 = (kc*32) & (IC-1);
    __syncthreads();
    #pragma unroll
    for (int rpt=0; rpt<MT; ++rpt){   // A tile: BM rows x 32 bf16
      int seg = t + 256*rpt;
      int arow = seg >> 2, aq = seg & 3;
      int b = rowB[arow];
      uint4 val = {0u,0u,0u,0u};
      if (b >= 0){
        int ix = idx[rowV[arow]*9 + s];
        val = *(const uint4*)(x + ((size_t)b*V + ix)*IC + c0 + aq*8);
      }
      *(uint4*)&Asm[arow*AST + aq*8] = val;
    }
    if (t < BN*4){ // B tile: BN rows of W, f32 -> bf16
      int br = t >> 2, bq = t & 3;
      const float* wsrc = W + (size_t)(o0+br)*K + kc*32 + bq*8;
      float4 w0 = *(const float4*)wsrc;
      float4 w1 = *(const float4*)(wsrc+4);
      alignas(16) u16 tmp[8] = {fb(w0.x),fb(w0.y),fb(w0.z),fb(w0.w),
                                fb(w1.x),fb(w1.y),fb(w1.z),fb(w1.w)};
      *(uint4*)&Bsm[br*AST + bq*8] = *(const uint4*)tmp;
    }
    __syncthreads();
    short8 a[MT];
    #pragma unroll
    for (int mi=0;mi<MT;mi++)
      a[mi] = *(const short8*)&Asm[(wave*MT*16 + mi*16 + col)*AST + quad*8];
    #pragma unroll
    for (int nt=0; nt<NT; ++nt){
      short8 bfr = *(const short8*)&Bsm[(nt*16 + col)*AST + quad*8];
      #pragma unroll
      for (int mi=0;mi<MT;mi++)
        acc[mi][nt] = __builtin_amdgcn_mfma_f32_16x16x32_bf16(a[mi], bfr, acc[mi][nt], 0, 0, 0);
    }
  }
  #pragma unroll
  for (int mi=0;mi<MT;mi++){
    #pragma unroll
    for (int nt=0; nt<NT; ++nt){
      int o = o0 + nt*16 + col;
      float bv = bias[o];
      #pragma unroll
      for (int r=0;r<4;r++){
        int mg = m0 + wave*MT*16 + mi*16 + quad*4 + r;
        if (mg < M){
          float val = acc[mi][nt][r] + bv;
          if (val < 0.f) val = expm1f(val);
          out[(size_t)mg*OC + o] = fb(val);
        }
      }
    }
  }
}

// ---- fused list builder for all 8 pool matrices ----
struct Lists {
  const int* rows[8];
  int nnz[8];
  int curoff[8];
  int lstoff[8];
};
__global__ void fill_all_k(Lists L, int* __restrict__ curBase, int* __restrict__ lstBase, int total){
  int i = blockIdx.x*blockDim.x + threadIdx.x;
  if (i >= total) return;
  int off = i, k = 0;
  while (off >= L.nnz[k]){ off -= L.nnz[k]; k++; }
  int r = L.rows[k][off];
  int p = atomicAdd(curBase + L.curoff[k] + r, 1);
  if (p < POOL_CAP) lstBase[L.lstoff[k] + r*POOL_CAP + p] = off;
}

// ---- pool gather, 4 channels/thread ----
__global__ void pool_g4_k(const u16* __restrict__ x, const int* __restrict__ cols,
                          const float* __restrict__ vals, const int* __restrict__ cur,
                          const int* __restrict__ lst, u16* __restrict__ out,
                          int B, int Vin, int Vout, int C){
  int C4 = C >> 2;
  int total = B*Vout*C4;
  int i = blockIdx.x*blockDim.x + threadIdx.x;
  if (i >= total) return;
  int c4 = i % C4; int tt = i / C4; int r = tt % Vout; int b = tt / Vout;
  int deg = cur[r]; if (deg > POOL_CAP) deg = POOL_CAP;
  const int* le = lst + r*POOL_CAP;
  float a0=0.f,a1=0.f,a2=0.f,a3=0.f;
  for (int k=0;k<deg;k++){
    int e = le[k];
    float v = vals[e];
    ushort4 xv = *(const ushort4*)(x + ((size_t)b*Vin + (size_t)cols[e])*C + c4*4);
    a0 += v*bf(xv.x); a1 += v*bf(xv.y); a2 += v*bf(xv.z); a3 += v*bf(xv.w);
  }
  ushort4 o; o.x=fb(a0); o.y=fb(a1); o.z=fb(a2); o.w=fb(a3);
  *(ushort4*)(out + ((size_t)b*Vout + (size_t)r)*C + c4*4) = o;
}

// ---- encoder linear, split-K: z[f]=b[f]+sum_{k<5120} x[k]W[f,k];
// also broadcast z into h0[t*128+64+f] for all 32 frames ----
__global__ void __launch_bounds__(256) enc_lin_k(
    const u16* __restrict__ x, const float* __restrict__ W,
    const float* __restrict__ b, float* __restrict__ h0){
  int f = blockIdx.x;          // 64 blocks
  int t = threadIdx.x;         // 256
  const ushort4* x4 = (const ushort4*)x;
  const float4* w4 = (const float4*)(W + (size_t)f*5120);
  float acc = 0.f;
  for (int k=t; k<1280; k+=256){
    ushort4 xv = x4[k]; float4 wv = w4[k];
    acc += bf(xv.x)*wv.x + bf(xv.y)*wv.y + bf(xv.z)*wv.z + bf(xv.w)*wv.w;
  }
  #pragma unroll
  for (int off=32; off; off>>=1) acc += __shfl_down(acc, off, 64);
  __shared__ float red[4];
  if ((t & 63) == 0) red[t>>6] = acc;
  __syncthreads();
  if (t < 32){
    float zf = b[f] + red[0] + red[1] + red[2] + red[3];
    h0[t*128 + 64 + f] = zf;
  }
}

// ---- LSTM with register-resident bf16-packed weights ----
__device__ __forceinline__ float sigm(float x){ return 1.f/(1.f+__expf(-x)); }
__device__ __forceinline__ float tanhfast(float x){ return 1.f - 2.f/(__expf(2.f*x)+1.f); }

template<int IN_DIM>
__device__ __forceinline__ void lstm_layer(
    int j, bool rev,
    const float* __restrict__ Wih, const float* __restrict__ Whh,
    const float* __restrict__ bih, const float* __restrict__ bhh,
    const float* __restrict__ xbuf, float* __restrict__ obuf_d,
    float* __restrict__ hsd, float* __restrict__ csd, float* __restrict__ gsd){
  unsigned wih[IN_DIM/2];
  #pragma unroll
  for (int k=0;k<IN_DIM/2;k++){
    float2 w = *(const float2*)&Wih[(size_t)j*IN_DIM + 2*k];
    wih[k] = ((unsigned)fb(w.x)) | (((unsigned)fb(w.y))<<16);
  }
  unsigned whh[16];
  #pragma unroll
  for (int k=0;k<16;k++){
    float2 w = *(const float2*)&Whh[(size_t)j*32 + 2*k];
    whh[k] = ((unsigned)fb(w.x)) | (((unsigned)fb(w.y))<<16);
  }
  float bias = bih[j] + bhh[j];
  if (j < 32){ hsd[j]=0.f; csd[j]=0.f; }
  __syncthreads();

  for (int s=0;s<32;s++){
    int tx = rev ? (31-s) : s;
    float acc = bias;
    const float2* x2 = (const float2*)&xbuf[tx*IN_DIM];
    #pragma unroll
    for (int k=0;k<IN_DIM/2;k++){
      unsigned u = wih[k]; float2 xv = x2[k];
      acc = fmaf(xv.x, __uint_as_float(u<<16), acc);
      acc = fmaf(xv.y, __uint_as_float(u & 0xffff0000u), acc);
    }
    const float2* h2 = (const float2*)hsd;
    #pragma unroll
    for (int k=0;k<16;k++){
      unsigned u = whh[k]; float2 hv = h2[k];
      acc = fmaf(hv.x, __uint_as_float(u<<16), acc);
      acc = fmaf(hv.y, __uint_as_float(u & 0xffff0000u), acc);
    }
    gsd[j] = acc;
    __syncthreads();
    if (j < 32){
      float ig = sigm(gsd[j]);
      float fg = sigm(gsd[32+j]);
      float gg = tanhfast(gsd[64+j]);
      float og = sigm(gsd[96+j]);
      float cn = fg*csd[j] + ig*gg;
      float hn = og*tanhfast(cn);
      csd[j]=cn; hsd[j]=hn;
      obuf_d[tx*64 + j] = hn;
    }
    __syncthreads();
  }
}

__global__ void __launch_bounds__(256) lstm3_k(
    const float* __restrict__ h0,
    const float* __restrict__ l0_Wih, const float* __restrict__ l0_Whh,
    const float* __restrict__ l0_bih, const float* __restrict__ l0_bhh,
    const float* __restrict__ l12_Wih, const float* __restrict__ l12_Whh,
    const float* __restrict__ l12_bih, const float* __restrict__ l12_bhh,
    float* __restrict__ latent){
  __shared__ __align__(16) float xbuf[32*128];
  __shared__ __align__(16) float obuf[32*64];
  __shared__ __align__(16) float hs[2][32];
  __shared__ __align__(16) float cs[2][32];
  __shared__ __align__(16) float gs[2][128];
  int t = threadIdx.x;
  int dir = t >> 7, j = t & 127;
  bool rev = (dir == 1);
  for (int i=t;i<32*128;i+=256) xbuf[i]=h0[i];
  __syncthreads();

  lstm_layer<128>(j, rev, l0_Wih + dir*128*128, l0_Whh + dir*128*32,
                  l0_bih + dir*128, l0_bhh + dir*128,
                  xbuf, obuf + dir*32, hs[dir], cs[dir], gs[dir]);
  __syncthreads();
  for (int i=t;i<32*64;i+=256) xbuf[i]=obuf[i];
  __syncthreads();

  for (int layer=1; layer<3; layer++){
    int m = (layer-1)*2 + dir;
    lstm_layer<64>(j, rev, l12_Wih + m*128*64, l12_Whh + m*128*32,
                   l12_bih + m*128, l12_bhh + m*128,
                   xbuf, obuf + dir*32, hs[dir], cs[dir], gs[dir]);
    __syncthreads();
    for (int i=t;i<32*64;i+=256) xbuf[i]=obuf[i];
    __syncthreads();
  }
  for (int i=t;i<32*64;i+=256) latent[i]=obuf[i];
}

// ---- decoder linear: y[t,r] = b[r] + sum_{k<64} latent[t,k]*W[r,k] -> bf16 ----
__global__ void dec_lin_k(const float* __restrict__ latent, const float* __restrict__ W,
                          const float* __restrict__ b, u16* __restrict__ y){
  int i = blockIdx.x*blockDim.x + threadIdx.x;
  if (i >= 32*5120) return;
  int r = i % 5120, t = i / 5120;
  const float4* x4 = (const float4*)(latent + t*64);
  const float4* w4 = (const float4*)(W + (size_t)r*64);
  float acc = b[r];
  #pragma unroll
  for (int k=0;k<16;k++){
    float4 xv=x4[k]; float4 wv=w4[k];
    acc += xv.x*wv.x+xv.y*wv.y+xv.z*wv.z+xv.w*wv.w;
  }
  y[i] = fb(acc);
}

// ---- final conv (OC=3, IC=32, no ELU) + actor residual -> f32 out ----
__global__ void final_k(const u16* __restrict__ x, const int* __restrict__ idx,
                        const float* __restrict__ W, const float* __restrict__ bias,
                        const float* __restrict__ actor, float* __restrict__ out){
  __shared__ float Wsm[3*288];
  __shared__ float bsm[3];
  int t = threadIdx.x;
  for (int i=t;i<864;i+=256) Wsm[i]=W[i];
  if (t<3) bsm[t]=bias[t];
  __syncthreads();
  int g = blockIdx.x*256 + t;
  if (g >= 32*5023) return;
  int v = g % 5023, b = g / 5023;
  const u16* xb = x + (size_t)b*5023*32;
  const int* vix = idx + v*9;
  float a0=bsm[0], a1=bsm[1], a2=bsm[2];
  for (int s=0;s<9;s++){
    const ushort4* xr = (const ushort4*)(xb + (size_t)vix[s]*32);
    #pragma unroll
    for (int k=0;k<8;k++){
      ushort4 xv = xr[k];
      float x0=bf(xv.x), x1=bf(xv.y), x2=bf(xv.z), x3=bf(xv.w);
      int kk = s*32 + k*4;
      a0 += x0*Wsm[kk] + x1*Wsm[kk+1] + x2*Wsm[kk+2] + x3*Wsm[kk+3];
      a1 += x0*Wsm[288+kk] + x1*Wsm[288+kk+1] + x2*Wsm[288+kk+2] + x3*Wsm[288+kk+3];
      a2 += x0*Wsm[576+kk] + x1*Wsm[576+kk+1] + x2*Wsm[576+kk+2] + x3*Wsm[576+kk+3];
    }
  }
  out[(size_t)g*3+0] = a0 + actor[v*3+0];
  out[(size_t)g*3+1] = a1 + actor[v*3+1];
  out[(size_t)g*3+2] = a2 + actor[v*3+2];
}

extern "C" void kernel_launch(void* const* d_in, const int* in_sizes, int n_in,
                              void* d_out, int out_size, void* d_ws, size_t ws_size,
                              hipStream_t stream){
  (void)in_sizes; (void)n_in; (void)out_size; (void)ws_size;

  const float* audio = (const float*)d_in[0];
  const float* actor = (const float*)d_in[2];
  const int* sp[4]   = {(const int*)d_in[3],(const int*)d_in[4],(const int*)d_in[5],(const int*)d_in[6]};
  const int* drows[4]; const int* dcols[4]; const float* dvals[4];
  for (int i=0;i<4;i++){ drows[i]=(const int*)d_in[7+3*i]; dcols[i]=(const int*)d_in[8+3*i]; dvals[i]=(const float*)d_in[9+3*i]; }
  const int* urows[4]; const int* ucols[4]; const float* uvals[4];
  for (int i=0;i<4;i++){ urows[i]=(const int*)d_in[19+3*i]; ucols[i]=(const int*)d_in[20+3*i]; uvals[i]=(const float*)d_in[21+3*i]; }
  const float* encW[4]={(const float*)d_in[31],(const float*)d_in[33],(const float*)d_in[35],(const float*)d_in[37]};
  const float* encB[4]={(const float*)d_in[32],(const float*)d_in[34],(const float*)d_in[36],(const float*)d_in[38]};
  const float* enc_lin_W=(const float*)d_in[39]; const float* enc_lin_b=(const float*)d_in[40];
  const float* dec_lin_W=(const float*)d_in[41]; const float* dec_lin_b=(const float*)d_in[42];
  const float* decW[5]={(const float*)d_in[43],(const float*)d_in[45],(const float*)d_in[47],(const float*)d_in[49],(const float*)d_in[51]};
  const float* decB[5]={(const float*)d_in[44],(const float*)d_in[46],(const float*)d_in[48],(const float*)d_in[50],(const float*)d_in[52]};
  const float* audW=(const float*)d_in[53]; const float* audB=(const float*)d_in[54];
  const float* l0_Wih=(const float*)d_in[55]; const float* l0_Whh=(const float*)d_in[56];
  const float* l0_bih=(const float*)d_in[57]; const float* l0_bhh=(const float*)d_in[58];
  const float* l12_Wih=(const float*)d_in[59]; const float* l12_Whh=(const float*)d_in[60];
  const float* l12_bih=(const float*)d_in[61]; const float* l12_bhh=(const float*)d_in[62];
  float* out = (float*)d_out;

  // ---- workspace layout (bytes) ----
  char* base = (char*)d_ws;
  u16* A  = (u16*)base;                          // 10,287,104 B
  u16* Bb = (u16*)(base + 10287104);             // 20,574,208 B
  int* curBase = (int*)(base + 30891520);        // 8341 ints
  int* lstBase = (int*)(base + 30924928);        // 533,824 ints
  float* sm = (float*)(base + 33060224);
  float* h0     = sm;                 // 4096
  float* latent = sm + 4096;          // 2048

  // pool bookkeeping: d0,d1,d2,d3,u0,u1,u2,u3
  const int pVout[8] = {1256,314,79,20,5023,1256,314,79};
  const int pNnz[8]  = {3768,942,237,60,15069,3768,942,237};
  Lists L; int curoff=0, lstoff=0, totnnz=0;
  const int* prow[8] = {drows[0],drows[1],drows[2],drows[3],urows[0],urows[1],urows[2],urows[3]};
  int curo[8], lsto[8];
  for (int k=0;k<8;k++){
    L.rows[k]=prow[k]; L.nnz[k]=pNnz[k];
    L.curoff[k]=curoff; L.lstoff[k]=lstoff;
    curo[k]=curoff; lsto[k]=lstoff;
    curoff += pVout[k]; lstoff += pVout[k]*POOL_CAP; totnnz += pNnz[k];
  }
  hipMemsetAsync(curBase, 0, (size_t)curoff*4, stream);
  fill_all_k<<<CDIV(totnnz,256),256,0,stream>>>(L, curBase, lstBase, totnnz);

  // ---- audio path (writes h0[:, :64]) ----
  audio_emb_k<<<32,256,0,stream>>>(audio, audW, audB, h0);

  // ---- encoder (B=1) ----
  conv3_k<<<CDIV(5023*32,256),256,0,stream>>>(actor, sp[0], encW[0], encB[0], A, 5023, 32);
  pool_g4_k<<<CDIV(1256*8,256),256,0,stream>>>(A, dcols[0], dvals[0], curBase+curo[0], lstBase+lsto[0], Bb, 1, 5023, 1256, 32);
  conv_mfma<32,64,64><<<dim3(CDIV(1256,64),1),256,0,stream>>>(Bb, sp[1], encW[1], encB[1], A, 1256, 64, 1256);
  pool_g4_k<<<CDIV(314*16,256),256,0,stream>>>(A, dcols[1], dvals[1], curBase+curo[1], lstBase+lsto[1], Bb, 1, 1256, 314, 64);
  conv_mfma<64,64,64><<<dim3(CDIV(314,64),2),256,0,stream>>>(Bb, sp[2], encW[2], encB[2], A, 314, 128, 314);
  pool_g4_k<<<CDIV(79*32,256),256,0,stream>>>(A, dcols[2], dvals[2], curBase+curo[2], lstBase+lsto[2], Bb, 1, 314, 79, 128);
  conv_mfma<128,64,64><<<dim3(CDIV(79,64),4),256,0,stream>>>(Bb, sp[3], encW[3], encB[3], A, 79, 256, 79);
  pool_g4_k<<<CDIV(20*64,256),256,0,stream>>>(A, dcols[3], dvals[3], curBase+curo[3], lstBase+lsto[3], Bb, 1, 79, 20, 256);

  // z -> h0[:, 64:] broadcast inside enc_lin_k
  enc_lin_k<<<64,256,0,stream>>>(Bb, enc_lin_W, enc_lin_b, h0);

  // ---- LSTM (serial, single block, reg-resident weights) ----
  lstm3_k<<<1,256,0,stream>>>(h0, l0_Wih, l0_Whh, l0_bih, l0_bhh,
                              l12_Wih, l12_Whh, l12_bih, l12_bhh, latent);

  // ---- decoder (B=32) ----
  dec_lin_k<<<CDIV(32*5120,256),256,0,stream>>>(latent, dec_lin_W, dec_lin_b, A); // (32,20,256)

  // j=3: up-pool u3 (20->79,C=256), conv IC=256 OC=256
  pool_g4_k<<<CDIV(32*79*64,256),256,0,stream>>>(A, ucols[3], uvals[3], curBase+curo[7], lstBase+lsto[7], Bb, 32, 20, 79, 256);
  conv_mfma<256,64,64><<<dim3(CDIV(2528,64),4),256,0,stream>>>(Bb, sp[3], decW[0], decB[0], A, 79, 256, 2528);

  // j=2: up-pool u2 (79->314,C=256), conv IC=256 OC=128
  pool_g4_k<<<CDIV(32*314*64,256),256,0,stream>>>(A, ucols[2], uvals[2], curBase+curo[6], lstBase+lsto[6], Bb, 32, 79, 314, 256);
  conv_mfma<256,64,128><<<dim3(CDIV(10048,128),2),256,0,stream>>>(Bb, sp[2], decW[1], decB[1], A, 314, 128, 10048);

  // j=1: up-pool u1 (314->1256,C=128), conv IC=128 OC=64
  pool_g4_k<<<CDIV(32*1256*32,256),256,0,stream>>>(A, ucols[1], uvals[1], curBase+curo[5], lstBase+lsto[5], Bb, 32, 314, 1256, 128);
  conv_mfma<128,64,128><<<dim3(CDIV(40192,128),1),256,0,stream>>>(Bb, sp[1], decW[2], decB[2], A, 1256, 64, 40192);

  // j=0: up-pool u0 (1256->5023,C=64), conv IC=64 OC=32
  pool_g4_k<<<CDIV(32*5023*16,256),256,0,stream>>>(A, ucols[0], uvals[0], curBase+curo[4], lstBase+lsto[4], Bb, 32, 1256, 5023, 64);
  conv_mfma<64,32,128><<<dim3(CDIV(160736,128),1),256,0,stream>>>(Bb, sp[0], decW[3], decB[3], A, 5023, 32, 160736);

  // final conv (288->3) + actor residual -> f32 out
  final_k<<<CDIV(32*5023,256),256,0,stream>>>(A, sp[0], decW[4], decB[4], actor, out);
}

// Round 7
// 736.015 us; speedup vs baseline: 8.0806x; 1.0475x over previous
//
#include <hip/hip_runtime.h>
#include <cstdint>
#include <cstddef>

// SpiralAutoencoder forward, MI355X gfx950.
// Inputs f32, indices i32, output f32. Internal activations bf16, fp32 accum.
// Spiral convs = MFMA bf16 GEMM (16x16x32), weights pre-cast to bf16 in ws.
// LSTM = register-resident weights, 4-way split accumulators.
// Pools = gather via device-built capped per-row edge lists (fused builder).

typedef unsigned short u16;
typedef __attribute__((ext_vector_type(8))) short short8;
typedef __attribute__((ext_vector_type(4))) float float4v;
#define CDIV(a,b) (((a)+(b)-1)/(b))
#define POOL_CAP 64

__device__ __forceinline__ float bf(u16 u){ return __uint_as_float(((unsigned)u)<<16); }
__device__ __forceinline__ u16 fb(float x){
  unsigned u = __float_as_uint(x);
  unsigned r = u + 0x7fffu + ((u>>16)&1u);   // RNE
  return (u16)(r>>16);
}

// ---- fused f32->bf16 cast of all conv weights ----
struct WCast { const float* src[7]; int cum[8]; };
__global__ void cast_all_k(WCast C, u16* __restrict__ dst, int total){
  int i = blockIdx.x*blockDim.x + threadIdx.x;
  if (i >= total) return;
  int k = 0;
  while (i >= C.cum[k+1]) k++;
  dst[i] = fb(C.src[k][i - C.cum[k]]);
}

// ---- audio embedding: (32,1536)@(64,1536)^T + b -> h0[t*128+f] (f<64) ----
__global__ void audio_emb_k(const float* __restrict__ ah, const float* __restrict__ W,
                            const float* __restrict__ b, float* __restrict__ h0){
  int t = blockIdx.x;
  int f = threadIdx.x >> 2, sl = threadIdx.x & 3;
  const float4* x4 = (const float4*)(ah + t*1536);
  const float4* w4 = (const float4*)(W + f*1536);
  float acc = 0.f;
  for (int k=sl; k<384; k+=4){
    float4 xv = x4[k], wv = w4[k];
    acc += xv.x*wv.x + xv.y*wv.y + xv.z*wv.z + xv.w*wv.w;
  }
  acc += __shfl_down(acc, 2, 64);
  acc += __shfl_down(acc, 1, 64);
  if (sl == 0) h0[t*128 + f] = acc + b[f];
}

// ---- scalar spiral conv for IC=3 (encoder stage 0), reads f32 actor ----
__global__ void conv3_k(const float* __restrict__ x, const int* __restrict__ idx,
                        const float* __restrict__ W, const float* __restrict__ bias,
                        u16* __restrict__ out, int V, int OC){
  int i = blockIdx.x*blockDim.x + threadIdx.x;
  if (i >= V*OC) return;
  int o = i % OC; int v = i / OC;
  const float* wrow = W + (size_t)o*27;
  const int* vix = idx + v*9;
  float acc = bias[o];
  for (int s=0;s<9;s++){
    const float* xr = x + (size_t)vix[s]*3;
    acc += xr[0]*wrow[s*3] + xr[1]*wrow[s*3+1] + xr[2]*wrow[s*3+2];
  }
  if (acc < 0.f) acc = expm1f(acc);
  out[i] = fb(acc);
}

// ---- MFMA spiral conv: out[m,o], m=b*V+v, K=9*IC, gathered A, bf16 W ----
template<int IC, int BN, int BM>
__global__ void __launch_bounds__(256) conv_mfma(
    const u16* __restrict__ x, const int* __restrict__ idx,
    const u16* __restrict__ Wb, const float* __restrict__ bias,
    u16* __restrict__ out, int V, int OC, int M){
  constexpr int K = 9*IC;
  constexpr int NT = BN/16;
  constexpr int MT = BM/64;
  constexpr int LOG2 = (IC==32?5: IC==64?6: IC==128?7:8);
  constexpr int AST = 40;                 // LDS row stride (u16): 32 data + 8 pad
  __shared__ u16 Asm[BM*AST];
  __shared__ u16 Bsm[BN*AST];
  __shared__ int rowB[BM], rowV[BM];
  int t = threadIdx.x;
  int m0 = blockIdx.x*BM;
  int o0 = blockIdx.y*BN;
  if (t < BM){
    int mg = m0 + t;
    if (mg < M){ int b = mg / V; rowB[t] = b; rowV[t] = mg - b*V; }
    else rowB[t] = -1;
  }
  int lane = t & 63, wave = t >> 6;
  int quad = lane >> 4, col = lane & 15;
  float4v acc[MT][NT];
  #pragma unroll
  for (int mi=0;mi<MT;mi++)
    #pragma unroll
    for (int nt=0;nt<NT;nt++) acc[mi][nt] = (float4v)0.f;

  for (int kc = 0; kc < K/32; ++kc){
    int s  = (kc*32) >> LOG2;
    int c0 = (kc*32) & (IC-1);
    __syncthreads();
    #pragma unroll
    for (int rpt=0; rpt<MT; ++rpt){   // A tile: BM rows x 32 bf16 (gathered)
      int seg = t + 256*rpt;
      int arow = seg >> 2, aq = seg & 3;
      int b = rowB[arow];
      uint4 val = {0u,0u,0u,0u};
      if (b >= 0){
        int ix = idx[rowV[arow]*9 + s];
        val = *(const uint4*)(x + ((size_t)b*V + ix)*IC + c0 + aq*8);
      }
      *(uint4*)&Asm[arow*AST + aq*8] = val;
    }
    if (t < BN*4){ // B tile: BN rows of bf16 W, straight 16B copies
      int br = t >> 2, bq = t & 3;
      *(uint4*)&Bsm[br*AST + bq*8] =
          *(const uint4*)(Wb + (size_t)(o0+br)*K + kc*32 + bq*8);
    }
    __syncthreads();
    short8 a[MT];
    #pragma unroll
    for (int mi=0;mi<MT;mi++)
      a[mi] = *(const short8*)&Asm[(wave*MT*16 + mi*16 + col)*AST + quad*8];
    #pragma unroll
    for (int nt=0; nt<NT; ++nt){
      short8 bfr = *(const short8*)&Bsm[(nt*16 + col)*AST + quad*8];
      #pragma unroll
      for (int mi=0;mi<MT;mi++)
        acc[mi][nt] = __builtin_amdgcn_mfma_f32_16x16x32_bf16(a[mi], bfr, acc[mi][nt], 0, 0, 0);
    }
  }
  #pragma unroll
  for (int mi=0;mi<MT;mi++){
    #pragma unroll
    for (int nt=0; nt<NT; ++nt){
      int o = o0 + nt*16 + col;
      float bv = bias[o];
      #pragma unroll
      for (int r=0;r<4;r++){
        int mg = m0 + wave*MT*16 + mi*16 + quad*4 + r;
        if (mg < M){
          float val = acc[mi][nt][r] + bv;
          if (val < 0.f) val = expm1f(val);
          out[(size_t)mg*OC + o] = fb(val);
        }
      }
    }
  }
}

// ---- fused list builder for all 8 pool matrices ----
struct Lists {
  const int* rows[8];
  int nnz[8];
  int curoff[8];
  int lstoff[8];
};
__global__ void fill_all_k(Lists L, int* __restrict__ curBase, int* __restrict__ lstBase, int total){
  int i = blockIdx.x*blockDim.x + threadIdx.x;
  if (i >= total) return;
  int off = i, k = 0;
  while (off >= L.nnz[k]){ off -= L.nnz[k]; k++; }
  int r = L.rows[k][off];
  int p = atomicAdd(curBase + L.curoff[k] + r, 1);
  if (p < POOL_CAP) lstBase[L.lstoff[k] + r*POOL_CAP + p] = off;
}

// ---- pool gather, 4 channels/thread ----
__global__ void pool_g4_k(const u16* __restrict__ x, const int* __restrict__ cols,
                          const float* __restrict__ vals, const int* __restrict__ cur,
                          const int* __restrict__ lst, u16* __restrict__ out,
                          int B, int Vin, int Vout, int C){
  int C4 = C >> 2;
  int total = B*Vout*C4;
  int i = blockIdx.x*blockDim.x + threadIdx.x;
  if (i >= total) return;
  int c4 = i % C4; int tt = i / C4; int r = tt % Vout; int b = tt / Vout;
  int deg = cur[r]; if (deg > POOL_CAP) deg = POOL_CAP;
  const int* le = lst + r*POOL_CAP;
  float a0=0.f,a1=0.f,a2=0.f,a3=0.f;
  for (int k=0;k<deg;k++){
    int e = le[k];
    float v = vals[e];
    ushort4 xv = *(const ushort4*)(x + ((size_t)b*Vin + (size_t)cols[e])*C + c4*4);
    a0 += v*bf(xv.x); a1 += v*bf(xv.y); a2 += v*bf(xv.z); a3 += v*bf(xv.w);
  }
  ushort4 o; o.x=fb(a0); o.y=fb(a1); o.z=fb(a2); o.w=fb(a3);
  *(ushort4*)(out + ((size_t)b*Vout + (size_t)r)*C + c4*4) = o;
}

// ---- encoder linear, split-K + broadcast into h0[:,64:] ----
__global__ void __launch_bounds__(256) enc_lin_k(
    const u16* __restrict__ x, const float* __restrict__ W,
    const float* __restrict__ b, float* __restrict__ h0){
  int f = blockIdx.x;          // 64 blocks
  int t = threadIdx.x;         // 256
  const ushort4* x4 = (const ushort4*)x;
  const float4* w4 = (const float4*)(W + (size_t)f*5120);
  float acc = 0.f;
  for (int k=t; k<1280; k+=256){
    ushort4 xv = x4[k]; float4 wv = w4[k];
    acc += bf(xv.x)*wv.x + bf(xv.y)*wv.y + bf(xv.z)*wv.z + bf(xv.w)*wv.w;
  }
  #pragma unroll
  for (int off=32; off; off>>=1) acc += __shfl_down(acc, off, 64);
  __shared__ float red[4];
  if ((t & 63) == 0) red[t>>6] = acc;
  __syncthreads();
  if (t < 32){
    float zf = b[f] + red[0] + red[1] + red[2] + red[3];
    h0[t*128 + 64 + f] = zf;
  }
}

// ---- LSTM with register-resident bf16-packed weights, 4-way acc split ----
__device__ __forceinline__ float sigm(float x){ return 1.f/(1.f+__expf(-x)); }
__device__ __forceinline__ float tanhfast(float x){ return 1.f - 2.f/(__expf(2.f*x)+1.f); }

template<int IN_DIM>
__device__ __forceinline__ void lstm_layer(
    int j, bool rev,
    const float* __restrict__ Wih, const float* __restrict__ Whh,
    const float* __restrict__ bih, const float* __restrict__ bhh,
    const float* __restrict__ xbuf, float* __restrict__ obuf_d,
    float* __restrict__ hsd, float* __restrict__ csd, float* __restrict__ gsd){
  unsigned wih[IN_DIM/2];
  #pragma unroll
  for (int k=0;k<IN_DIM/2;k++){
    float2 w = *(const float2*)&Wih[(size_t)j*IN_DIM + 2*k];
    wih[k] = ((unsigned)fb(w.x)) | (((unsigned)fb(w.y))<<16);
  }
  unsigned whh[16];
  #pragma unroll
  for (int k=0;k<16;k++){
    float2 w = *(const float2*)&Whh[(size_t)j*32 + 2*k];
    whh[k] = ((unsigned)fb(w.x)) | (((unsigned)fb(w.y))<<16);
  }
  float bias = bih[j] + bhh[j];
  if (j < 32){ hsd[j]=0.f; csd[j]=0.f; }
  __syncthreads();

  for (int s=0;s<32;s++){
    int tx = rev ? (31-s) : s;
    // 4 independent accumulators to break the dependent-FMA chain
    float a0=0.f, a1=0.f, a2=0.f, a3=0.f;
    const float2* x2 = (const float2*)&xbuf[tx*IN_DIM];
    #pragma unroll
    for (int k=0;k<IN_DIM/2;k+=4){
      unsigned u0=wih[k], u1=wih[k+1], u2=wih[k+2], u3=wih[k+3];
      float2 v0=x2[k], v1=x2[k+1], v2=x2[k+2], v3=x2[k+3];
      a0 = fmaf(v0.x, __uint_as_float(u0<<16), a0);
      a0 = fmaf(v0.y, __uint_as_float(u0 & 0xffff0000u), a0);
      a1 = fmaf(v1.x, __uint_as_float(u1<<16), a1);
      a1 = fmaf(v1.y, __uint_as_float(u1 & 0xffff0000u), a1);
      a2 = fmaf(v2.x, __uint_as_float(u2<<16), a2);
      a2 = fmaf(v2.y, __uint_as_float(u2 & 0xffff0000u), a2);
      a3 = fmaf(v3.x, __uint_as_float(u3<<16), a3);
      a3 = fmaf(v3.y, __uint_as_float(u3 & 0xffff0000u), a3);
    }
    const float2* h2 = (const float2*)hsd;
    #pragma unroll
    for (int k=0;k<16;k+=4){
      unsigned u0=whh[k], u1=whh[k+1], u2=whh[k+2], u3=whh[k+3];
      float2 v0=h2[k], v1=h2[k+1], v2=h2[k+2], v3=h2[k+3];
      a0 = fmaf(v0.x, __uint_as_float(u0<<16), a0);
      a0 = fmaf(v0.y, __uint_as_float(u0 & 0xffff0000u), a0);
      a1 = fmaf(v1.x, __uint_as_float(u1<<16), a1);
      a1 = fmaf(v1.y, __uint_as_float(u1 & 0xffff0000u), a1);
      a2 = fmaf(v2.x, __uint_as_float(u2<<16), a2);
      a2 = fmaf(v2.y, __uint_as_float(u2 & 0xffff0000u), a2);
      a3 = fmaf(v3.x, __uint_as_float(u3<<16), a3);
      a3 = fmaf(v3.y, __uint_as_float(u3 & 0xffff0000u), a3);
    }
    gsd[j] = bias + ((a0+a1) + (a2+a3));
    __syncthreads();
    if (j < 32){
      float ig = sigm(gsd[j]);
      float fg = sigm(gsd[32+j]);
      float gg = tanhfast(gsd[64+j]);
      float og = sigm(gsd[96+j]);
      float cn = fg*csd[j] + ig*gg;
      float hn = og*tanhfast(cn);
      csd[j]=cn; hsd[j]=hn;
      obuf_d[tx*64 + j] = hn;
    }
    __syncthreads();
  }
}

__global__ void __launch_bounds__(256) lstm3_k(
    const float* __restrict__ h0,
    const float* __restrict__ l0_Wih, const float* __restrict__ l0_Whh,
    const float* __restrict__ l0_bih, const float* __restrict__ l0_bhh,
    const float* __restrict__ l12_Wih, const float* __restrict__ l12_Whh,
    const float* __restrict__ l12_bih, const float* __restrict__ l12_bhh,
    float* __restrict__ latent){
  __shared__ __align__(16) float xbuf[32*128];
  __shared__ __align__(16) float obuf[32*64];
  __shared__ __align__(16) float hs[2][32];
  __shared__ __align__(16) float cs[2][32];
  __shared__ __align__(16) float gs[2][128];
  int t = threadIdx.x;
  int dir = t >> 7, j = t & 127;
  bool rev = (dir == 1);
  for (int i=t;i<32*128;i+=256) xbuf[i]=h0[i];
  __syncthreads();

  lstm_layer<128>(j, rev, l0_Wih + dir*128*128, l0_Whh + dir*128*32,
                  l0_bih + dir*128, l0_bhh + dir*128,
                  xbuf, obuf + dir*32, hs[dir], cs[dir], gs[dir]);
  __syncthreads();
  for (int i=t;i<32*64;i+=256) xbuf[i]=obuf[i];
  __syncthreads();

  for (int layer=1; layer<3; layer++){
    int m = (layer-1)*2 + dir;
    lstm_layer<64>(j, rev, l12_Wih + m*128*64, l12_Whh + m*128*32,
                   l12_bih + m*128, l12_bhh + m*128,
                   xbuf, obuf + dir*32, hs[dir], cs[dir], gs[dir]);
    __syncthreads();
    for (int i=t;i<32*64;i+=256) xbuf[i]=obuf[i];
    __syncthreads();
  }
  for (int i=t;i<32*64;i+=256) latent[i]=obuf[i];
}

// ---- decoder linear: y[t,r] = b[r] + sum_{k<64} latent[t,k]*W[r,k] -> bf16 ----
__global__ void dec_lin_k(const float* __restrict__ latent, const float* __restrict__ W,
                          const float* __restrict__ b, u16* __restrict__ y){
  int i = blockIdx.x*blockDim.x + threadIdx.x;
  if (i >= 32*5120) return;
  int r = i % 5120, t = i / 5120;
  const float4* x4 = (const float4*)(latent + t*64);
  const float4* w4 = (const float4*)(W + (size_t)r*64);
  float acc = b[r];
  #pragma unroll
  for (int k=0;k<16;k++){
    float4 xv=x4[k]; float4 wv=w4[k];
    acc += xv.x*wv.x+xv.y*wv.y+xv.z*wv.z+xv.w*wv.w;
  }
  y[i] = fb(acc);
}

// ---- final conv (OC=3, IC=32, no ELU) + actor residual -> f32 out ----
__global__ void final_k(const u16* __restrict__ x, const int* __restrict__ idx,
                        const float* __restrict__ W, const float* __restrict__ bias,
                        const float* __restrict__ actor, float* __restrict__ out){
  __shared__ float Wsm[3*288];
  __shared__ float bsm[3];
  int t = threadIdx.x;
  for (int i=t;i<864;i+=256) Wsm[i]=W[i];
  if (t<3) bsm[t]=bias[t];
  __syncthreads();
  int g = blockIdx.x*256 + t;
  if (g >= 32*5023) return;
  int v = g % 5023, b = g / 5023;
  const u16* xb = x + (size_t)b*5023*32;
  const int* vix = idx + v*9;
  float a0=bsm[0], a1=bsm[1], a2=bsm[2];
  for (int s=0;s<9;s++){
    const ushort4* xr = (const ushort4*)(xb + (size_t)vix[s]*32);
    #pragma unroll
    for (int k=0;k<8;k++){
      ushort4 xv = xr[k];
      float x0=bf(xv.x), x1=bf(xv.y), x2=bf(xv.z), x3=bf(xv.w);
      int kk = s*32 + k*4;
      a0 += x0*Wsm[kk] + x1*Wsm[kk+1] + x2*Wsm[kk+2] + x3*Wsm[kk+3];
      a1 += x0*Wsm[288+kk] + x1*Wsm[288+kk+1] + x2*Wsm[288+kk+2] + x3*Wsm[288+kk+3];
      a2 += x0*Wsm[576+kk] + x1*Wsm[576+kk+1] + x2*Wsm[576+kk+2] + x3*Wsm[576+kk+3];
    }
  }
  out[(size_t)g*3+0] = a0 + actor[v*3+0];
  out[(size_t)g*3+1] = a1 + actor[v*3+1];
  out[(size_t)g*3+2] = a2 + actor[v*3+2];
}

extern "C" void kernel_launch(void* const* d_in, const int* in_sizes, int n_in,
                              void* d_out, int out_size, void* d_ws, size_t ws_size,
                              hipStream_t stream){
  (void)in_sizes; (void)n_in; (void)out_size; (void)ws_size;

  const float* audio = (const float*)d_in[0];
  const float* actor = (const float*)d_in[2];
  const int* sp[4]   = {(const int*)d_in[3],(const int*)d_in[4],(const int*)d_in[5],(const int*)d_in[6]};
  const int* drows[4]; const int* dcols[4]; const float* dvals[4];
  for (int i=0;i<4;i++){ drows[i]=(const int*)d_in[7+3*i]; dcols[i]=(const int*)d_in[8+3*i]; dvals[i]=(const float*)d_in[9+3*i]; }
  const int* urows[4]; const int* ucols[4]; const float* uvals[4];
  for (int i=0;i<4;i++){ urows[i]=(const int*)d_in[19+3*i]; ucols[i]=(const int*)d_in[20+3*i]; uvals[i]=(const float*)d_in[21+3*i]; }
  const float* encW[4]={(const float*)d_in[31],(const float*)d_in[33],(const float*)d_in[35],(const float*)d_in[37]};
  const float* encB[4]={(const float*)d_in[32],(const float*)d_in[34],(const float*)d_in[36],(const float*)d_in[38]};
  const float* enc_lin_W=(const float*)d_in[39]; const float* enc_lin_b=(const float*)d_in[40];
  const float* dec_lin_W=(const float*)d_in[41]; const float* dec_lin_b=(const float*)d_in[42];
  const float* decW[5]={(const float*)d_in[43],(const float*)d_in[45],(const float*)d_in[47],(const float*)d_in[49],(const float*)d_in[51]};
  const float* decB[5]={(const float*)d_in[44],(const float*)d_in[46],(const float*)d_in[48],(const float*)d_in[50],(const float*)d_in[52]};
  const float* audW=(const float*)d_in[53]; const float* audB=(const float*)d_in[54];
  const float* l0_Wih=(const float*)d_in[55]; const float* l0_Whh=(const float*)d_in[56];
  const float* l0_bih=(const float*)d_in[57]; const float* l0_bhh=(const float*)d_in[58];
  const float* l12_Wih=(const float*)d_in[59]; const float* l12_Whh=(const float*)d_in[60];
  const float* l12_bih=(const float*)d_in[61]; const float* l12_bhh=(const float*)d_in[62];
  float* out = (float*)d_out;

  // ---- workspace layout (bytes) ----
  char* base = (char*)d_ws;
  u16* A  = (u16*)base;                          // 10,287,104 B
  u16* Bb = (u16*)(base + 10287104);             // 20,574,208 B
  int* curBase = (int*)(base + 30891520);        // 8341 ints
  int* lstBase = (int*)(base + 30924928);        // 533,824 ints -> ends 33,060,224
  u16* Wbf = (u16*)(base + 33060224);            // 1,363,968 bf16 = 2,727,936 B
  float* sm = (float*)(base + 35788160);
  float* h0     = sm;                 // 4096
  float* latent = sm + 4096;          // 2048

  // bf16 weight segment offsets (elements): enc1,enc2,enc3,dec0,dec1,dec2,dec3
  const int wsz[7] = {64*288, 128*576, 256*1152, 256*2304, 128*2304, 64*1152, 32*576};
  WCast WC; int wcum = 0;
  const float* wsrc[7] = {encW[1],encW[2],encW[3],decW[0],decW[1],decW[2],decW[3]};
  int wo[7];
  for (int k=0;k<7;k++){ WC.src[k]=wsrc[k]; WC.cum[k]=wcum; wo[k]=wcum; wcum+=wsz[k]; }
  WC.cum[7]=wcum;
  cast_all_k<<<CDIV(wcum,256),256,0,stream>>>(WC, Wbf, wcum);

  // pool bookkeeping: d0,d1,d2,d3,u0,u1,u2,u3
  const int pVout[8] = {1256,314,79,20,5023,1256,314,79};
  const int pNnz[8]  = {3768,942,237,60,15069,3768,942,237};
  Lists L; int curoff=0, lstoff=0, totnnz=0;
  const int* prow[8] = {drows[0],drows[1],drows[2],drows[3],urows[0],urows[1],urows[2],urows[3]};
  int curo[8], lsto[8];
  for (int k=0;k<8;k++){
    L.rows[k]=prow[k]; L.nnz[k]=pNnz[k];
    L.curoff[k]=curoff; L.lstoff[k]=lstoff;
    curo[k]=curoff; lsto[k]=lstoff;
    curoff += pVout[k]; lstoff += pVout[k]*POOL_CAP; totnnz += pNnz[k];
  }
  hipMemsetAsync(curBase, 0, (size_t)curoff*4, stream);
  fill_all_k<<<CDIV(totnnz,256),256,0,stream>>>(L, curBase, lstBase, totnnz);

  // ---- audio path (writes h0[:, :64]) ----
  audio_emb_k<<<32,256,0,stream>>>(audio, audW, audB, h0);

  // ---- encoder (B=1) ----
  conv3_k<<<CDIV(5023*32,256),256,0,stream>>>(actor, sp[0], encW[0], encB[0], A, 5023, 32);
  pool_g4_k<<<CDIV(1256*8,256),256,0,stream>>>(A, dcols[0], dvals[0], curBase+curo[0], lstBase+lsto[0], Bb, 1, 5023, 1256, 32);
  conv_mfma<32,64,64><<<dim3(CDIV(1256,64),1),256,0,stream>>>(Bb, sp[1], Wbf+wo[0], encB[1], A, 1256, 64, 1256);
  pool_g4_k<<<CDIV(314*16,256),256,0,stream>>>(A, dcols[1], dvals[1], curBase+curo[1], lstBase+lsto[1], Bb, 1, 1256, 314, 64);
  conv_mfma<64,64,64><<<dim3(CDIV(314,64),2),256,0,stream>>>(Bb, sp[2], Wbf+wo[1], encB[2], A, 314, 128, 314);
  pool_g4_k<<<CDIV(79*32,256),256,0,stream>>>(A, dcols[2], dvals[2], curBase+curo[2], lstBase+lsto[2], Bb, 1, 314, 79, 128);
  conv_mfma<128,64,64><<<dim3(CDIV(79,64),4),256,0,stream>>>(Bb, sp[3], Wbf+wo[2], encB[3], A, 79, 256, 79);
  pool_g4_k<<<CDIV(20*64,256),256,0,stream>>>(A, dcols[3], dvals[3], curBase+curo[3], lstBase+lsto[3], Bb, 1, 79, 20, 256);

  enc_lin_k<<<64,256,0,stream>>>(Bb, enc_lin_W, enc_lin_b, h0);

  // ---- LSTM (serial, single block, reg-resident weights) ----
  lstm3_k<<<1,256,0,stream>>>(h0, l0_Wih, l0_Whh, l0_bih, l0_bhh,
                              l12_Wih, l12_Whh, l12_bih, l12_bhh, latent);

  // ---- decoder (B=32) ----
  dec_lin_k<<<CDIV(32*5120,256),256,0,stream>>>(latent, dec_lin_W, dec_lin_b, A); // (32,20,256)

  // j=3: up-pool u3 (20->79,C=256), conv IC=256 OC=256
  pool_g4_k<<<CDIV(32*79*64,256),256,0,stream>>>(A, ucols[3], uvals[3], curBase+curo[7], lstBase+lsto[7], Bb, 32, 20, 79, 256);
  conv_mfma<256,64,64><<<dim3(CDIV(2528,64),4),256,0,stream>>>(Bb, sp[3], Wbf+wo[3], decB[0], A, 79, 256, 2528);

  // j=2: up-pool u2 (79->314,C=256), conv IC=256 OC=128
  pool_g4_k<<<CDIV(32*314*64,256),256,0,stream>>>(A, ucols[2], uvals[2], curBase+curo[6], lstBase+lsto[6], Bb, 32, 79, 314, 256);
  conv_mfma<256,64,128><<<dim3(CDIV(10048,128),2),256,0,stream>>>(Bb, sp[2], Wbf+wo[4], decB[1], A, 314, 128, 10048);

  // j=1: up-pool u1 (314->1256,C=128), conv IC=128 OC=64
  pool_g4_k<<<CDIV(32*1256*32,256),256,0,stream>>>(A, ucols[1], uvals[1], curBase+curo[5], lstBase+lsto[5], Bb, 32, 314, 1256, 128);
  conv_mfma<128,64,128><<<dim3(CDIV(40192,128),1),256,0,stream>>>(Bb, sp[1], Wbf+wo[5], decB[2], A, 1256, 64, 40192);

  // j=0: up-pool u0 (1256->5023,C=64), conv IC=64 OC=32
  pool_g4_k<<<CDIV(32*5023*16,256),256,0,stream>>>(A, ucols[0], uvals[0], curBase+curo[4], lstBase+lsto[4], Bb, 32, 1256, 5023, 64);
  conv_mfma<64,32,128><<<dim3(CDIV(160736,128),1),256,0,stream>>>(Bb, sp[0], Wbf+wo[6], decB[3], A, 5023, 32, 160736);

  // final conv (288->3) + actor residual -> f32 out
  final_k<<<CDIV(32*5023,256),256,0,stream>>>(A, sp[0], decW[4], decB[4], actor, out);
}

// Round 8
// 729.350 us; speedup vs baseline: 8.1544x; 1.0091x over previous
//
#include <hip/hip_runtime.h>
#include <cstdint>
#include <cstddef>

// SpiralAutoencoder forward, MI355X gfx950.
// Inputs f32, indices i32, output f32. Internal activations bf16, fp32 accum.
// Spiral convs = MFMA bf16 GEMM (16x16x32), weights pre-cast to bf16 in ws.
// LSTM = register-resident packed-bf16 weights + bf16 LDS activations
//        (R7 postmortem: single-CU LDS instruction throughput was the limiter).
// Pools = gather via device-built capped per-row edge lists (fused builder).

typedef unsigned short u16;
typedef __attribute__((ext_vector_type(8))) short short8;
typedef __attribute__((ext_vector_type(4))) float float4v;
#define CDIV(a,b) (((a)+(b)-1)/(b))
#define POOL_CAP 64

__device__ __forceinline__ float bf(u16 u){ return __uint_as_float(((unsigned)u)<<16); }
__device__ __forceinline__ u16 fb(float x){
  unsigned u = __float_as_uint(x);
  unsigned r = u + 0x7fffu + ((u>>16)&1u);   // RNE
  return (u16)(r>>16);
}
__device__ __forceinline__ float lo16(unsigned u){ return __uint_as_float(u<<16); }
__device__ __forceinline__ float hi16(unsigned u){ return __uint_as_float(u & 0xffff0000u); }

// ---- fused f32->bf16 cast of all conv weights ----
struct WCast { const float* src[7]; int cum[8]; };
__global__ void cast_all_k(WCast C, u16* __restrict__ dst, int total){
  int i = blockIdx.x*blockDim.x + threadIdx.x;
  if (i >= total) return;
  int k = 0;
  while (i >= C.cum[k+1]) k++;
  dst[i] = fb(C.src[k][i - C.cum[k]]);
}

// ---- audio embedding: (32,1536)@(64,1536)^T + b -> h0[t*128+f] (f<64) ----
__global__ void audio_emb_k(const float* __restrict__ ah, const float* __restrict__ W,
                            const float* __restrict__ b, float* __restrict__ h0){
  int t = blockIdx.x;
  int f = threadIdx.x >> 2, sl = threadIdx.x & 3;
  const float4* x4 = (const float4*)(ah + t*1536);
  const float4* w4 = (const float4*)(W + f*1536);
  float acc = 0.f;
  for (int k=sl; k<384; k+=4){
    float4 xv = x4[k], wv = w4[k];
    acc += xv.x*wv.x + xv.y*wv.y + xv.z*wv.z + xv.w*wv.w;
  }
  acc += __shfl_down(acc, 2, 64);
  acc += __shfl_down(acc, 1, 64);
  if (sl == 0) h0[t*128 + f] = acc + b[f];
}

// ---- scalar spiral conv for IC=3 (encoder stage 0), reads f32 actor ----
__global__ void conv3_k(const float* __restrict__ x, const int* __restrict__ idx,
                        const float* __restrict__ W, const float* __restrict__ bias,
                        u16* __restrict__ out, int V, int OC){
  int i = blockIdx.x*blockDim.x + threadIdx.x;
  if (i >= V*OC) return;
  int o = i % OC; int v = i / OC;
  const float* wrow = W + (size_t)o*27;
  const int* vix = idx + v*9;
  float acc = bias[o];
  for (int s=0;s<9;s++){
    const float* xr = x + (size_t)vix[s]*3;
    acc += xr[0]*wrow[s*3] + xr[1]*wrow[s*3+1] + xr[2]*wrow[s*3+2];
  }
  if (acc < 0.f) acc = expm1f(acc);
  out[i] = fb(acc);
}

// ---- MFMA spiral conv: out[m,o], m=b*V+v, K=9*IC, gathered A, bf16 W ----
template<int IC, int BN, int BM>
__global__ void __launch_bounds__(256) conv_mfma(
    const u16* __restrict__ x, const int* __restrict__ idx,
    const u16* __restrict__ Wb, const float* __restrict__ bias,
    u16* __restrict__ out, int V, int OC, int M){
  constexpr int K = 9*IC;
  constexpr int NT = BN/16;
  constexpr int MT = BM/64;
  constexpr int LOG2 = (IC==32?5: IC==64?6: IC==128?7:8);
  constexpr int AST = 40;                 // LDS row stride (u16): 32 data + 8 pad
  __shared__ u16 Asm[BM*AST];
  __shared__ u16 Bsm[BN*AST];
  __shared__ int rowB[BM], rowV[BM];
  int t = threadIdx.x;
  int m0 = blockIdx.x*BM;
  int o0 = blockIdx.y*BN;
  if (t < BM){
    int mg = m0 + t;
    if (mg < M){ int b = mg / V; rowB[t] = b; rowV[t] = mg - b*V; }
    else rowB[t] = -1;
  }
  int lane = t & 63, wave = t >> 6;
  int quad = lane >> 4, col = lane & 15;
  float4v acc[MT][NT];
  #pragma unroll
  for (int mi=0;mi<MT;mi++)
    #pragma unroll
    for (int nt=0;nt<NT;nt++) acc[mi][nt] = (float4v)0.f;

  for (int kc = 0; kc < K/32; ++kc){
    int s  = (kc*32) >> LOG2;
    int c0 = (kc*32) & (IC-1);
    __syncthreads();
    #pragma unroll
    for (int rpt=0; rpt<MT; ++rpt){   // A tile: BM rows x 32 bf16 (gathered)
      int seg = t + 256*rpt;
      int arow = seg >> 2, aq = seg & 3;
      int b = rowB[arow];
      uint4 val = {0u,0u,0u,0u};
      if (b >= 0){
        int ix = idx[rowV[arow]*9 + s];
        val = *(const uint4*)(x + ((size_t)b*V + ix)*IC + c0 + aq*8);
      }
      *(uint4*)&Asm[arow*AST + aq*8] = val;
    }
    if (t < BN*4){ // B tile: BN rows of bf16 W, straight 16B copies
      int br = t >> 2, bq = t & 3;
      *(uint4*)&Bsm[br*AST + bq*8] =
          *(const uint4*)(Wb + (size_t)(o0+br)*K + kc*32 + bq*8);
    }
    __syncthreads();
    short8 a[MT];
    #pragma unroll
    for (int mi=0;mi<MT;mi++)
      a[mi] = *(const short8*)&Asm[(wave*MT*16 + mi*16 + col)*AST + quad*8];
    #pragma unroll
    for (int nt=0; nt<NT; ++nt){
      short8 bfr = *(const short8*)&Bsm[(nt*16 + col)*AST + quad*8];
      #pragma unroll
      for (int mi=0;mi<MT;mi++)
        acc[mi][nt] = __builtin_amdgcn_mfma_f32_16x16x32_bf16(a[mi], bfr, acc[mi][nt], 0, 0, 0);
    }
  }
  #pragma unroll
  for (int mi=0;mi<MT;mi++){
    #pragma unroll
    for (int nt=0; nt<NT; ++nt){
      int o = o0 + nt*16 + col;
      float bv = bias[o];
      #pragma unroll
      for (int r=0;r<4;r++){
        int mg = m0 + wave*MT*16 + mi*16 + quad*4 + r;
        if (mg < M){
          float val = acc[mi][nt][r] + bv;
          if (val < 0.f) val = expm1f(val);
          out[(size_t)mg*OC + o] = fb(val);
        }
      }
    }
  }
}

// ---- fused list builder for all 8 pool matrices ----
struct Lists {
  const int* rows[8];
  int nnz[8];
  int curoff[8];
  int lstoff[8];
};
__global__ void fill_all_k(Lists L, int* __restrict__ curBase, int* __restrict__ lstBase, int total){
  int i = blockIdx.x*blockDim.x + threadIdx.x;
  if (i >= total) return;
  int off = i, k = 0;
  while (off >= L.nnz[k]){ off -= L.nnz[k]; k++; }
  int r = L.rows[k][off];
  int p = atomicAdd(curBase + L.curoff[k] + r, 1);
  if (p < POOL_CAP) lstBase[L.lstoff[k] + r*POOL_CAP + p] = off;
}

// ---- pool gather, 4 channels/thread ----
__global__ void pool_g4_k(const u16* __restrict__ x, const int* __restrict__ cols,
                          const float* __restrict__ vals, const int* __restrict__ cur,
                          const int* __restrict__ lst, u16* __restrict__ out,
                          int B, int Vin, int Vout, int C){
  int C4 = C >> 2;
  int total = B*Vout*C4;
  int i = blockIdx.x*blockDim.x + threadIdx.x;
  if (i >= total) return;
  int c4 = i % C4; int tt = i / C4; int r = tt % Vout; int b = tt / Vout;
  int deg = cur[r]; if (deg > POOL_CAP) deg = POOL_CAP;
  const int* le = lst + r*POOL_CAP;
  float a0=0.f,a1=0.f,a2=0.f,a3=0.f;
  for (int k=0;k<deg;k++){
    int e = le[k];
    float v = vals[e];
    ushort4 xv = *(const ushort4*)(x + ((size_t)b*Vin + (size_t)cols[e])*C + c4*4);
    a0 += v*bf(xv.x); a1 += v*bf(xv.y); a2 += v*bf(xv.z); a3 += v*bf(xv.w);
  }
  ushort4 o; o.x=fb(a0); o.y=fb(a1); o.z=fb(a2); o.w=fb(a3);
  *(ushort4*)(out + ((size_t)b*Vout + (size_t)r)*C + c4*4) = o;
}

// ---- encoder linear, split-K + broadcast into h0[:,64:] ----
__global__ void __launch_bounds__(256) enc_lin_k(
    const u16* __restrict__ x, const float* __restrict__ W,
    const float* __restrict__ b, float* __restrict__ h0){
  int f = blockIdx.x;          // 64 blocks
  int t = threadIdx.x;         // 256
  const ushort4* x4 = (const ushort4*)x;
  const float4* w4 = (const float4*)(W + (size_t)f*5120);
  float acc = 0.f;
  for (int k=t; k<1280; k+=256){
    ushort4 xv = x4[k]; float4 wv = w4[k];
    acc += bf(xv.x)*wv.x + bf(xv.y)*wv.y + bf(xv.z)*wv.z + bf(xv.w)*wv.w;
  }
  #pragma unroll
  for (int off=32; off; off>>=1) acc += __shfl_down(acc, off, 64);
  __shared__ float red[4];
  if ((t & 63) == 0) red[t>>6] = acc;
  __syncthreads();
  if (t < 32){
    float zf = b[f] + red[0] + red[1] + red[2] + red[3];
    h0[t*128 + 64 + f] = zf;
  }
}

// ---- LSTM v3: bf16 LDS activations, packed-bf16 reg weights,
//      per-gate pre-activation (R7: LDS instr throughput was the limiter) ----
__device__ __forceinline__ float sigm(float x){ return 1.f/(1.f+__expf(-x)); }
__device__ __forceinline__ float tanhfast(float x){ return 1.f - 2.f/(__expf(2.f*x)+1.f); }

template<int IN_DIM>
__device__ __forceinline__ void lstm_layer(
    int j, bool rev,
    const float* __restrict__ Wih, const float* __restrict__ Whh,
    const float* __restrict__ bih, const float* __restrict__ bhh,
    const u16* __restrict__ xbuf, u16* __restrict__ obuf_d,
    u16* __restrict__ hsd, float* __restrict__ csd, float* __restrict__ gsd){
  unsigned wih[IN_DIM/2];
  #pragma unroll
  for (int k=0;k<IN_DIM/2;k++){
    float2 w = *(const float2*)&Wih[(size_t)j*IN_DIM + 2*k];
    wih[k] = ((unsigned)fb(w.x)) | (((unsigned)fb(w.y))<<16);
  }
  unsigned whh[16];
  #pragma unroll
  for (int k=0;k<16;k++){
    float2 w = *(const float2*)&Whh[(size_t)j*32 + 2*k];
    whh[k] = ((unsigned)fb(w.x)) | (((unsigned)fb(w.y))<<16);
  }
  float bias = bih[j] + bhh[j];
  int gtype = j >> 5;   // 0:i 1:f 2:g 3:o
  if (j < 32){ hsd[j]=0; csd[j]=0.f; }
  __syncthreads();

  for (int s=0;s<32;s++){
    int tx = rev ? (31-s) : s;
    float a0=0.f, a1=0.f, a2=0.f, a3=0.f;
    const uint4* x4 = (const uint4*)&xbuf[tx*IN_DIM];
    #pragma unroll
    for (int k=0;k<IN_DIM/8;k++){
      uint4 xv = x4[k];
      unsigned w0=wih[4*k], w1=wih[4*k+1], w2=wih[4*k+2], w3=wih[4*k+3];
      a0 = fmaf(lo16(xv.x), lo16(w0), a0);
      a0 = fmaf(hi16(xv.x), hi16(w0), a0);
      a1 = fmaf(lo16(xv.y), lo16(w1), a1);
      a1 = fmaf(hi16(xv.y), hi16(w1), a1);
      a2 = fmaf(lo16(xv.z), lo16(w2), a2);
      a2 = fmaf(hi16(xv.z), hi16(w2), a2);
      a3 = fmaf(lo16(xv.w), lo16(w3), a3);
      a3 = fmaf(hi16(xv.w), hi16(w3), a3);
    }
    const uint4* h4 = (const uint4*)hsd;
    #pragma unroll
    for (int k=0;k<4;k++){
      uint4 hv = h4[k];
      unsigned w0=whh[4*k], w1=whh[4*k+1], w2=whh[4*k+2], w3=whh[4*k+3];
      a0 = fmaf(lo16(hv.x), lo16(w0), a0);
      a0 = fmaf(hi16(hv.x), hi16(w0), a0);
      a1 = fmaf(lo16(hv.y), lo16(w1), a1);
      a1 = fmaf(hi16(hv.y), hi16(w1), a1);
      a2 = fmaf(lo16(hv.z), lo16(w2), a2);
      a2 = fmaf(hi16(hv.z), hi16(w2), a2);
      a3 = fmaf(lo16(hv.w), lo16(w3), a3);
      a3 = fmaf(hi16(hv.w), hi16(w3), a3);
    }
    float g = bias + ((a0+a1) + (a2+a3));
    gsd[j] = (gtype == 2) ? tanhfast(g) : sigm(g);   // pre-activated gates
    __syncthreads();
    if (j < 32){
      float cn = gsd[32+j]*csd[j] + gsd[j]*gsd[64+j];
      float hn = gsd[96+j]*tanhfast(cn);
      csd[j]=cn;
      u16 hb = fb(hn);
      hsd[j]=hb;
      obuf_d[tx*64 + j] = hb;
    }
    __syncthreads();
  }
}

__global__ void __launch_bounds__(256) lstm3_k(
    const float* __restrict__ h0,
    const float* __restrict__ l0_Wih, const float* __restrict__ l0_Whh,
    const float* __restrict__ l0_bih, const float* __restrict__ l0_bhh,
    const float* __restrict__ l12_Wih, const float* __restrict__ l12_Whh,
    const float* __restrict__ l12_bih, const float* __restrict__ l12_bhh,
    float* __restrict__ latent){
  __shared__ __align__(16) u16 xbuf[32*128];
  __shared__ __align__(16) u16 obuf[32*64];
  __shared__ __align__(16) u16 hsh[2][32];
  __shared__ __align__(16) float cs[2][32];
  __shared__ __align__(16) float gs[2][128];
  int t = threadIdx.x;
  int dir = t >> 7, j = t & 127;
  bool rev = (dir == 1);
  for (int i=t;i<32*128;i+=256) xbuf[i] = fb(h0[i]);
  __syncthreads();

  lstm_layer<128>(j, rev, l0_Wih + dir*128*128, l0_Whh + dir*128*32,
                  l0_bih + dir*128, l0_bhh + dir*128,
                  xbuf, obuf + dir*32, hsh[dir], cs[dir], gs[dir]);
  __syncthreads();
  for (int i=t;i<32*16;i+=256) ((uint4*)xbuf)[i] = ((const uint4*)obuf)[i];
  __syncthreads();

  for (int layer=1; layer<3; layer++){
    int m = (layer-1)*2 + dir;
    lstm_layer<64>(j, rev, l12_Wih + m*128*64, l12_Whh + m*128*32,
                   l12_bih + m*128, l12_bhh + m*128,
                   xbuf, obuf + dir*32, hsh[dir], cs[dir], gs[dir]);
    __syncthreads();
    if (layer < 2){
      for (int i=t;i<32*16;i+=256) ((uint4*)xbuf)[i] = ((const uint4*)obuf)[i];
      __syncthreads();
    }
  }
  for (int i=t;i<32*64;i+=256) latent[i] = bf(obuf[i]);
}

// ---- decoder linear: y[t,r] = b[r] + sum_{k<64} latent[t,k]*W[r,k] -> bf16 ----
__global__ void dec_lin_k(const float* __restrict__ latent, const float* __restrict__ W,
                          const float* __restrict__ b, u16* __restrict__ y){
  int i = blockIdx.x*blockDim.x + threadIdx.x;
  if (i >= 32*5120) return;
  int r = i % 5120, t = i / 5120;
  const float4* x4 = (const float4*)(latent + t*64);
  const float4* w4 = (const float4*)(W + (size_t)r*64);
  float acc = b[r];
  #pragma unroll
  for (int k=0;k<16;k++){
    float4 xv=x4[k]; float4 wv=w4[k];
    acc += xv.x*wv.x+xv.y*wv.y+xv.z*wv.z+xv.w*wv.w;
  }
  y[i] = fb(acc);
}

// ---- final conv (OC=3, IC=32, no ELU) + actor residual -> f32 out ----
__global__ void final_k(const u16* __restrict__ x, const int* __restrict__ idx,
                        const float* __restrict__ W, const float* __restrict__ bias,
                        const float* __restrict__ actor, float* __restrict__ out){
  __shared__ float Wsm[3*288];
  __shared__ float bsm[3];
  int t = threadIdx.x;
  for (int i=t;i<864;i+=256) Wsm[i]=W[i];
  if (t<3) bsm[t]=bias[t];
  __syncthreads();
  int g = blockIdx.x*256 + t;
  if (g >= 32*5023) return;
  int v = g % 5023, b = g / 5023;
  const u16* xb = x + (size_t)b*5023*32;
  const int* vix = idx + v*9;
  float a0=bsm[0], a1=bsm[1], a2=bsm[2];
  for (int s=0;s<9;s++){
    const ushort4* xr = (const ushort4*)(xb + (size_t)vix[s]*32);
    #pragma unroll
    for (int k=0;k<8;k++){
      ushort4 xv = xr[k];
      float x0=bf(xv.x), x1=bf(xv.y), x2=bf(xv.z), x3=bf(xv.w);
      int kk = s*32 + k*4;
      a0 += x0*Wsm[kk] + x1*Wsm[kk+1] + x2*Wsm[kk+2] + x3*Wsm[kk+3];
      a1 += x0*Wsm[288+kk] + x1*Wsm[288+kk+1] + x2*Wsm[288+kk+2] + x3*Wsm[288+kk+3];
      a2 += x0*Wsm[576+kk] + x1*Wsm[576+kk+1] + x2*Wsm[576+kk+2] + x3*Wsm[576+kk+3];
    }
  }
  out[(size_t)g*3+0] = a0 + actor[v*3+0];
  out[(size_t)g*3+1] = a1 + actor[v*3+1];
  out[(size_t)g*3+2] = a2 + actor[v*3+2];
}

extern "C" void kernel_launch(void* const* d_in, const int* in_sizes, int n_in,
                              void* d_out, int out_size, void* d_ws, size_t ws_size,
                              hipStream_t stream){
  (void)in_sizes; (void)n_in; (void)out_size; (void)ws_size;

  const float* audio = (const float*)d_in[0];
  const float* actor = (const float*)d_in[2];
  const int* sp[4]   = {(const int*)d_in[3],(const int*)d_in[4],(const int*)d_in[5],(const int*)d_in[6]};
  const int* drows[4]; const int* dcols[4]; const float* dvals[4];
  for (int i=0;i<4;i++){ drows[i]=(const int*)d_in[7+3*i]; dcols[i]=(const int*)d_in[8+3*i]; dvals[i]=(const float*)d_in[9+3*i]; }
  const int* urows[4]; const int* ucols[4]; const float* uvals[4];
  for (int i=0;i<4;i++){ urows[i]=(const int*)d_in[19+3*i]; ucols[i]=(const int*)d_in[20+3*i]; uvals[i]=(const float*)d_in[21+3*i]; }
  const float* encW[4]={(const float*)d_in[31],(const float*)d_in[33],(const float*)d_in[35],(const float*)d_in[37]};
  const float* encB[4]={(const float*)d_in[32],(const float*)d_in[34],(const float*)d_in[36],(const float*)d_in[38]};
  const float* enc_lin_W=(const float*)d_in[39]; const float* enc_lin_b=(const float*)d_in[40];
  const float* dec_lin_W=(const float*)d_in[41]; const float* dec_lin_b=(const float*)d_in[42];
  const float* decW[5]={(const float*)d_in[43],(const float*)d_in[45],(const float*)d_in[47],(const float*)d_in[49],(const float*)d_in[51]};
  const float* decB[5]={(const float*)d_in[44],(const float*)d_in[46],(const float*)d_in[48],(const float*)d_in[50],(const float*)d_in[52]};
  const float* audW=(const float*)d_in[53]; const float* audB=(const float*)d_in[54];
  const float* l0_Wih=(const float*)d_in[55]; const float* l0_Whh=(const float*)d_in[56];
  const float* l0_bih=(const float*)d_in[57]; const float* l0_bhh=(const float*)d_in[58];
  const float* l12_Wih=(const float*)d_in[59]; const float* l12_Whh=(const float*)d_in[60];
  const float* l12_bih=(const float*)d_in[61]; const float* l12_bhh=(const float*)d_in[62];
  float* out = (float*)d_out;

  // ---- workspace layout (bytes) ----
  char* base = (char*)d_ws;
  u16* A  = (u16*)base;                          // 10,287,104 B
  u16* Bb = (u16*)(base + 10287104);             // 20,574,208 B
  int* curBase = (int*)(base + 30891520);        // 8341 ints
  int* lstBase = (int*)(base + 30924928);        // 533,824 ints -> ends 33,060,224
  u16* Wbf = (u16*)(base + 33060224);            // 1,363,968 bf16 = 2,727,936 B
  float* sm = (float*)(base + 35788160);
  float* h0     = sm;                 // 4096
  float* latent = sm + 4096;          // 2048

  // bf16 weight segment offsets (elements): enc1,enc2,enc3,dec0,dec1,dec2,dec3
  const int wsz[7] = {64*288, 128*576, 256*1152, 256*2304, 128*2304, 64*1152, 32*576};
  WCast WC; int wcum = 0;
  const float* wsrc[7] = {encW[1],encW[2],encW[3],decW[0],decW[1],decW[2],decW[3]};
  int wo[7];
  for (int k=0;k<7;k++){ WC.src[k]=wsrc[k]; WC.cum[k]=wcum; wo[k]=wcum; wcum+=wsz[k]; }
  WC.cum[7]=wcum;
  cast_all_k<<<CDIV(wcum,256),256,0,stream>>>(WC, Wbf, wcum);

  // pool bookkeeping: d0,d1,d2,d3,u0,u1,u2,u3
  const int pVout[8] = {1256,314,79,20,5023,1256,314,79};
  const int pNnz[8]  = {3768,942,237,60,15069,3768,942,237};
  Lists L; int curoff=0, lstoff=0, totnnz=0;
  const int* prow[8] = {drows[0],drows[1],drows[2],drows[3],urows[0],urows[1],urows[2],urows[3]};
  int curo[8], lsto[8];
  for (int k=0;k<8;k++){
    L.rows[k]=prow[k]; L.nnz[k]=pNnz[k];
    L.curoff[k]=curoff; L.lstoff[k]=lstoff;
    curo[k]=curoff; lsto[k]=lstoff;
    curoff += pVout[k]; lstoff += pVout[k]*POOL_CAP; totnnz += pNnz[k];
  }
  hipMemsetAsync(curBase, 0, (size_t)curoff*4, stream);
  fill_all_k<<<CDIV(totnnz,256),256,0,stream>>>(L, curBase, lstBase, totnnz);

  // ---- audio path (writes h0[:, :64]) ----
  audio_emb_k<<<32,256,0,stream>>>(audio, audW, audB, h0);

  // ---- encoder (B=1) ----
  conv3_k<<<CDIV(5023*32,256),256,0,stream>>>(actor, sp[0], encW[0], encB[0], A, 5023, 32);
  pool_g4_k<<<CDIV(1256*8,256),256,0,stream>>>(A, dcols[0], dvals[0], curBase+curo[0], lstBase+lsto[0], Bb, 1, 5023, 1256, 32);
  conv_mfma<32,64,64><<<dim3(CDIV(1256,64),1),256,0,stream>>>(Bb, sp[1], Wbf+wo[0], encB[1], A, 1256, 64, 1256);
  pool_g4_k<<<CDIV(314*16,256),256,0,stream>>>(A, dcols[1], dvals[1], curBase+curo[1], lstBase+lsto[1], Bb, 1, 1256, 314, 64);
  conv_mfma<64,64,64><<<dim3(CDIV(314,64),2),256,0,stream>>>(Bb, sp[2], Wbf+wo[1], encB[2], A, 314, 128, 314);
  pool_g4_k<<<CDIV(79*32,256),256,0,stream>>>(A, dcols[2], dvals[2], curBase+curo[2], lstBase+lsto[2], Bb, 1, 314, 79, 128);
  conv_mfma<128,64,64><<<dim3(CDIV(79,64),4),256,0,stream>>>(Bb, sp[3], Wbf+wo[2], encB[3], A, 79, 256, 79);
  pool_g4_k<<<CDIV(20*64,256),256,0,stream>>>(A, dcols[3], dvals[3], curBase+curo[3], lstBase+lsto[3], Bb, 1, 79, 20, 256);

  enc_lin_k<<<64,256,0,stream>>>(Bb, enc_lin_W, enc_lin_b, h0);

  // ---- LSTM (serial, single block, reg-resident weights, bf16 LDS) ----
  lstm3_k<<<1,256,0,stream>>>(h0, l0_Wih, l0_Whh, l0_bih, l0_bhh,
                              l12_Wih, l12_Whh, l12_bih, l12_bhh, latent);

  // ---- decoder (B=32) ----
  dec_lin_k<<<CDIV(32*5120,256),256,0,stream>>>(latent, dec_lin_W, dec_lin_b, A); // (32,20,256)

  // j=3: up-pool u3 (20->79,C=256), conv IC=256 OC=256
  pool_g4_k<<<CDIV(32*79*64,256),256,0,stream>>>(A, ucols[3], uvals[3], curBase+curo[7], lstBase+lsto[7], Bb, 32, 20, 79, 256);
  conv_mfma<256,64,64><<<dim3(CDIV(2528,64),4),256,0,stream>>>(Bb, sp[3], Wbf+wo[3], decB[0], A, 79, 256, 2528);

  // j=2: up-pool u2 (79->314,C=256), conv IC=256 OC=128
  pool_g4_k<<<CDIV(32*314*64,256),256,0,stream>>>(A, ucols[2], uvals[2], curBase+curo[6], lstBase+lsto[6], Bb, 32, 79, 314, 256);
  conv_mfma<256,64,128><<<dim3(CDIV(10048,128),2),256,0,stream>>>(Bb, sp[2], Wbf+wo[4], decB[1], A, 314, 128, 10048);

  // j=1: up-pool u1 (314->1256,C=128), conv IC=128 OC=64
  pool_g4_k<<<CDIV(32*1256*32,256),256,0,stream>>>(A, ucols[1], uvals[1], curBase+curo[5], lstBase+lsto[5], Bb, 32, 314, 1256, 128);
  conv_mfma<128,64,128><<<dim3(CDIV(40192,128),1),256,0,stream>>>(Bb, sp[1], Wbf+wo[5], decB[2], A, 1256, 64, 40192);

  // j=0: up-pool u0 (1256->5023,C=64), conv IC=64 OC=32
  pool_g4_k<<<CDIV(32*5023*16,256),256,0,stream>>>(A, ucols[0], uvals[0], curBase+curo[4], lstBase+lsto[4], Bb, 32, 1256, 5023, 64);
  conv_mfma<64,32,128><<<dim3(CDIV(160736,128),1),256,0,stream>>>(Bb, sp[0], Wbf+wo[6], decB[3], A, 5023, 32, 160736);

  // final conv (288->3) + actor residual -> f32 out
  final_k<<<CDIV(32*5023,256),256,0,stream>>>(A, sp[0], decW[4], decB[4], actor, out);
}

// Round 9
// 698.070 us; speedup vs baseline: 8.5198x; 1.0448x over previous
//
#include <hip/hip_runtime.h>
#include <cstdint>
#include <cstddef>

// SpiralAutoencoder forward, MI355X gfx950.
// Inputs f32, indices i32, output f32. Internal activations bf16, fp32 accum.
// Spiral convs = MFMA bf16 GEMM (16x16x32), weights pre-cast to bf16 in ws.
// LSTM v4: x-projection hoisted out of the serial loop (done by MFMA for all
//   timesteps in parallel); recurrence keeps only Whh*h + shuffle-gathered
//   gates, c in registers, ONE barrier per step.
//   (R7/R8 postmortem: serial critical path, not VALU/LDS throughput.)
// Pools = gather via device-built capped per-row edge lists (fused builder).

typedef unsigned short u16;
typedef __attribute__((ext_vector_type(8))) short short8;
typedef __attribute__((ext_vector_type(4))) float float4v;
#define CDIV(a,b) (((a)+(b)-1)/(b))
#define POOL_CAP 64

__device__ __forceinline__ float bf(u16 u){ return __uint_as_float(((unsigned)u)<<16); }
__device__ __forceinline__ u16 fb(float x){
  unsigned u = __float_as_uint(x);
  unsigned r = u + 0x7fffu + ((u>>16)&1u);   // RNE
  return (u16)(r>>16);
}
__device__ __forceinline__ float lo16(unsigned u){ return __uint_as_float(u<<16); }
__device__ __forceinline__ float hi16(unsigned u){ return __uint_as_float(u & 0xffff0000u); }

// ---- fused f32->bf16 cast of all conv weights ----
struct WCast { const float* src[7]; int cum[8]; };
__global__ void cast_all_k(WCast C, u16* __restrict__ dst, int total){
  int i = blockIdx.x*blockDim.x + threadIdx.x;
  if (i >= total) return;
  int k = 0;
  while (i >= C.cum[k+1]) k++;
  dst[i] = fb(C.src[k][i - C.cum[k]]);
}

// ---- audio embedding: (32,1536)@(64,1536)^T + b -> h0[t*128+f] (f<64) ----
__global__ void audio_emb_k(const float* __restrict__ ah, const float* __restrict__ W,
                            const float* __restrict__ b, float* __restrict__ h0){
  int t = blockIdx.x;
  int f = threadIdx.x >> 2, sl = threadIdx.x & 3;
  const float4* x4 = (const float4*)(ah + t*1536);
  const float4* w4 = (const float4*)(W + f*1536);
  float acc = 0.f;
  for (int k=sl; k<384; k+=4){
    float4 xv = x4[k], wv = w4[k];
    acc += xv.x*wv.x + xv.y*wv.y + xv.z*wv.z + xv.w*wv.w;
  }
  acc += __shfl_down(acc, 2, 64);
  acc += __shfl_down(acc, 1, 64);
  if (sl == 0) h0[t*128 + f] = acc + b[f];
}

// ---- scalar spiral conv for IC=3 (encoder stage 0), reads f32 actor ----
__global__ void conv3_k(const float* __restrict__ x, const int* __restrict__ idx,
                        const float* __restrict__ W, const float* __restrict__ bias,
                        u16* __restrict__ out, int V, int OC){
  int i = blockIdx.x*blockDim.x + threadIdx.x;
  if (i >= V*OC) return;
  int o = i % OC; int v = i / OC;
  const float* wrow = W + (size_t)o*27;
  const int* vix = idx + v*9;
  float acc = bias[o];
  for (int s=0;s<9;s++){
    const float* xr = x + (size_t)vix[s]*3;
    acc += xr[0]*wrow[s*3] + xr[1]*wrow[s*3+1] + xr[2]*wrow[s*3+2];
  }
  if (acc < 0.f) acc = expm1f(acc);
  out[i] = fb(acc);
}

// ---- MFMA spiral conv: out[m,o], m=b*V+v, K=9*IC, gathered A, bf16 W ----
template<int IC, int BN, int BM>
__global__ void __launch_bounds__(256) conv_mfma(
    const u16* __restrict__ x, const int* __restrict__ idx,
    const u16* __restrict__ Wb, const float* __restrict__ bias,
    u16* __restrict__ out, int V, int OC, int M){
  constexpr int K = 9*IC;
  constexpr int NT = BN/16;
  constexpr int MT = BM/64;
  constexpr int LOG2 = (IC==32?5: IC==64?6: IC==128?7:8);
  constexpr int AST = 40;                 // LDS row stride (u16): 32 data + 8 pad
  __shared__ u16 Asm[BM*AST];
  __shared__ u16 Bsm[BN*AST];
  __shared__ int rowB[BM], rowV[BM];
  int t = threadIdx.x;
  int m0 = blockIdx.x*BM;
  int o0 = blockIdx.y*BN;
  if (t < BM){
    int mg = m0 + t;
    if (mg < M){ int b = mg / V; rowB[t] = b; rowV[t] = mg - b*V; }
    else rowB[t] = -1;
  }
  int lane = t & 63, wave = t >> 6;
  int quad = lane >> 4, col = lane & 15;
  float4v acc[MT][NT];
  #pragma unroll
  for (int mi=0;mi<MT;mi++)
    #pragma unroll
    for (int nt=0;nt<NT;nt++) acc[mi][nt] = (float4v)0.f;

  for (int kc = 0; kc < K/32; ++kc){
    int s  = (kc*32) >> LOG2;
    int c0 = (kc*32) & (IC-1);
    __syncthreads();
    #pragma unroll
    for (int rpt=0; rpt<MT; ++rpt){   // A tile: BM rows x 32 bf16 (gathered)
      int seg = t + 256*rpt;
      int arow = seg >> 2, aq = seg & 3;
      int b = rowB[arow];
      uint4 val = {0u,0u,0u,0u};
      if (b >= 0){
        int ix = idx[rowV[arow]*9 + s];
        val = *(const uint4*)(x + ((size_t)b*V + ix)*IC + c0 + aq*8);
      }
      *(uint4*)&Asm[arow*AST + aq*8] = val;
    }
    if (t < BN*4){ // B tile: BN rows of bf16 W, straight 16B copies
      int br = t >> 2, bq = t & 3;
      *(uint4*)&Bsm[br*AST + bq*8] =
          *(const uint4*)(Wb + (size_t)(o0+br)*K + kc*32 + bq*8);
    }
    __syncthreads();
    short8 a[MT];
    #pragma unroll
    for (int mi=0;mi<MT;mi++)
      a[mi] = *(const short8*)&Asm[(wave*MT*16 + mi*16 + col)*AST + quad*8];
    #pragma unroll
    for (int nt=0; nt<NT; ++nt){
      short8 bfr = *(const short8*)&Bsm[(nt*16 + col)*AST + quad*8];
      #pragma unroll
      for (int mi=0;mi<MT;mi++)
        acc[mi][nt] = __builtin_amdgcn_mfma_f32_16x16x32_bf16(a[mi], bfr, acc[mi][nt], 0, 0, 0);
    }
  }
  #pragma unroll
  for (int mi=0;mi<MT;mi++){
    #pragma unroll
    for (int nt=0; nt<NT; ++nt){
      int o = o0 + nt*16 + col;
      float bv = bias[o];
      #pragma unroll
      for (int r=0;r<4;r++){
        int mg = m0 + wave*MT*16 + mi*16 + quad*4 + r;
        if (mg < M){
          float val = acc[mi][nt][r] + bv;
          if (val < 0.f) val = expm1f(val);
          out[(size_t)mg*OC + o] = fb(val);
        }
      }
    }
  }
}

// ---- fused list builder for all 8 pool matrices ----
struct Lists {
  const int* rows[8];
  int nnz[8];
  int curoff[8];
  int lstoff[8];
};
__global__ void fill_all_k(Lists L, int* __restrict__ curBase, int* __restrict__ lstBase, int total){
  int i = blockIdx.x*blockDim.x + threadIdx.x;
  if (i >= total) return;
  int off = i, k = 0;
  while (off >= L.nnz[k]){ off -= L.nnz[k]; k++; }
  int r = L.rows[k][off];
  int p = atomicAdd(curBase + L.curoff[k] + r, 1);
  if (p < POOL_CAP) lstBase[L.lstoff[k] + r*POOL_CAP + p] = off;
}

// ---- pool gather, 4 channels/thread ----
__global__ void pool_g4_k(const u16* __restrict__ x, const int* __restrict__ cols,
                          const float* __restrict__ vals, const int* __restrict__ cur,
                          const int* __restrict__ lst, u16* __restrict__ out,
                          int B, int Vin, int Vout, int C){
  int C4 = C >> 2;
  int total = B*Vout*C4;
  int i = blockIdx.x*blockDim.x + threadIdx.x;
  if (i >= total) return;
  int c4 = i % C4; int tt = i / C4; int r = tt % Vout; int b = tt / Vout;
  int deg = cur[r]; if (deg > POOL_CAP) deg = POOL_CAP;
  const int* le = lst + r*POOL_CAP;
  float a0=0.f,a1=0.f,a2=0.f,a3=0.f;
  for (int k=0;k<deg;k++){
    int e = le[k];
    float v = vals[e];
    ushort4 xv = *(const ushort4*)(x + ((size_t)b*Vin + (size_t)cols[e])*C + c4*4);
    a0 += v*bf(xv.x); a1 += v*bf(xv.y); a2 += v*bf(xv.z); a3 += v*bf(xv.w);
  }
  ushort4 o; o.x=fb(a0); o.y=fb(a1); o.z=fb(a2); o.w=fb(a3);
  *(ushort4*)(out + ((size_t)b*Vout + (size_t)r)*C + c4*4) = o;
}

// ---- encoder linear, split-K + broadcast into h0[:,64:] ----
__global__ void __launch_bounds__(256) enc_lin_k(
    const u16* __restrict__ x, const float* __restrict__ W,
    const float* __restrict__ b, float* __restrict__ h0){
  int f = blockIdx.x;          // 64 blocks
  int t = threadIdx.x;         // 256
  const ushort4* x4 = (const ushort4*)x;
  const float4* w4 = (const float4*)(W + (size_t)f*5120);
  float acc = 0.f;
  for (int k=t; k<1280; k+=256){
    ushort4 xv = x4[k]; float4 wv = w4[k];
    acc += bf(xv.x)*wv.x + bf(xv.y)*wv.y + bf(xv.z)*wv.z + bf(xv.w)*wv.w;
  }
  #pragma unroll
  for (int off=32; off; off>>=1) acc += __shfl_down(acc, off, 64);
  __shared__ float red[4];
  if ((t & 63) == 0) red[t>>6] = acc;
  __syncthreads();
  if (t < 32){
    float zf = b[f] + red[0] + red[1] + red[2] + red[3];
    h0[t*128 + 64 + f] = zf;
  }
}

// ---- LSTM v4 ----
__device__ __forceinline__ float sigm(float x){ return 1.f/(1.f+__expf(-x)); }
__device__ __forceinline__ float tanhfast(float x){ return 1.f - 2.f/(__expf(2.f*x)+1.f); }

__global__ void __launch_bounds__(256) lstm3_k(
    const float* __restrict__ h0,
    const float* __restrict__ l0_Wih, const float* __restrict__ l0_Whh,
    const float* __restrict__ l0_bih, const float* __restrict__ l0_bhh,
    const float* __restrict__ l12_Wih, const float* __restrict__ l12_Whh,
    const float* __restrict__ l12_bih, const float* __restrict__ l12_bhh,
    float* __restrict__ latent){
  __shared__ __align__(16) u16 xb[32*136];       // x, bf16, stride 136
  __shared__ __align__(16) float xp[2*32*128];   // xproj+bias, [dir][t][j]
  __shared__ __align__(16) u16 obuf[32*64];
  __shared__ __align__(16) u16 hsh[2][32];
  __shared__ float bias_l[256];
  int t = threadIdx.x;
  int lane = t & 63, wave = t >> 6;
  int quad = lane >> 4, col = lane & 15;
  int dir = t >> 7;                 // recurrence: waves 0,1 -> dir0; 2,3 -> dir1
  bool rev = (dir == 1);
  int w2 = (t >> 6) & 1;            // which wave within dir
  int unit = w2*16 + col;           // hidden unit 0..31
  int jj = quad*32 + unit;          // Wih/Whh row (gate*32+unit)

  for (int i=t;i<32*128;i+=256){ int tt=i>>7, k=i&127; xb[tt*136+k]=fb(h0[i]); }

  for (int layer=0; layer<3; layer++){
    int IN = (layer==0)?128:64;
    const float *Wih,*Whh,*bih,*bhh;
    if (layer==0){ Wih=l0_Wih; Whh=l0_Whh; bih=l0_bih; bhh=l0_bhh; }
    else {
      int mb=(layer-1)*2;
      Wih=l12_Wih + (size_t)mb*128*64; Whh=l12_Whh + (size_t)mb*128*32;
      bih=l12_bih + mb*128; bhh=l12_bhh + mb*128;
    }
    // per-thread recurrence weights (row jj of this dir's Whh), packed bf16
    const float* WhhD = Whh + (size_t)dir*128*32 + (size_t)jj*32;
    unsigned whh[16];
    #pragma unroll
    for (int k=0;k<16;k++){
      float2 w = *(const float2*)&WhhD[2*k];
      whh[k] = ((unsigned)fb(w.x)) | (((unsigned)fb(w.y))<<16);
    }
    bias_l[t] = bih[dir*128 + (t&127)] + bhh[dir*128 + (t&127)];
    if (quad == 0) hsh[dir][unit] = 0;
    float creg = 0.f;                // c for this lane's unit (quad==0 lanes)
    __syncthreads();

    // ---- Phase A: xproj[dirA][t][j] = x @ WihA^T + bias, via MFMA ----
    {
      int dirA = wave >> 1, o0 = (wave & 1)*64;
      const float* WA = Wih + (size_t)dirA*128*IN;
      float4v acc[2][4];
      #pragma unroll
      for (int mi=0;mi<2;mi++)
        #pragma unroll
        for (int nt=0;nt<4;nt++) acc[mi][nt] = (float4v)0.f;
      for (int kc=0; kc<IN/32; ++kc){
        short8 bfrag[4];
        #pragma unroll
        for (int nt=0;nt<4;nt++){
          const float* src = WA + (size_t)(o0+nt*16+col)*IN + kc*32 + quad*8;
          float4 w0 = *(const float4*)src;
          float4 w1 = *(const float4*)(src+4);
          alignas(16) u16 tmp[8] = {fb(w0.x),fb(w0.y),fb(w0.z),fb(w0.w),
                                    fb(w1.x),fb(w1.y),fb(w1.z),fb(w1.w)};
          bfrag[nt] = *(const short8*)tmp;
        }
        short8 afrag[2];
        #pragma unroll
        for (int mi=0;mi<2;mi++)
          afrag[mi] = *(const short8*)&xb[(mi*16+col)*136 + kc*32 + quad*8];
        #pragma unroll
        for (int nt=0;nt<4;nt++)
          #pragma unroll
          for (int mi=0;mi<2;mi++)
            acc[mi][nt] = __builtin_amdgcn_mfma_f32_16x16x32_bf16(afrag[mi], bfrag[nt], acc[mi][nt], 0, 0, 0);
      }
      #pragma unroll
      for (int mi=0;mi<2;mi++)
        #pragma unroll
        for (int nt=0;nt<4;nt++){
          int j = o0 + nt*16 + col;
          float bv = bias_l[dirA*128 + j];
          #pragma unroll
          for (int r=0;r<4;r++){
            int tt = mi*16 + quad*4 + r;
            xp[dirA*4096 + tt*128 + j] = acc[mi][nt][r] + bv;
          }
        }
    }
    __syncthreads();

    // ---- Phase B: recurrence, one barrier per step ----
    for (int s=0;s<32;s++){
      int tx = rev ? (31-s) : s;
      float g = xp[dir*4096 + tx*128 + jj];
      const uint4* h4 = (const uint4*)hsh[dir];
      float a0=0.f,a1=0.f,a2=0.f,a3=0.f;
      #pragma unroll
      for (int k=0;k<4;k++){
        uint4 hv = h4[k];
        unsigned u0=whh[4*k], u1=whh[4*k+1], u2=whh[4*k+2], u3=whh[4*k+3];
        a0 = fmaf(lo16(hv.x), lo16(u0), a0);
        a0 = fmaf(hi16(hv.x), hi16(u0), a0);
        a1 = fmaf(lo16(hv.y), lo16(u1), a1);
        a1 = fmaf(hi16(hv.y), hi16(u1), a1);
        a2 = fmaf(lo16(hv.z), lo16(u2), a2);
        a2 = fmaf(hi16(hv.z), hi16(u2), a2);
        a3 = fmaf(lo16(hv.w), lo16(u3), a3);
        a3 = fmaf(hi16(hv.w), hi16(u3), a3);
      }
      g += (a0+a1) + (a2+a3);
      float act = (quad == 2) ? tanhfast(g) : sigm(g);   // gate = quad
      // gather 4 gates of this unit via in-wave shuffles
      float gi = __shfl(act, col, 64);
      float gf = __shfl(act, 16+col, 64);
      float gg = __shfl(act, 32+col, 64);
      float go = __shfl(act, 48+col, 64);
      if (quad == 0){
        float cn = gf*creg + gi*gg;
        float hn = go*tanhfast(cn);
        creg = cn;
        u16 hb = fb(hn);
        hsh[dir][unit] = hb;
        obuf[tx*64 + dir*32 + unit] = hb;
      }
      __syncthreads();
    }
    if (layer < 2){
      for (int i=t;i<32*64;i+=256){ int tt=i>>6, k=i&63; xb[tt*136+k]=obuf[i]; }
      __syncthreads();
    }
  }
  for (int i=t;i<32*64;i+=256) latent[i] = bf(obuf[i]);
}

// ---- decoder linear: y[t,r] = b[r] + sum_{k<64} latent[t,k]*W[r,k] -> bf16 ----
__global__ void dec_lin_k(const float* __restrict__ latent, const float* __restrict__ W,
                          const float* __restrict__ b, u16* __restrict__ y){
  int i = blockIdx.x*blockDim.x + threadIdx.x;
  if (i >= 32*5120) return;
  int r = i % 5120, t = i / 5120;
  const float4* x4 = (const float4*)(latent + t*64);
  const float4* w4 = (const float4*)(W + (size_t)r*64);
  float acc = b[r];
  #pragma unroll
  for (int k=0;k<16;k++){
    float4 xv=x4[k]; float4 wv=w4[k];
    acc += xv.x*wv.x+xv.y*wv.y+xv.z*wv.z+xv.w*wv.w;
  }
  y[i] = fb(acc);
}

// ---- final conv (OC=3, IC=32, no ELU) + actor residual -> f32 out ----
__global__ void final_k(const u16* __restrict__ x, const int* __restrict__ idx,
                        const float* __restrict__ W, const float* __restrict__ bias,
                        const float* __restrict__ actor, float* __restrict__ out){
  __shared__ float Wsm[3*288];
  __shared__ float bsm[3];
  int t = threadIdx.x;
  for (int i=t;i<864;i+=256) Wsm[i]=W[i];
  if (t<3) bsm[t]=bias[t];
  __syncthreads();
  int g = blockIdx.x*256 + t;
  if (g >= 32*5023) return;
  int v = g % 5023, b = g / 5023;
  const u16* xb = x + (size_t)b*5023*32;
  const int* vix = idx + v*9;
  float a0=bsm[0], a1=bsm[1], a2=bsm[2];
  for (int s=0;s<9;s++){
    const ushort4* xr = (const ushort4*)(xb + (size_t)vix[s]*32);
    #pragma unroll
    for (int k=0;k<8;k++){
      ushort4 xv = xr[k];
      float x0=bf(xv.x), x1=bf(xv.y), x2=bf(xv.z), x3=bf(xv.w);
      int kk = s*32 + k*4;
      a0 += x0*Wsm[kk] + x1*Wsm[kk+1] + x2*Wsm[kk+2] + x3*Wsm[kk+3];
      a1 += x0*Wsm[288+kk] + x1*Wsm[288+kk+1] + x2*Wsm[288+kk+2] + x3*Wsm[288+kk+3];
      a2 += x0*Wsm[576+kk] + x1*Wsm[576+kk+1] + x2*Wsm[576+kk+2] + x3*Wsm[576+kk+3];
    }
  }
  out[(size_t)g*3+0] = a0 + actor[v*3+0];
  out[(size_t)g*3+1] = a1 + actor[v*3+1];
  out[(size_t)g*3+2] = a2 + actor[v*3+2];
}

extern "C" void kernel_launch(void* const* d_in, const int* in_sizes, int n_in,
                              void* d_out, int out_size, void* d_ws, size_t ws_size,
                              hipStream_t stream){
  (void)in_sizes; (void)n_in; (void)out_size; (void)ws_size;

  const float* audio = (const float*)d_in[0];
  const float* actor = (const float*)d_in[2];
  const int* sp[4]   = {(const int*)d_in[3],(const int*)d_in[4],(const int*)d_in[5],(const int*)d_in[6]};
  const int* drows[4]; const int* dcols[4]; const float* dvals[4];
  for (int i=0;i<4;i++){ drows[i]=(const int*)d_in[7+3*i]; dcols[i]=(const int*)d_in[8+3*i]; dvals[i]=(const float*)d_in[9+3*i]; }
  const int* urows[4]; const int* ucols[4]; const float* uvals[4];
  for (int i=0;i<4;i++){ urows[i]=(const int*)d_in[19+3*i]; ucols[i]=(const int*)d_in[20+3*i]; uvals[i]=(const float*)d_in[21+3*i]; }
  const float* encW[4]={(const float*)d_in[31],(const float*)d_in[33],(const float*)d_in[35],(const float*)d_in[37]};
  const float* encB[4]={(const float*)d_in[32],(const float*)d_in[34],(const float*)d_in[36],(const float*)d_in[38]};
  const float* enc_lin_W=(const float*)d_in[39]; const float* enc_lin_b=(const float*)d_in[40];
  const float* dec_lin_W=(const float*)d_in[41]; const float* dec_lin_b=(const float*)d_in[42];
  const float* decW[5]={(const float*)d_in[43],(const float*)d_in[45],(const float*)d_in[47],(const float*)d_in[49],(const float*)d_in[51]};
  const float* decB[5]={(const float*)d_in[44],(const float*)d_in[46],(const float*)d_in[48],(const float*)d_in[50],(const float*)d_in[52]};
  const float* audW=(const float*)d_in[53]; const float* audB=(const float*)d_in[54];
  const float* l0_Wih=(const float*)d_in[55]; const float* l0_Whh=(const float*)d_in[56];
  const float* l0_bih=(const float*)d_in[57]; const float* l0_bhh=(const float*)d_in[58];
  const float* l12_Wih=(const float*)d_in[59]; const float* l12_Whh=(const float*)d_in[60];
  const float* l12_bih=(const float*)d_in[61]; const float* l12_bhh=(const float*)d_in[62];
  float* out = (float*)d_out;

  // ---- workspace layout (bytes) ----
  char* base = (char*)d_ws;
  u16* A  = (u16*)base;                          // 10,287,104 B
  u16* Bb = (u16*)(base + 10287104);             // 20,574,208 B
  int* curBase = (int*)(base + 30891520);        // 8341 ints
  int* lstBase = (int*)(base + 30924928);        // 533,824 ints -> ends 33,060,224
  u16* Wbf = (u16*)(base + 33060224);            // 1,363,968 bf16 = 2,727,936 B
  float* sm = (float*)(base + 35788160);
  float* h0     = sm;                 // 4096
  float* latent = sm + 4096;          // 2048

  // bf16 weight segment offsets (elements): enc1,enc2,enc3,dec0,dec1,dec2,dec3
  const int wsz[7] = {64*288, 128*576, 256*1152, 256*2304, 128*2304, 64*1152, 32*576};
  WCast WC; int wcum = 0;
  const float* wsrc[7] = {encW[1],encW[2],encW[3],decW[0],decW[1],decW[2],decW[3]};
  int wo[7];
  for (int k=0;k<7;k++){ WC.src[k]=wsrc[k]; WC.cum[k]=wcum; wo[k]=wcum; wcum+=wsz[k]; }
  WC.cum[7]=wcum;
  cast_all_k<<<CDIV(wcum,256),256,0,stream>>>(WC, Wbf, wcum);

  // pool bookkeeping: d0,d1,d2,d3,u0,u1,u2,u3
  const int pVout[8] = {1256,314,79,20,5023,1256,314,79};
  const int pNnz[8]  = {3768,942,237,60,15069,3768,942,237};
  Lists L; int curoff=0, lstoff=0, totnnz=0;
  const int* prow[8] = {drows[0],drows[1],drows[2],drows[3],urows[0],urows[1],urows[2],urows[3]};
  int curo[8], lsto[8];
  for (int k=0;k<8;k++){
    L.rows[k]=prow[k]; L.nnz[k]=pNnz[k];
    L.curoff[k]=curoff; L.lstoff[k]=lstoff;
    curo[k]=curoff; lsto[k]=lstoff;
    curoff += pVout[k]; lstoff += pVout[k]*POOL_CAP; totnnz += pNnz[k];
  }
  hipMemsetAsync(curBase, 0, (size_t)curoff*4, stream);
  fill_all_k<<<CDIV(totnnz,256),256,0,stream>>>(L, curBase, lstBase, totnnz);

  // ---- audio path (writes h0[:, :64]) ----
  audio_emb_k<<<32,256,0,stream>>>(audio, audW, audB, h0);

  // ---- encoder (B=1) ----
  conv3_k<<<CDIV(5023*32,256),256,0,stream>>>(actor, sp[0], encW[0], encB[0], A, 5023, 32);
  pool_g4_k<<<CDIV(1256*8,256),256,0,stream>>>(A, dcols[0], dvals[0], curBase+curo[0], lstBase+lsto[0], Bb, 1, 5023, 1256, 32);
  conv_mfma<32,64,64><<<dim3(CDIV(1256,64),1),256,0,stream>>>(Bb, sp[1], Wbf+wo[0], encB[1], A, 1256, 64, 1256);
  pool_g4_k<<<CDIV(314*16,256),256,0,stream>>>(A, dcols[1], dvals[1], curBase+curo[1], lstBase+lsto[1], Bb, 1, 1256, 314, 64);
  conv_mfma<64,64,64><<<dim3(CDIV(314,64),2),256,0,stream>>>(Bb, sp[2], Wbf+wo[1], encB[2], A, 314, 128, 314);
  pool_g4_k<<<CDIV(79*32,256),256,0,stream>>>(A, dcols[2], dvals[2], curBase+curo[2], lstBase+lsto[2], Bb, 1, 314, 79, 128);
  conv_mfma<128,64,64><<<dim3(CDIV(79,64),4),256,0,stream>>>(Bb, sp[3], Wbf+wo[2], encB[3], A, 79, 256, 79);
  pool_g4_k<<<CDIV(20*64,256),256,0,stream>>>(A, dcols[3], dvals[3], curBase+curo[3], lstBase+lsto[3], Bb, 1, 79, 20, 256);

  enc_lin_k<<<64,256,0,stream>>>(Bb, enc_lin_W, enc_lin_b, h0);

  // ---- LSTM v4 (single block) ----
  lstm3_k<<<1,256,0,stream>>>(h0, l0_Wih, l0_Whh, l0_bih, l0_bhh,
                              l12_Wih, l12_Whh, l12_bih, l12_bhh, latent);

  // ---- decoder (B=32) ----
  dec_lin_k<<<CDIV(32*5120,256),256,0,stream>>>(latent, dec_lin_W, dec_lin_b, A); // (32,20,256)

  // j=3: up-pool u3 (20->79,C=256), conv IC=256 OC=256
  pool_g4_k<<<CDIV(32*79*64,256),256,0,stream>>>(A, ucols[3], uvals[3], curBase+curo[7], lstBase+lsto[7], Bb, 32, 20, 79, 256);
  conv_mfma<256,64,64><<<dim3(CDIV(2528,64),4),256,0,stream>>>(Bb, sp[3], Wbf+wo[3], decB[0], A, 79, 256, 2528);

  // j=2: up-pool u2 (79->314,C=256), conv IC=256 OC=128
  pool_g4_k<<<CDIV(32*314*64,256),256,0,stream>>>(A, ucols[2], uvals[2], curBase+curo[6], lstBase+lsto[6], Bb, 32, 79, 314, 256);
  conv_mfma<256,64,128><<<dim3(CDIV(10048,128),2),256,0,stream>>>(Bb, sp[2], Wbf+wo[4], decB[1], A, 314, 128, 10048);

  // j=1: up-pool u1 (314->1256,C=128), conv IC=128 OC=64
  pool_g4_k<<<CDIV(32*1256*32,256),256,0,stream>>>(A, ucols[1], uvals[1], curBase+curo[5], lstBase+lsto[5], Bb, 32, 314, 1256, 128);
  conv_mfma<128,64,128><<<dim3(CDIV(40192,128),1),256,0,stream>>>(Bb, sp[1], Wbf+wo[5], decB[2], A, 1256, 64, 40192);

  // j=0: up-pool u0 (1256->5023,C=64), conv IC=64 OC=32
  pool_g4_k<<<CDIV(32*5023*16,256),256,0,stream>>>(A, ucols[0], uvals[0], curBase+curo[4], lstBase+lsto[4], Bb, 32, 1256, 5023, 64);
  conv_mfma<64,32,128><<<dim3(CDIV(160736,128),1),256,0,stream>>>(Bb, sp[0], Wbf+wo[6], decB[3], A, 5023, 32, 160736);

  // final conv (288->3) + actor residual -> f32 out
  final_k<<<CDIV(32*5023,256),256,0,stream>>>(A, sp[0], decW[4], decB[4], actor, out);
}

// Round 10
// 590.987 us; speedup vs baseline: 10.0635x; 1.1812x over previous
//
#include <hip/hip_runtime.h>
#include <cstdint>
#include <cstddef>

// SpiralAutoencoder forward, MI355X gfx950.
// Inputs f32, indices i32, output f32. Internal activations bf16, fp32 accum.
// Spiral convs = MFMA bf16 GEMM (16x16x32), weights pre-cast to bf16,
//   R9: software-pipelined K-loop (reg prefetch + LDS double buffer, ONE
//   barrier/iter) + spiral idx preloaded to LDS (gather chain off critical path).
// LSTM v4: x-proj via MFMA (parallel), recurrence Whh*h + shfl gates.
// Pools = gather via device-built capped per-row edge lists (fused builder).

typedef unsigned short u16;
typedef __attribute__((ext_vector_type(8))) short short8;
typedef __attribute__((ext_vector_type(4))) float float4v;
#define CDIV(a,b) (((a)+(b)-1)/(b))
#define POOL_CAP 64

__device__ __forceinline__ float bf(u16 u){ return __uint_as_float(((unsigned)u)<<16); }
__device__ __forceinline__ u16 fb(float x){
  unsigned u = __float_as_uint(x);
  unsigned r = u + 0x7fffu + ((u>>16)&1u);   // RNE
  return (u16)(r>>16);
}
__device__ __forceinline__ float lo16(unsigned u){ return __uint_as_float(u<<16); }
__device__ __forceinline__ float hi16(unsigned u){ return __uint_as_float(u & 0xffff0000u); }

// ---- fused f32->bf16 cast of all conv weights ----
struct WCast { const float* src[7]; int cum[8]; };
__global__ void cast_all_k(WCast C, u16* __restrict__ dst, int total){
  int i = blockIdx.x*blockDim.x + threadIdx.x;
  if (i >= total) return;
  int k = 0;
  while (i >= C.cum[k+1]) k++;
  dst[i] = fb(C.src[k][i - C.cum[k]]);
}

// ---- audio embedding: (32,1536)@(64,1536)^T + b -> h0[t*128+f] (f<64) ----
__global__ void audio_emb_k(const float* __restrict__ ah, const float* __restrict__ W,
                            const float* __restrict__ b, float* __restrict__ h0){
  int t = blockIdx.x;
  int f = threadIdx.x >> 2, sl = threadIdx.x & 3;
  const float4* x4 = (const float4*)(ah + t*1536);
  const float4* w4 = (const float4*)(W + f*1536);
  float acc = 0.f;
  for (int k=sl; k<384; k+=4){
    float4 xv = x4[k], wv = w4[k];
    acc += xv.x*wv.x + xv.y*wv.y + xv.z*wv.z + xv.w*wv.w;
  }
  acc += __shfl_down(acc, 2, 64);
  acc += __shfl_down(acc, 1, 64);
  if (sl == 0) h0[t*128 + f] = acc + b[f];
}

// ---- scalar spiral conv for IC=3 (encoder stage 0), reads f32 actor ----
__global__ void conv3_k(const float* __restrict__ x, const int* __restrict__ idx,
                        const float* __restrict__ W, const float* __restrict__ bias,
                        u16* __restrict__ out, int V, int OC){
  int i = blockIdx.x*blockDim.x + threadIdx.x;
  if (i >= V*OC) return;
  int o = i % OC; int v = i / OC;
  const float* wrow = W + (size_t)o*27;
  const int* vix = idx + v*9;
  float acc = bias[o];
  for (int s=0;s<9;s++){
    const float* xr = x + (size_t)vix[s]*3;
    acc += xr[0]*wrow[s*3] + xr[1]*wrow[s*3+1] + xr[2]*wrow[s*3+2];
  }
  if (acc < 0.f) acc = expm1f(acc);
  out[i] = fb(acc);
}

// ---- MFMA spiral conv, software-pipelined (R9) ----
template<int IC, int BN, int BM>
__global__ void __launch_bounds__(256) conv_mfma(
    const u16* __restrict__ x, const int* __restrict__ idx,
    const u16* __restrict__ Wb, const float* __restrict__ bias,
    u16* __restrict__ out, int V, int OC, int M){
  constexpr int K = 9*IC;
  constexpr int KC = K/32;
  constexpr int NT = BN/16;
  constexpr int MT = BM/64;
  constexpr int LOG2 = (IC==32?5: IC==64?6: IC==128?7:8);
  constexpr int AST = 40;                 // LDS row stride (u16): 32 data + 8 pad
  __shared__ u16 Asm[2][BM*AST];
  __shared__ u16 Bsm[2][BN*AST];
  __shared__ int rowB[BM], rowV[BM];
  __shared__ int sidx[BM*9];
  int t = threadIdx.x;
  int m0 = blockIdx.x*BM;
  int o0 = blockIdx.y*BN;
  if (t < BM){
    int mg = m0 + t;
    if (mg < M){ int b = mg / V; rowB[t] = b; rowV[t] = mg - b*V; }
    else rowB[t] = -1;
  }
  __syncthreads();
  for (int i=t; i<BM*9; i+=256){           // spiral idx preload (once)
    int r = i/9, s = i - r*9;
    sidx[i] = (rowB[r] >= 0) ? idx[rowV[r]*9 + s] : 0;
  }
  int lane = t & 63, wave = t >> 6;
  int quad = lane >> 4, col = lane & 15;
  float4v acc[MT][NT];
  #pragma unroll
  for (int mi=0;mi<MT;mi++)
    #pragma unroll
    for (int nt=0;nt<NT;nt++) acc[mi][nt] = (float4v)0.f;

  uint4 aval[MT]; uint4 bval;
  auto fetch = [&](int kc){
    int s  = (kc*32) >> LOG2;
    int c0 = (kc*32) & (IC-1);
    #pragma unroll
    for (int rpt=0; rpt<MT; ++rpt){
      int seg = t + 256*rpt;
      int arow = seg >> 2, aq = seg & 3;
      int b = rowB[arow];
      uint4 v = {0u,0u,0u,0u};
      if (b >= 0){
        int ix = sidx[arow*9 + s];
        v = *(const uint4*)(x + ((size_t)b*V + ix)*IC + c0 + aq*8);
      }
      aval[rpt] = v;
    }
    if (t < BN*4){
      int br = t >> 2, bq = t & 3;
      bval = *(const uint4*)(Wb + (size_t)(o0+br)*K + kc*32 + bq*8);
    }
  };

  __syncthreads();      // sidx ready
  fetch(0);

  for (int kc = 0; kc < KC; ++kc){
    int buf = kc & 1;
    #pragma unroll
    for (int rpt=0; rpt<MT; ++rpt){
      int seg = t + 256*rpt;
      int arow = seg >> 2, aq = seg & 3;
      *(uint4*)&Asm[buf][arow*AST + aq*8] = aval[rpt];
    }
    if (t < BN*4){
      int br = t >> 2, bq = t & 3;
      *(uint4*)&Bsm[buf][br*AST + bq*8] = bval;
    }
    __syncthreads();                      // the ONLY barrier per iteration
    if (kc+1 < KC) fetch(kc+1);           // latency overlaps MFMA below
    short8 a[MT];
    #pragma unroll
    for (int mi=0;mi<MT;mi++)
      a[mi] = *(const short8*)&Asm[buf][(wave*MT*16 + mi*16 + col)*AST + quad*8];
    #pragma unroll
    for (int nt=0; nt<NT; ++nt){
      short8 bfr = *(const short8*)&Bsm[buf][(nt*16 + col)*AST + quad*8];
      #pragma unroll
      for (int mi=0;mi<MT;mi++)
        acc[mi][nt] = __builtin_amdgcn_mfma_f32_16x16x32_bf16(a[mi], bfr, acc[mi][nt], 0, 0, 0);
    }
  }
  #pragma unroll
  for (int mi=0;mi<MT;mi++){
    #pragma unroll
    for (int nt=0; nt<NT; ++nt){
      int o = o0 + nt*16 + col;
      float bv = bias[o];
      #pragma unroll
      for (int r=0;r<4;r++){
        int mg = m0 + wave*MT*16 + mi*16 + quad*4 + r;
        if (mg < M){
          float val = acc[mi][nt][r] + bv;
          if (val < 0.f) val = expm1f(val);
          out[(size_t)mg*OC + o] = fb(val);
        }
      }
    }
  }
}

// ---- fused list builder for all 8 pool matrices ----
struct Lists {
  const int* rows[8];
  int nnz[8];
  int curoff[8];
  int lstoff[8];
};
__global__ void fill_all_k(Lists L, int* __restrict__ curBase, int* __restrict__ lstBase, int total){
  int i = blockIdx.x*blockDim.x + threadIdx.x;
  if (i >= total) return;
  int off = i, k = 0;
  while (off >= L.nnz[k]){ off -= L.nnz[k]; k++; }
  int r = L.rows[k][off];
  int p = atomicAdd(curBase + L.curoff[k] + r, 1);
  if (p < POOL_CAP) lstBase[L.lstoff[k] + r*POOL_CAP + p] = off;
}

// ---- pool gather, 4 channels/thread ----
__global__ void pool_g4_k(const u16* __restrict__ x, const int* __restrict__ cols,
                          const float* __restrict__ vals, const int* __restrict__ cur,
                          const int* __restrict__ lst, u16* __restrict__ out,
                          int B, int Vin, int Vout, int C){
  int C4 = C >> 2;
  int total = B*Vout*C4;
  int i = blockIdx.x*blockDim.x + threadIdx.x;
  if (i >= total) return;
  int c4 = i % C4; int tt = i / C4; int r = tt % Vout; int b = tt / Vout;
  int deg = cur[r]; if (deg > POOL_CAP) deg = POOL_CAP;
  const int* le = lst + r*POOL_CAP;
  float a0=0.f,a1=0.f,a2=0.f,a3=0.f;
  for (int k=0;k<deg;k++){
    int e = le[k];
    float v = vals[e];
    ushort4 xv = *(const ushort4*)(x + ((size_t)b*Vin + (size_t)cols[e])*C + c4*4);
    a0 += v*bf(xv.x); a1 += v*bf(xv.y); a2 += v*bf(xv.z); a3 += v*bf(xv.w);
  }
  ushort4 o; o.x=fb(a0); o.y=fb(a1); o.z=fb(a2); o.w=fb(a3);
  *(ushort4*)(out + ((size_t)b*Vout + (size_t)r)*C + c4*4) = o;
}

// ---- encoder linear, split-K + broadcast into h0[:,64:] ----
__global__ void __launch_bounds__(256) enc_lin_k(
    const u16* __restrict__ x, const float* __restrict__ W,
    const float* __restrict__ b, float* __restrict__ h0){
  int f = blockIdx.x;          // 64 blocks
  int t = threadIdx.x;         // 256
  const ushort4* x4 = (const ushort4*)x;
  const float4* w4 = (const float4*)(W + (size_t)f*5120);
  float acc = 0.f;
  for (int k=t; k<1280; k+=256){
    ushort4 xv = x4[k]; float4 wv = w4[k];
    acc += bf(xv.x)*wv.x + bf(xv.y)*wv.y + bf(xv.z)*wv.z + bf(xv.w)*wv.w;
  }
  #pragma unroll
  for (int off=32; off; off>>=1) acc += __shfl_down(acc, off, 64);
  __shared__ float red[4];
  if ((t & 63) == 0) red[t>>6] = acc;
  __syncthreads();
  if (t < 32){
    float zf = b[f] + red[0] + red[1] + red[2] + red[3];
    h0[t*128 + 64 + f] = zf;
  }
}

// ---- LSTM v4 ----
__device__ __forceinline__ float sigm(float x){ return 1.f/(1.f+__expf(-x)); }
__device__ __forceinline__ float tanhfast(float x){ return 1.f - 2.f/(__expf(2.f*x)+1.f); }

__global__ void __launch_bounds__(256) lstm3_k(
    const float* __restrict__ h0,
    const float* __restrict__ l0_Wih, const float* __restrict__ l0_Whh,
    const float* __restrict__ l0_bih, const float* __restrict__ l0_bhh,
    const float* __restrict__ l12_Wih, const float* __restrict__ l12_Whh,
    const float* __restrict__ l12_bih, const float* __restrict__ l12_bhh,
    float* __restrict__ latent){
  __shared__ __align__(16) u16 xb[32*136];       // x, bf16, stride 136
  __shared__ __align__(16) float xp[2*32*128];   // xproj+bias, [dir][t][j]
  __shared__ __align__(16) u16 obuf[32*64];
  __shared__ __align__(16) u16 hsh[2][32];
  __shared__ float bias_l[256];
  int t = threadIdx.x;
  int lane = t & 63, wave = t >> 6;
  int quad = lane >> 4, col = lane & 15;
  int dir = t >> 7;
  bool rev = (dir == 1);
  int w2 = (t >> 6) & 1;
  int unit = w2*16 + col;
  int jj = quad*32 + unit;

  for (int i=t;i<32*128;i+=256){ int tt=i>>7, k=i&127; xb[tt*136+k]=fb(h0[i]); }

  for (int layer=0; layer<3; layer++){
    int IN = (layer==0)?128:64;
    const float *Wih,*Whh,*bih,*bhh;
    if (layer==0){ Wih=l0_Wih; Whh=l0_Whh; bih=l0_bih; bhh=l0_bhh; }
    else {
      int mb=(layer-1)*2;
      Wih=l12_Wih + (size_t)mb*128*64; Whh=l12_Whh + (size_t)mb*128*32;
      bih=l12_bih + mb*128; bhh=l12_bhh + mb*128;
    }
    const float* WhhD = Whh + (size_t)dir*128*32 + (size_t)jj*32;
    unsigned whh[16];
    #pragma unroll
    for (int k=0;k<16;k++){
      float2 w = *(const float2*)&WhhD[2*k];
      whh[k] = ((unsigned)fb(w.x)) | (((unsigned)fb(w.y))<<16);
    }
    bias_l[t] = bih[dir*128 + (t&127)] + bhh[dir*128 + (t&127)];
    if (quad == 0) hsh[dir][unit] = 0;
    float creg = 0.f;
    __syncthreads();

    // Phase A: xproj via MFMA
    {
      int dirA = wave >> 1, o0 = (wave & 1)*64;
      const float* WA = Wih + (size_t)dirA*128*IN;
      float4v acc[2][4];
      #pragma unroll
      for (int mi=0;mi<2;mi++)
        #pragma unroll
        for (int nt=0;nt<4;nt++) acc[mi][nt] = (float4v)0.f;
      for (int kc=0; kc<IN/32; ++kc){
        short8 bfrag[4];
        #pragma unroll
        for (int nt=0;nt<4;nt++){
          const float* src = WA + (size_t)(o0+nt*16+col)*IN + kc*32 + quad*8;
          float4 w0 = *(const float4*)src;
          float4 w1 = *(const float4*)(src+4);
          alignas(16) u16 tmp[8] = {fb(w0.x),fb(w0.y),fb(w0.z),fb(w0.w),
                                    fb(w1.x),fb(w1.y),fb(w1.z),fb(w1.w)};
          bfrag[nt] = *(const short8*)tmp;
        }
        short8 afrag[2];
        #pragma unroll
        for (int mi=0;mi<2;mi++)
          afrag[mi] = *(const short8*)&xb[(mi*16+col)*136 + kc*32 + quad*8];
        #pragma unroll
        for (int nt=0;nt<4;nt++)
          #pragma unroll
          for (int mi=0;mi<2;mi++)
            acc[mi][nt] = __builtin_amdgcn_mfma_f32_16x16x32_bf16(afrag[mi], bfrag[nt], acc[mi][nt], 0, 0, 0);
      }
      #pragma unroll
      for (int mi=0;mi<2;mi++)
        #pragma unroll
        for (int nt=0;nt<4;nt++){
          int j = o0 + nt*16 + col;
          float bv = bias_l[dirA*128 + j];
          #pragma unroll
          for (int r=0;r<4;r++){
            int tt = mi*16 + quad*4 + r;
            xp[dirA*4096 + tt*128 + j] = acc[mi][nt][r] + bv;
          }
        }
    }
    __syncthreads();

    // Phase B: recurrence, one barrier per step
    for (int s=0;s<32;s++){
      int tx = rev ? (31-s) : s;
      float g = xp[dir*4096 + tx*128 + jj];
      const uint4* h4 = (const uint4*)hsh[dir];
      float a0=0.f,a1=0.f,a2=0.f,a3=0.f;
      #pragma unroll
      for (int k=0;k<4;k++){
        uint4 hv = h4[k];
        unsigned u0=whh[4*k], u1=whh[4*k+1], u2=whh[4*k+2], u3=whh[4*k+3];
        a0 = fmaf(lo16(hv.x), lo16(u0), a0);
        a0 = fmaf(hi16(hv.x), hi16(u0), a0);
        a1 = fmaf(lo16(hv.y), lo16(u1), a1);
        a1 = fmaf(hi16(hv.y), hi16(u1), a1);
        a2 = fmaf(lo16(hv.z), lo16(u2), a2);
        a2 = fmaf(hi16(hv.z), hi16(u2), a2);
        a3 = fmaf(lo16(hv.w), lo16(u3), a3);
        a3 = fmaf(hi16(hv.w), hi16(u3), a3);
      }
      g += (a0+a1) + (a2+a3);
      float act = (quad == 2) ? tanhfast(g) : sigm(g);
      float gi = __shfl(act, col, 64);
      float gf = __shfl(act, 16+col, 64);
      float gg = __shfl(act, 32+col, 64);
      float go = __shfl(act, 48+col, 64);
      if (quad == 0){
        float cn = gf*creg + gi*gg;
        float hn = go*tanhfast(cn);
        creg = cn;
        u16 hb = fb(hn);
        hsh[dir][unit] = hb;
        obuf[tx*64 + dir*32 + unit] = hb;
      }
      __syncthreads();
    }
    if (layer < 2){
      for (int i=t;i<32*64;i+=256){ int tt=i>>6, k=i&63; xb[tt*136+k]=obuf[i]; }
      __syncthreads();
    }
  }
  for (int i=t;i<32*64;i+=256) latent[i] = bf(obuf[i]);
}

// ---- decoder linear: y[t,r] = b[r] + sum_{k<64} latent[t,k]*W[r,k] -> bf16 ----
__global__ void dec_lin_k(const float* __restrict__ latent, const float* __restrict__ W,
                          const float* __restrict__ b, u16* __restrict__ y){
  int i = blockIdx.x*blockDim.x + threadIdx.x;
  if (i >= 32*5120) return;
  int r = i % 5120, t = i / 5120;
  const float4* x4 = (const float4*)(latent + t*64);
  const float4* w4 = (const float4*)(W + (size_t)r*64);
  float acc = b[r];
  #pragma unroll
  for (int k=0;k<16;k++){
    float4 xv=x4[k]; float4 wv=w4[k];
    acc += xv.x*wv.x+xv.y*wv.y+xv.z*wv.z+xv.w*wv.w;
  }
  y[i] = fb(acc);
}

// ---- final conv (OC=3, IC=32, no ELU) + actor residual -> f32 out ----
__global__ void final_k(const u16* __restrict__ x, const int* __restrict__ idx,
                        const float* __restrict__ W, const float* __restrict__ bias,
                        const float* __restrict__ actor, float* __restrict__ out){
  __shared__ float Wsm[3*288];
  __shared__ float bsm[3];
  int t = threadIdx.x;
  for (int i=t;i<864;i+=256) Wsm[i]=W[i];
  if (t<3) bsm[t]=bias[t];
  __syncthreads();
  int g = blockIdx.x*256 + t;
  if (g >= 32*5023) return;
  int v = g % 5023, b = g / 5023;
  const u16* xb = x + (size_t)b*5023*32;
  const int* vix = idx + v*9;
  float a0=bsm[0], a1=bsm[1], a2=bsm[2];
  for (int s=0;s<9;s++){
    const ushort4* xr = (const ushort4*)(xb + (size_t)vix[s]*32);
    #pragma unroll
    for (int k=0;k<8;k++){
      ushort4 xv = xr[k];
      float x0=bf(xv.x), x1=bf(xv.y), x2=bf(xv.z), x3=bf(xv.w);
      int kk = s*32 + k*4;
      a0 += x0*Wsm[kk] + x1*Wsm[kk+1] + x2*Wsm[kk+2] + x3*Wsm[kk+3];
      a1 += x0*Wsm[288+kk] + x1*Wsm[288+kk+1] + x2*Wsm[288+kk+2] + x3*Wsm[288+kk+3];
      a2 += x0*Wsm[576+kk] + x1*Wsm[576+kk+1] + x2*Wsm[576+kk+2] + x3*Wsm[576+kk+3];
    }
  }
  out[(size_t)g*3+0] = a0 + actor[v*3+0];
  out[(size_t)g*3+1] = a1 + actor[v*3+1];
  out[(size_t)g*3+2] = a2 + actor[v*3+2];
}

extern "C" void kernel_launch(void* const* d_in, const int* in_sizes, int n_in,
                              void* d_out, int out_size, void* d_ws, size_t ws_size,
                              hipStream_t stream){
  (void)in_sizes; (void)n_in; (void)out_size; (void)ws_size;

  const float* audio = (const float*)d_in[0];
  const float* actor = (const float*)d_in[2];
  const int* sp[4]   = {(const int*)d_in[3],(const int*)d_in[4],(const int*)d_in[5],(const int*)d_in[6]};
  const int* drows[4]; const int* dcols[4]; const float* dvals[4];
  for (int i=0;i<4;i++){ drows[i]=(const int*)d_in[7+3*i]; dcols[i]=(const int*)d_in[8+3*i]; dvals[i]=(const float*)d_in[9+3*i]; }
  const int* urows[4]; const int* ucols[4]; const float* uvals[4];
  for (int i=0;i<4;i++){ urows[i]=(const int*)d_in[19+3*i]; ucols[i]=(const int*)d_in[20+3*i]; uvals[i]=(const float*)d_in[21+3*i]; }
  const float* encW[4]={(const float*)d_in[31],(const float*)d_in[33],(const float*)d_in[35],(const float*)d_in[37]};
  const float* encB[4]={(const float*)d_in[32],(const float*)d_in[34],(const float*)d_in[36],(const float*)d_in[38]};
  const float* enc_lin_W=(const float*)d_in[39]; const float* enc_lin_b=(const float*)d_in[40];
  const float* dec_lin_W=(const float*)d_in[41]; const float* dec_lin_b=(const float*)d_in[42];
  const float* decW[5]={(const float*)d_in[43],(const float*)d_in[45],(const float*)d_in[47],(const float*)d_in[49],(const float*)d_in[51]};
  const float* decB[5]={(const float*)d_in[44],(const float*)d_in[46],(const float*)d_in[48],(const float*)d_in[50],(const float*)d_in[52]};
  const float* audW=(const float*)d_in[53]; const float* audB=(const float*)d_in[54];
  const float* l0_Wih=(const float*)d_in[55]; const float* l0_Whh=(const float*)d_in[56];
  const float* l0_bih=(const float*)d_in[57]; const float* l0_bhh=(const float*)d_in[58];
  const float* l12_Wih=(const float*)d_in[59]; const float* l12_Whh=(const float*)d_in[60];
  const float* l12_bih=(const float*)d_in[61]; const float* l12_bhh=(const float*)d_in[62];
  float* out = (float*)d_out;

  // ---- workspace layout (bytes) ----
  char* base = (char*)d_ws;
  u16* A  = (u16*)base;                          // 10,287,104 B
  u16* Bb = (u16*)(base + 10287104);             // 20,574,208 B
  int* curBase = (int*)(base + 30891520);        // 8341 ints
  int* lstBase = (int*)(base + 30924928);        // 533,824 ints -> ends 33,060,224
  u16* Wbf = (u16*)(base + 33060224);            // 1,363,968 bf16 = 2,727,936 B
  float* sm = (float*)(base + 35788160);
  float* h0     = sm;                 // 4096
  float* latent = sm + 4096;          // 2048

  // bf16 weight segment offsets (elements): enc1,enc2,enc3,dec0,dec1,dec2,dec3
  const int wsz[7] = {64*288, 128*576, 256*1152, 256*2304, 128*2304, 64*1152, 32*576};
  WCast WC; int wcum = 0;
  const float* wsrc[7] = {encW[1],encW[2],encW[3],decW[0],decW[1],decW[2],decW[3]};
  int wo[7];
  for (int k=0;k<7;k++){ WC.src[k]=wsrc[k]; WC.cum[k]=wcum; wo[k]=wcum; wcum+=wsz[k]; }
  WC.cum[7]=wcum;
  cast_all_k<<<CDIV(wcum,256),256,0,stream>>>(WC, Wbf, wcum);

  // pool bookkeeping: d0,d1,d2,d3,u0,u1,u2,u3
  const int pVout[8] = {1256,314,79,20,5023,1256,314,79};
  const int pNnz[8]  = {3768,942,237,60,15069,3768,942,237};
  Lists L; int curoff=0, lstoff=0, totnnz=0;
  const int* prow[8] = {drows[0],drows[1],drows[2],drows[3],urows[0],urows[1],urows[2],urows[3]};
  int curo[8], lsto[8];
  for (int k=0;k<8;k++){
    L.rows[k]=prow[k]; L.nnz[k]=pNnz[k];
    L.curoff[k]=curoff; L.lstoff[k]=lstoff;
    curo[k]=curoff; lsto[k]=lstoff;
    curoff += pVout[k]; lstoff += pVout[k]*POOL_CAP; totnnz += pNnz[k];
  }
  hipMemsetAsync(curBase, 0, (size_t)curoff*4, stream);
  fill_all_k<<<CDIV(totnnz,256),256,0,stream>>>(L, curBase, lstBase, totnnz);

  // ---- audio path (writes h0[:, :64]) ----
  audio_emb_k<<<32,256,0,stream>>>(audio, audW, audB, h0);

  // ---- encoder (B=1) ----
  conv3_k<<<CDIV(5023*32,256),256,0,stream>>>(actor, sp[0], encW[0], encB[0], A, 5023, 32);
  pool_g4_k<<<CDIV(1256*8,256),256,0,stream>>>(A, dcols[0], dvals[0], curBase+curo[0], lstBase+lsto[0], Bb, 1, 5023, 1256, 32);
  conv_mfma<32,64,64><<<dim3(CDIV(1256,64),1),256,0,stream>>>(Bb, sp[1], Wbf+wo[0], encB[1], A, 1256, 64, 1256);
  pool_g4_k<<<CDIV(314*16,256),256,0,stream>>>(A, dcols[1], dvals[1], curBase+curo[1], lstBase+lsto[1], Bb, 1, 1256, 314, 64);
  conv_mfma<64,64,64><<<dim3(CDIV(314,64),2),256,0,stream>>>(Bb, sp[2], Wbf+wo[1], encB[2], A, 314, 128, 314);
  pool_g4_k<<<CDIV(79*32,256),256,0,stream>>>(A, dcols[2], dvals[2], curBase+curo[2], lstBase+lsto[2], Bb, 1, 314, 79, 128);
  conv_mfma<128,64,64><<<dim3(CDIV(79,64),4),256,0,stream>>>(Bb, sp[3], Wbf+wo[2], encB[3], A, 79, 256, 79);
  pool_g4_k<<<CDIV(20*64,256),256,0,stream>>>(A, dcols[3], dvals[3], curBase+curo[3], lstBase+lsto[3], Bb, 1, 79, 20, 256);

  enc_lin_k<<<64,256,0,stream>>>(Bb, enc_lin_W, enc_lin_b, h0);

  // ---- LSTM v4 (single block) ----
  lstm3_k<<<1,256,0,stream>>>(h0, l0_Wih, l0_Whh, l0_bih, l0_bhh,
                              l12_Wih, l12_Whh, l12_bih, l12_bhh, latent);

  // ---- decoder (B=32) ----
  dec_lin_k<<<CDIV(32*5120,256),256,0,stream>>>(latent, dec_lin_W, dec_lin_b, A); // (32,20,256)

  // j=3: up-pool u3 (20->79,C=256), conv IC=256 OC=256
  pool_g4_k<<<CDIV(32*79*64,256),256,0,stream>>>(A, ucols[3], uvals[3], curBase+curo[7], lstBase+lsto[7], Bb, 32, 20, 79, 256);
  conv_mfma<256,64,64><<<dim3(CDIV(2528,64),4),256,0,stream>>>(Bb, sp[3], Wbf+wo[3], decB[0], A, 79, 256, 2528);

  // j=2: up-pool u2 (79->314,C=256), conv IC=256 OC=128  (BM=64 -> 2x blocks)
  pool_g4_k<<<CDIV(32*314*64,256),256,0,stream>>>(A, ucols[2], uvals[2], curBase+curo[6], lstBase+lsto[6], Bb, 32, 79, 314, 256);
  conv_mfma<256,64,64><<<dim3(CDIV(10048,64),2),256,0,stream>>>(Bb, sp[2], Wbf+wo[4], decB[1], A, 314, 128, 10048);

  // j=1: up-pool u1 (314->1256,C=128), conv IC=128 OC=64
  pool_g4_k<<<CDIV(32*1256*32,256),256,0,stream>>>(A, ucols[1], uvals[1], curBase+curo[5], lstBase+lsto[5], Bb, 32, 314, 1256, 128);
  conv_mfma<128,64,128><<<dim3(CDIV(40192,128),1),256,0,stream>>>(Bb, sp[1], Wbf+wo[5], decB[2], A, 1256, 64, 40192);

  // j=0: up-pool u0 (1256->5023,C=64), conv IC=64 OC=32
  pool_g4_k<<<CDIV(32*5023*16,256),256,0,stream>>>(A, ucols[0], uvals[0], curBase+curo[4], lstBase+lsto[4], Bb, 32, 1256, 5023, 64);
  conv_mfma<64,32,128><<<dim3(CDIV(160736,128),1),256,0,stream>>>(Bb, sp[0], Wbf+wo[6], decB[3], A, 5023, 32, 160736);

  // final conv (288->3) + actor residual -> f32 out
  final_k<<<CDIV(32*5023,256),256,0,stream>>>(A, sp[0], decW[4], decB[4], actor, out);
}